// Round 1
// baseline (1237.310 us; speedup 1.0000x reference)
//
#include <hip/hip_runtime.h>
#include <cstdint>
#include <cstddef>

#define N_NODES 100000
#define N_EDGES 1600000
#define EPS 1e-5f

// ---------------- graph prep ----------------
__global__ void k_count(const int* __restrict__ src, const int* __restrict__ dst,
                        int* degs, int* degd) {
  int e = blockIdx.x * 256 + threadIdx.x;
  if (e < N_EDGES) {
    atomicAdd(&degs[src[e]], 1);
    atomicAdd(&degd[dst[e]], 1);
  }
}

__global__ void k_norms(const int* __restrict__ degs, const int* __restrict__ degd,
                        float* out_norm, float* in_norm) {
  int i = blockIdx.x * 256 + threadIdx.x;
  if (i < N_NODES) {
    out_norm[i] = rsqrtf((float)max(degs[i], 1));
    in_norm[i]  = rsqrtf((float)max(degd[i], 1));
  }
}

__global__ void k_scan1(const int* __restrict__ degd, int* bsum) {
  __shared__ int s[256];
  int t = threadIdx.x;
  int i = blockIdx.x * 256 + t;
  s[t] = (i < N_NODES) ? degd[i] : 0;
  __syncthreads();
  for (int off = 128; off > 0; off >>= 1) {
    if (t < off) s[t] += s[t + off];
    __syncthreads();
  }
  if (t == 0) bsum[blockIdx.x] = s[0];
}

__global__ void k_scan2(int* bsum, int nb) {
  __shared__ int s[512];
  int t = threadIdx.x;
  int v = (t < nb) ? bsum[t] : 0;
  s[t] = v;
  __syncthreads();
  for (int off = 1; off < 512; off <<= 1) {
    int x = (t >= off) ? s[t - off] : 0;
    __syncthreads();
    s[t] += x;
    __syncthreads();
  }
  if (t < nb) bsum[t] = s[t] - v;  // exclusive
}

__global__ void k_scan3(const int* __restrict__ degd, const int* __restrict__ bsum,
                        int* row_start) {
  __shared__ int s[256];
  int t = threadIdx.x;
  int i = blockIdx.x * 256 + t;
  int v = (i < N_NODES) ? degd[i] : 0;
  s[t] = v;
  __syncthreads();
  for (int off = 1; off < 256; off <<= 1) {
    int x = (t >= off) ? s[t - off] : 0;
    __syncthreads();
    s[t] += x;
    __syncthreads();
  }
  if (i < N_NODES) row_start[i] = bsum[blockIdx.x] + s[t] - v;
  if (i == 0) row_start[N_NODES] = N_EDGES;
}

__global__ void k_scatter(const int* __restrict__ src, const int* __restrict__ dst,
                          const int* __restrict__ row_start, int* cursor, int* col) {
  int e = blockIdx.x * 256 + threadIdx.x;
  if (e < N_EDGES) {
    int d = dst[e];
    int pos = row_start[d] + atomicAdd(&cursor[d], 1);
    col[pos] = src[e];
  }
}

// ---------------- aggregation: out[d] = in_norm[d] * sum_e out_norm[s]*h[s] ----------------
__global__ void k_agg128(const float* __restrict__ h, const int* __restrict__ col,
                         const int* __restrict__ row_start,
                         const float* __restrict__ out_norm,
                         const float* __restrict__ in_norm,
                         float* __restrict__ out) {
  int wave = threadIdx.x >> 6;
  int lane = threadIdx.x & 63;
  int node = blockIdx.x * 4 + wave;
  if (node >= N_NODES) return;
  int s0 = row_start[node], s1 = row_start[node + 1];
  const float2* hp = (const float2*)h;
  float2 acc = make_float2(0.f, 0.f);
  for (int e = s0; e < s1; ++e) {
    int s = col[e];
    float w = out_norm[s];
    float2 v = hp[(size_t)s * 64 + lane];
    acc.x += v.x * w;
    acc.y += v.y * w;
  }
  float sc = in_norm[node];
  ((float2*)out)[(size_t)node * 64 + lane] = make_float2(acc.x * sc, acc.y * sc);
}

// ---------------- dual GEMM: Out = Xa @ Wa^T + Xh @ Wh^T  (128x128 weights, (out,in) layout)
// Safe for Out aliasing Xh: each block reads only its own 64-row tile (staged to LDS) before writing.
__launch_bounds__(256, 2)
__global__ void k_gemm_dual(const float* __restrict__ Xa, const float* __restrict__ Xh,
                            const float* __restrict__ Wa, const float* __restrict__ Wh,
                            float* __restrict__ Out) {
  __shared__ float sX[128][64];   // [k][row] 32 KB
  __shared__ float sW[64][128];   // [k-kc][j] 32 KB
  int t = threadIdx.x;
  int row0 = blockIdx.x * 64;
  int rg = t & 7;    // 8 row-groups of 8 rows
  int cg = t >> 3;   // 32 col-groups of 4 cols
  float acc[8][4];
#pragma unroll
  for (int r = 0; r < 8; ++r)
#pragma unroll
    for (int c = 0; c < 4; ++c) acc[r][c] = 0.f;

  for (int phase = 0; phase < 2; ++phase) {
    const float* X = phase ? Xh : Xa;
    const float* W = phase ? Wh : Wa;
    __syncthreads();  // previous compute done before restaging sX
    {
      int r = t & 63, kq = t >> 6;
      int row = min(row0 + r, N_NODES - 1);
      const float4* xr = (const float4*)(X + (size_t)row * 128);
#pragma unroll
      for (int it = 0; it < 8; ++it) {
        int k4 = kq * 8 + it;
        float4 v = xr[k4];
        sX[k4 * 4 + 0][r] = v.x;
        sX[k4 * 4 + 1][r] = v.y;
        sX[k4 * 4 + 2][r] = v.z;
        sX[k4 * 4 + 3][r] = v.w;
      }
    }
    for (int kc = 0; kc < 128; kc += 64) {
      __syncthreads();  // sX staged / previous sW chunk consumed
      {
        int j = t & 127, kh = t >> 7;
        const float4* wr = (const float4*)(W + (size_t)j * 128);
#pragma unroll
        for (int it = 0; it < 8; ++it) {
          int k4 = (kc >> 2) + kh * 8 + it;
          float4 v = wr[k4];
          int kk = k4 * 4 - kc;
          sW[kk + 0][j] = v.x;
          sW[kk + 1][j] = v.y;
          sW[kk + 2][j] = v.z;
          sW[kk + 3][j] = v.w;
        }
      }
      __syncthreads();
#pragma unroll 4
      for (int k = 0; k < 64; ++k) {
        float4 a0 = *(const float4*)&sX[kc + k][rg * 8];
        float4 a1 = *(const float4*)&sX[kc + k][rg * 8 + 4];
        float4 w = *(const float4*)&sW[k][cg * 4];
        float a[8] = {a0.x, a0.y, a0.z, a0.w, a1.x, a1.y, a1.z, a1.w};
        float wv[4] = {w.x, w.y, w.z, w.w};
#pragma unroll
        for (int r = 0; r < 8; ++r)
#pragma unroll
          for (int c = 0; c < 4; ++c) acc[r][c] += a[r] * wv[c];
      }
    }
  }
#pragma unroll
  for (int r = 0; r < 8; ++r) {
    int row = row0 + rg * 8 + r;
    if (row < N_NODES) {
      float4 v = make_float4(acc[r][0], acc[r][1], acc[r][2], acc[r][3]);
      *(float4*)&Out[(size_t)row * 128 + cg * 4] = v;
    }
  }
}

// ---------------- BN stats: per-column sum & sumsq ----------------
__global__ void k_stats(const float* __restrict__ x, float* stats) {
  __shared__ float ls[256], ls2[256];
  int t = threadIdx.x;
  int c = t & 127, half = t >> 7;
  int base = blockIdx.x * 128;
  float s = 0.f, s2 = 0.f;
  for (int r = half; r < 128; r += 2) {
    int row = base + r;
    if (row < N_NODES) {
      float v = x[(size_t)row * 128 + c];
      s += v;
      s2 += v * v;
    }
  }
  ls[t] = s;
  ls2[t] = s2;
  __syncthreads();
  if (half == 0) {
    s += ls[t + 128];
    s2 += ls2[t + 128];
    atomicAdd(&stats[c], s);
    atomicAdd(&stats[128 + c], s2);
  }
}

__global__ void k_bnrelu(float* __restrict__ x, const float* __restrict__ stats,
                         const float* __restrict__ g, const float* __restrict__ b) {
  int i = blockIdx.x * 256 + threadIdx.x;  // float4 index
  if (i >= N_NODES * 32) return;
  int c4 = (i & 31) * 4;
  float4 v = ((const float4*)x)[i];
  float vv[4] = {v.x, v.y, v.z, v.w};
  const float inv = 1.f / (float)N_NODES;
#pragma unroll
  for (int j = 0; j < 4; ++j) {
    int c = c4 + j;
    float mu = stats[c] * inv;
    float var = stats[128 + c] * inv - mu * mu;
    float rs = rsqrtf(var + EPS);
    float y = (vv[j] - mu) * rs * g[c] + b[c];
    vv[j] = y > 0.f ? y : 0.f;
  }
  ((float4*)x)[i] = make_float4(vv[0], vv[1], vv[2], vv[3]);
}

// ---------------- layer-2 GEMM: p = out_norm*(X@w2^T)  (stored), out = X@l2^T + b2 ----------------
__launch_bounds__(256)
__global__ void k_gemm2(const float* __restrict__ X, const float* __restrict__ w2,
                        const float* __restrict__ l2, const float* __restrict__ b2,
                        const float* __restrict__ out_norm,
                        float* __restrict__ p, float* __restrict__ out) {
  __shared__ float sX[128][32];  // 16 KB
  __shared__ float sW[128][80];  // 40 KB  cols 0..39 = w2, 40..79 = l2
  int t = threadIdx.x;
  int row0 = blockIdx.x * 32;
  {
    int r = t & 31, kq = t >> 5;
    int row = min(row0 + r, N_NODES - 1);
    const float4* xr = (const float4*)(X + (size_t)row * 128);
#pragma unroll
    for (int it = 0; it < 4; ++it) {
      int k4 = kq * 4 + it;
      float4 v = xr[k4];
      sX[k4 * 4 + 0][r] = v.x;
      sX[k4 * 4 + 1][r] = v.y;
      sX[k4 * 4 + 2][r] = v.z;
      sX[k4 * 4 + 3][r] = v.w;
    }
  }
#pragma unroll
  for (int it = 0; it < 10; ++it) {
    int i = it * 1024 + t * 4;
    int k = i & 127, j = i >> 7;
    const float* srcp = (j < 40) ? (w2 + (size_t)j * 128 + k) : (l2 + (size_t)(j - 40) * 128 + k);
    float4 v = *(const float4*)srcp;
    sW[k + 0][j] = v.x;
    sW[k + 1][j] = v.y;
    sW[k + 2][j] = v.z;
    sW[k + 3][j] = v.w;
  }
  __syncthreads();
  int cg = t & 15, rg = t >> 4;  // 16 col-groups x 5 cols, 16 row-groups x 2 rows
  float acc[2][5];
#pragma unroll
  for (int r = 0; r < 2; ++r)
#pragma unroll
    for (int i = 0; i < 5; ++i) acc[r][i] = 0.f;
  for (int k = 0; k < 128; ++k) {
    float x0 = sX[k][rg * 2];
    float x1 = sX[k][rg * 2 + 1];
    float w[5];
#pragma unroll
    for (int i = 0; i < 5; ++i) w[i] = sW[k][cg * 5 + i];
#pragma unroll
    for (int i = 0; i < 5; ++i) {
      acc[0][i] += x0 * w[i];
      acc[1][i] += x1 * w[i];
    }
  }
#pragma unroll
  for (int r = 0; r < 2; ++r) {
    int row = row0 + rg * 2 + r;
    if (row >= N_NODES) continue;
    if (cg < 8) {
      float on = out_norm[row];
#pragma unroll
      for (int i = 0; i < 5; ++i) p[(size_t)row * 40 + cg * 5 + i] = on * acc[r][i];
    } else {
      int j0 = cg * 5 - 40;
#pragma unroll
      for (int i = 0; i < 5; ++i) out[(size_t)row * 40 + j0 + i] = acc[r][i] + b2[j0 + i];
    }
  }
}

// ---------------- layer-2 aggregation: out[d] += in_norm[d] * sum_e p[src] ----------------
__global__ void k_agg40(const float* __restrict__ p, const int* __restrict__ col,
                        const int* __restrict__ row_start,
                        const float* __restrict__ in_norm,
                        float* __restrict__ out) {
  int wave = threadIdx.x >> 6, lane = threadIdx.x & 63;
  int node = blockIdx.x * 4 + wave;
  if (node >= N_NODES) return;
  int s0 = row_start[node], s1 = row_start[node + 1];
  float acc = 0.f;
  for (int e = s0; e < s1; ++e) {
    int s = col[e];
    acc += p[(size_t)s * 40 + lane];  // lanes >=40 read junk inside buffer, masked at store
  }
  if (lane < 40) out[(size_t)node * 40 + lane] += in_norm[node] * acc;
}

extern "C" void kernel_launch(void* const* d_in, const int* in_sizes, int n_in,
                              void* d_out, int out_size, void* d_ws, size_t ws_size,
                              hipStream_t stream) {
  const float* feat = (const float*)d_in[0];
  const int* src = (const int*)d_in[1];
  const int* dst = (const int*)d_in[2];
  const float* w0 = (const float*)d_in[3];
  const float* w1 = (const float*)d_in[4];
  const float* w2 = (const float*)d_in[5];
  const float* b2 = (const float*)d_in[6];
  const float* l0 = (const float*)d_in[7];
  const float* l1 = (const float*)d_in[8];
  const float* l2 = (const float*)d_in[9];
  const float* g0 = (const float*)d_in[10];
  const float* beta0 = (const float*)d_in[11];
  const float* g1 = (const float*)d_in[12];
  const float* beta1 = (const float*)d_in[13];
  float* out = (float*)d_out;

  char* ws = (char*)d_ws;
  size_t off = 0;
  auto alloc = [&](size_t bytes) {
    void* ptr = ws + off;
    off = (off + bytes + 255) & ~(size_t)255;
    return ptr;
  };
  float* A = (float*)alloc(sizeof(float) * (size_t)N_NODES * 128);  // agg / p
  float* B = (float*)alloc(sizeof(float) * (size_t)N_NODES * 128);  // h / t
  int* degs = (int*)alloc(sizeof(int) * N_NODES);
  int* degd = (int*)alloc(sizeof(int) * N_NODES);
  int* cursor = (int*)alloc(sizeof(int) * N_NODES);
  int* row_start = (int*)alloc(sizeof(int) * (N_NODES + 1));
  int* colb = (int*)alloc(sizeof(int) * N_EDGES);
  float* out_norm = (float*)alloc(sizeof(float) * N_NODES);
  float* in_norm = (float*)alloc(sizeof(float) * N_NODES);
  int* bsum = (int*)alloc(sizeof(int) * 512);
  float* stats = (float*)alloc(sizeof(float) * 256);

  hipMemsetAsync(degs, 0, sizeof(int) * N_NODES, stream);
  hipMemsetAsync(degd, 0, sizeof(int) * N_NODES, stream);
  hipMemsetAsync(cursor, 0, sizeof(int) * N_NODES, stream);

  int eb = (N_EDGES + 255) / 256;  // 6250
  int nb = (N_NODES + 255) / 256;  // 391
  k_count<<<eb, 256, 0, stream>>>(src, dst, degs, degd);
  k_norms<<<nb, 256, 0, stream>>>(degs, degd, out_norm, in_norm);
  k_scan1<<<nb, 256, 0, stream>>>(degd, bsum);
  k_scan2<<<1, 512, 0, stream>>>(bsum, nb);
  k_scan3<<<nb, 256, 0, stream>>>(degd, bsum, row_start);
  k_scatter<<<eb, 256, 0, stream>>>(src, dst, row_start, cursor, colb);

  int ab = (N_NODES + 3) / 4;  // 25000 (wave per node)
  int gb = (N_NODES + 63) / 64;

  // layer 0: h1 = relu(bn(agg(feat)@w0^T + feat@l0^T))
  k_agg128<<<ab, 256, 0, stream>>>(feat, colb, row_start, out_norm, in_norm, A);
  k_gemm_dual<<<gb, 256, 0, stream>>>(A, feat, w0, l0, B);
  hipMemsetAsync(stats, 0, sizeof(float) * 256, stream);
  k_stats<<<(N_NODES + 127) / 128, 256, 0, stream>>>(B, stats);
  k_bnrelu<<<(N_NODES * 32 + 255) / 256, 256, 0, stream>>>(B, stats, g0, beta0);

  // layer 1: h2 = relu(bn(agg(h1)@w1^T + h1@l1^T))   (gemm in-place on B is tile-safe)
  k_agg128<<<ab, 256, 0, stream>>>(B, colb, row_start, out_norm, in_norm, A);
  k_gemm_dual<<<gb, 256, 0, stream>>>(A, B, w1, l1, B);
  hipMemsetAsync(stats, 0, sizeof(float) * 256, stream);
  k_stats<<<(N_NODES + 127) / 128, 256, 0, stream>>>(B, stats);
  k_bnrelu<<<(N_NODES * 32 + 255) / 256, 256, 0, stream>>>(B, stats, g1, beta1);

  // layer 2: out = in_norm*agg(out_norm*(h2@w2^T)) + b2 + h2@l2^T
  k_gemm2<<<(N_NODES + 31) / 32, 256, 0, stream>>>(B, w2, l2, b2, out_norm, A, out);
  k_agg40<<<ab, 256, 0, stream>>>(A, colb, row_start, in_norm, out);
}

// Round 3
// 1078.172 us; speedup vs baseline: 1.1476x; 1.1476x over previous
//
#include <hip/hip_runtime.h>
#include <cstdint>
#include <cstddef>

#define N_NODES 100000
#define N_EDGES 1600000
#define EPS 1e-5f

// ---------------- graph prep ----------------
__global__ void k_count(const int* __restrict__ src, const int* __restrict__ dst,
                        int* degs, int* degd) {
  int e = blockIdx.x * 256 + threadIdx.x;
  if (e < N_EDGES) {
    atomicAdd(&degs[src[e]], 1);
    atomicAdd(&degd[dst[e]], 1);
  }
}

__global__ void k_norms(const int* __restrict__ degs, const int* __restrict__ degd,
                        float* out_norm, float* in_norm) {
  int i = blockIdx.x * 256 + threadIdx.x;
  if (i < N_NODES) {
    out_norm[i] = rsqrtf((float)max(degs[i], 1));
    in_norm[i]  = rsqrtf((float)max(degd[i], 1));
  }
}

__global__ void k_scan1(const int* __restrict__ degd, int* bsum) {
  __shared__ int s[256];
  int t = threadIdx.x;
  int i = blockIdx.x * 256 + t;
  s[t] = (i < N_NODES) ? degd[i] : 0;
  __syncthreads();
  for (int off = 128; off > 0; off >>= 1) {
    if (t < off) s[t] += s[t + off];
    __syncthreads();
  }
  if (t == 0) bsum[blockIdx.x] = s[0];
}

__global__ void k_scan2(int* bsum, int nb) {
  __shared__ int s[512];
  int t = threadIdx.x;
  int v = (t < nb) ? bsum[t] : 0;
  s[t] = v;
  __syncthreads();
  for (int off = 1; off < 512; off <<= 1) {
    int x = (t >= off) ? s[t - off] : 0;
    __syncthreads();
    s[t] += x;
    __syncthreads();
  }
  if (t < nb) bsum[t] = s[t] - v;  // exclusive
}

__global__ void k_scan3(const int* __restrict__ degd, const int* __restrict__ bsum,
                        int* row_start) {
  __shared__ int s[256];
  int t = threadIdx.x;
  int i = blockIdx.x * 256 + t;
  int v = (i < N_NODES) ? degd[i] : 0;
  s[t] = v;
  __syncthreads();
  for (int off = 1; off < 256; off <<= 1) {
    int x = (t >= off) ? s[t - off] : 0;
    __syncthreads();
    s[t] += x;
    __syncthreads();
  }
  if (i < N_NODES) row_start[i] = bsum[blockIdx.x] + s[t] - v;
  if (i == 0) row_start[N_NODES] = N_EDGES;
}

__global__ void k_scatter(const int* __restrict__ src, const int* __restrict__ dst,
                          const int* __restrict__ row_start, int* cursor, int* col) {
  int e = blockIdx.x * 256 + threadIdx.x;
  if (e < N_EDGES) {
    int d = dst[e];
    int pos = row_start[d] + atomicAdd(&cursor[d], 1);
    col[pos] = src[e];
  }
}

// ---------------- aggregation: out[d] = in_norm[d] * sum_e out_norm[s]*h[s]
// fp32 gather, unrolled x4 for MLP (4 independent 512B row gathers in flight per wave)
__global__ void k_agg128(const float* __restrict__ h, const int* __restrict__ col,
                         const int* __restrict__ row_start,
                         const float* __restrict__ out_norm,
                         const float* __restrict__ in_norm,
                         float* __restrict__ out) {
  int wave = threadIdx.x >> 6;
  int lane = threadIdx.x & 63;
  int node = blockIdx.x * 4 + wave;
  if (node >= N_NODES) return;
  int s0 = row_start[node], s1 = row_start[node + 1];
  const float2* hp = (const float2*)h;
  float ax0 = 0.f, ay0 = 0.f, ax1 = 0.f, ay1 = 0.f;
  float ax2 = 0.f, ay2 = 0.f, ax3 = 0.f, ay3 = 0.f;
  int e = s0;
  for (; e + 4 <= s1; e += 4) {
    int sA = col[e], sB = col[e + 1], sC = col[e + 2], sD = col[e + 3];
    float wA = out_norm[sA], wB = out_norm[sB], wC = out_norm[sC], wD = out_norm[sD];
    float2 vA = hp[(size_t)sA * 64 + lane];
    float2 vB = hp[(size_t)sB * 64 + lane];
    float2 vC = hp[(size_t)sC * 64 + lane];
    float2 vD = hp[(size_t)sD * 64 + lane];
    ax0 += vA.x * wA; ay0 += vA.y * wA;
    ax1 += vB.x * wB; ay1 += vB.y * wB;
    ax2 += vC.x * wC; ay2 += vC.y * wC;
    ax3 += vD.x * wD; ay3 += vD.y * wD;
  }
  for (; e < s1; ++e) {
    int s = col[e];
    float w = out_norm[s];
    float2 v = hp[(size_t)s * 64 + lane];
    ax0 += v.x * w; ay0 += v.y * w;
  }
  float sc = in_norm[node];
  float rx = (ax0 + ax1) + (ax2 + ax3);
  float ry = (ay0 + ay1) + (ay2 + ay3);
  ((float2*)out)[(size_t)node * 64 + lane] = make_float2(rx * sc, ry * sc);
}

// ---------------- dual GEMM: Out = Xa @ Wa^T + Xh @ Wh^T  (128x128 weights, (out,in) layout)
// Safe for Out aliasing Xh: each block reads only its own 64-row tile (staged to LDS) before writing.
__launch_bounds__(256, 2)
__global__ void k_gemm_dual(const float* __restrict__ Xa, const float* __restrict__ Xh,
                            const float* __restrict__ Wa, const float* __restrict__ Wh,
                            float* __restrict__ Out) {
  __shared__ float sX[128][64];   // [k][row] 32 KB
  __shared__ float sW[64][128];   // [k-kc][j] 32 KB
  int t = threadIdx.x;
  int row0 = blockIdx.x * 64;
  int rg = t & 7;    // 8 row-groups of 8 rows
  int cg = t >> 3;   // 32 col-groups of 4 cols
  float acc[8][4];
#pragma unroll
  for (int r = 0; r < 8; ++r)
#pragma unroll
    for (int c = 0; c < 4; ++c) acc[r][c] = 0.f;

  for (int phase = 0; phase < 2; ++phase) {
    const float* X = phase ? Xh : Xa;
    const float* W = phase ? Wh : Wa;
    __syncthreads();  // previous compute done before restaging sX
    {
      int r = t & 63, kq = t >> 6;
      int row = min(row0 + r, N_NODES - 1);
      const float4* xr = (const float4*)(X + (size_t)row * 128);
#pragma unroll
      for (int it = 0; it < 8; ++it) {
        int k4 = kq * 8 + it;
        float4 v = xr[k4];
        sX[k4 * 4 + 0][r] = v.x;
        sX[k4 * 4 + 1][r] = v.y;
        sX[k4 * 4 + 2][r] = v.z;
        sX[k4 * 4 + 3][r] = v.w;
      }
    }
    for (int kc = 0; kc < 128; kc += 64) {
      __syncthreads();  // sX staged / previous sW chunk consumed
      {
        int j = t & 127, kh = t >> 7;
        const float4* wr = (const float4*)(W + (size_t)j * 128);
#pragma unroll
        for (int it = 0; it < 8; ++it) {
          int k4 = (kc >> 2) + kh * 8 + it;
          float4 v = wr[k4];
          int kk = k4 * 4 - kc;
          sW[kk + 0][j] = v.x;
          sW[kk + 1][j] = v.y;
          sW[kk + 2][j] = v.z;
          sW[kk + 3][j] = v.w;
        }
      }
      __syncthreads();
#pragma unroll 4
      for (int k = 0; k < 64; ++k) {
        float4 a0 = *(const float4*)&sX[kc + k][rg * 8];
        float4 a1 = *(const float4*)&sX[kc + k][rg * 8 + 4];
        float4 w = *(const float4*)&sW[k][cg * 4];
        float a[8] = {a0.x, a0.y, a0.z, a0.w, a1.x, a1.y, a1.z, a1.w};
        float wv[4] = {w.x, w.y, w.z, w.w};
#pragma unroll
        for (int r = 0; r < 8; ++r)
#pragma unroll
          for (int c = 0; c < 4; ++c) acc[r][c] += a[r] * wv[c];
      }
    }
  }
#pragma unroll
  for (int r = 0; r < 8; ++r) {
    int row = row0 + rg * 8 + r;
    if (row < N_NODES) {
      float4 v = make_float4(acc[r][0], acc[r][1], acc[r][2], acc[r][3]);
      *(float4*)&Out[(size_t)row * 128 + cg * 4] = v;
    }
  }
}

// ---------------- BN stats: per-column sum & sumsq ----------------
__global__ void k_stats(const float* __restrict__ x, float* stats) {
  __shared__ float ls[256], ls2[256];
  int t = threadIdx.x;
  int c = t & 127, half = t >> 7;
  int base = blockIdx.x * 128;
  float s = 0.f, s2 = 0.f;
  for (int r = half; r < 128; r += 2) {
    int row = base + r;
    if (row < N_NODES) {
      float v = x[(size_t)row * 128 + c];
      s += v;
      s2 += v * v;
    }
  }
  ls[t] = s;
  ls2[t] = s2;
  __syncthreads();
  if (half == 0) {
    s += ls[t + 128];
    s2 += ls2[t + 128];
    atomicAdd(&stats[c], s);
    atomicAdd(&stats[128 + c], s2);
  }
}

__global__ void k_bnrelu(float* __restrict__ x, const float* __restrict__ stats,
                         const float* __restrict__ g, const float* __restrict__ b) {
  int i = blockIdx.x * 256 + threadIdx.x;  // float4 index
  if (i >= N_NODES * 32) return;
  int c4 = (i & 31) * 4;
  float4 v = ((const float4*)x)[i];
  float vv[4] = {v.x, v.y, v.z, v.w};
  const float inv = 1.f / (float)N_NODES;
#pragma unroll
  for (int j = 0; j < 4; ++j) {
    int c = c4 + j;
    float mu = stats[c] * inv;
    float var = stats[128 + c] * inv - mu * mu;
    float rs = rsqrtf(var + EPS);
    float y = (vv[j] - mu) * rs * g[c] + b[c];
    vv[j] = y > 0.f ? y : 0.f;
  }
  ((float4*)x)[i] = make_float4(vv[0], vv[1], vv[2], vv[3]);
}

// ---------------- layer-2 GEMM: p = out_norm*(X@w2^T)  (stored), out = X@l2^T + b2 ----------------
__launch_bounds__(256)
__global__ void k_gemm2(const float* __restrict__ X, const float* __restrict__ w2,
                        const float* __restrict__ l2, const float* __restrict__ b2,
                        const float* __restrict__ out_norm,
                        float* __restrict__ p, float* __restrict__ out) {
  __shared__ float sX[128][32];  // 16 KB
  __shared__ float sW[128][80];  // 40 KB  cols 0..39 = w2, 40..79 = l2
  int t = threadIdx.x;
  int row0 = blockIdx.x * 32;
  {
    int r = t & 31, kq = t >> 5;
    int row = min(row0 + r, N_NODES - 1);
    const float4* xr = (const float4*)(X + (size_t)row * 128);
#pragma unroll
    for (int it = 0; it < 4; ++it) {
      int k4 = kq * 4 + it;
      float4 v = xr[k4];
      sX[k4 * 4 + 0][r] = v.x;
      sX[k4 * 4 + 1][r] = v.y;
      sX[k4 * 4 + 2][r] = v.z;
      sX[k4 * 4 + 3][r] = v.w;
    }
  }
#pragma unroll
  for (int it = 0; it < 10; ++it) {
    int i = it * 1024 + t * 4;
    int k = i & 127, j = i >> 7;
    const float* srcp = (j < 40) ? (w2 + (size_t)j * 128 + k) : (l2 + (size_t)(j - 40) * 128 + k);
    float4 v = *(const float4*)srcp;
    sW[k + 0][j] = v.x;
    sW[k + 1][j] = v.y;
    sW[k + 2][j] = v.z;
    sW[k + 3][j] = v.w;
  }
  __syncthreads();
  int cg = t & 15, rg = t >> 4;  // 16 col-groups x 5 cols, 16 row-groups x 2 rows
  float acc[2][5];
#pragma unroll
  for (int r = 0; r < 2; ++r)
#pragma unroll
    for (int i = 0; i < 5; ++i) acc[r][i] = 0.f;
  for (int k = 0; k < 128; ++k) {
    float x0 = sX[k][rg * 2];
    float x1 = sX[k][rg * 2 + 1];
    float w[5];
#pragma unroll
    for (int i = 0; i < 5; ++i) w[i] = sW[k][cg * 5 + i];
#pragma unroll
    for (int i = 0; i < 5; ++i) {
      acc[0][i] += x0 * w[i];
      acc[1][i] += x1 * w[i];
    }
  }
#pragma unroll
  for (int r = 0; r < 2; ++r) {
    int row = row0 + rg * 2 + r;
    if (row >= N_NODES) continue;
    if (cg < 8) {
      float on = out_norm[row];
#pragma unroll
      for (int i = 0; i < 5; ++i) p[(size_t)row * 40 + cg * 5 + i] = on * acc[r][i];
    } else {
      int j0 = cg * 5 - 40;
#pragma unroll
      for (int i = 0; i < 5; ++i) out[(size_t)row * 40 + j0 + i] = acc[r][i] + b2[j0 + i];
    }
  }
}

// ---------------- layer-2 aggregation: out[d] += in_norm[d] * sum_e p[src]  (unrolled x4)
__global__ void k_agg40(const float* __restrict__ p, const int* __restrict__ col,
                        const int* __restrict__ row_start,
                        const float* __restrict__ in_norm,
                        float* __restrict__ out) {
  int wave = threadIdx.x >> 6, lane = threadIdx.x & 63;
  int node = blockIdx.x * 4 + wave;
  if (node >= N_NODES) return;
  int s0 = row_start[node], s1 = row_start[node + 1];
  float a0 = 0.f, a1 = 0.f, a2 = 0.f, a3 = 0.f;
  int e = s0;
  // lanes 40..63 read in-bounds garbage (buffer is N*128 floats), masked at store
  for (; e + 4 <= s1; e += 4) {
    int sA = col[e], sB = col[e + 1], sC = col[e + 2], sD = col[e + 3];
    float vA = p[(size_t)sA * 40 + lane];
    float vB = p[(size_t)sB * 40 + lane];
    float vC = p[(size_t)sC * 40 + lane];
    float vD = p[(size_t)sD * 40 + lane];
    a0 += vA; a1 += vB; a2 += vC; a3 += vD;
  }
  for (; e < s1; ++e) {
    a0 += p[(size_t)col[e] * 40 + lane];
  }
  if (lane < 40) out[(size_t)node * 40 + lane] += in_norm[node] * ((a0 + a1) + (a2 + a3));
}

extern "C" void kernel_launch(void* const* d_in, const int* in_sizes, int n_in,
                              void* d_out, int out_size, void* d_ws, size_t ws_size,
                              hipStream_t stream) {
  const float* feat = (const float*)d_in[0];
  const int* src = (const int*)d_in[1];
  const int* dst = (const int*)d_in[2];
  const float* w0 = (const float*)d_in[3];
  const float* w1 = (const float*)d_in[4];
  const float* w2 = (const float*)d_in[5];
  const float* b2 = (const float*)d_in[6];
  const float* l0 = (const float*)d_in[7];
  const float* l1 = (const float*)d_in[8];
  const float* l2 = (const float*)d_in[9];
  const float* g0 = (const float*)d_in[10];
  const float* beta0 = (const float*)d_in[11];
  const float* g1 = (const float*)d_in[12];
  const float* beta1 = (const float*)d_in[13];
  float* out = (float*)d_out;

  char* ws = (char*)d_ws;
  size_t off = 0;
  auto alloc = [&](size_t bytes) {
    void* ptr = ws + off;
    off = (off + bytes + 255) & ~(size_t)255;
    return ptr;
  };
  float* A = (float*)alloc(sizeof(float) * (size_t)N_NODES * 128);  // agg / p
  float* B = (float*)alloc(sizeof(float) * (size_t)N_NODES * 128);  // h
  int* degs = (int*)alloc(sizeof(int) * N_NODES);
  int* degd = (int*)alloc(sizeof(int) * N_NODES);
  int* cursor = (int*)alloc(sizeof(int) * N_NODES);
  int* row_start = (int*)alloc(sizeof(int) * (N_NODES + 1));
  int* colb = (int*)alloc(sizeof(int) * N_EDGES);
  float* out_norm = (float*)alloc(sizeof(float) * N_NODES);
  float* in_norm = (float*)alloc(sizeof(float) * N_NODES);
  int* bsum = (int*)alloc(sizeof(int) * 512);
  float* stats = (float*)alloc(sizeof(float) * 256);

  hipMemsetAsync(degs, 0, sizeof(int) * N_NODES, stream);
  hipMemsetAsync(degd, 0, sizeof(int) * N_NODES, stream);
  hipMemsetAsync(cursor, 0, sizeof(int) * N_NODES, stream);

  int eb = (N_EDGES + 255) / 256;  // 6250
  int nb = (N_NODES + 255) / 256;  // 391
  k_count<<<eb, 256, 0, stream>>>(src, dst, degs, degd);
  k_norms<<<nb, 256, 0, stream>>>(degs, degd, out_norm, in_norm);
  k_scan1<<<nb, 256, 0, stream>>>(degd, bsum);
  k_scan2<<<1, 512, 0, stream>>>(bsum, nb);
  k_scan3<<<nb, 256, 0, stream>>>(degd, bsum, row_start);
  k_scatter<<<eb, 256, 0, stream>>>(src, dst, row_start, cursor, colb);

  int ab = (N_NODES + 3) / 4;  // wave per node
  int gb = (N_NODES + 63) / 64;

  // layer 0: h1 = relu(bn(agg(feat)@w0^T + feat@l0^T))
  k_agg128<<<ab, 256, 0, stream>>>(feat, colb, row_start, out_norm, in_norm, A);
  k_gemm_dual<<<gb, 256, 0, stream>>>(A, feat, w0, l0, B);
  hipMemsetAsync(stats, 0, sizeof(float) * 256, stream);
  k_stats<<<(N_NODES + 127) / 128, 256, 0, stream>>>(B, stats);
  k_bnrelu<<<(N_NODES * 32 + 255) / 256, 256, 0, stream>>>(B, stats, g0, beta0);

  // layer 1: h2 = relu(bn(agg(h1)@w1^T + h1@l1^T))   (gemm in-place on B is tile-safe)
  k_agg128<<<ab, 256, 0, stream>>>(B, colb, row_start, out_norm, in_norm, A);
  k_gemm_dual<<<gb, 256, 0, stream>>>(A, B, w1, l1, B);
  hipMemsetAsync(stats, 0, sizeof(float) * 256, stream);
  k_stats<<<(N_NODES + 127) / 128, 256, 0, stream>>>(B, stats);
  k_bnrelu<<<(N_NODES * 32 + 255) / 256, 256, 0, stream>>>(B, stats, g1, beta1);

  // layer 2: out = in_norm*agg(out_norm*(h2@w2^T)) + b2 + h2@l2^T
  k_gemm2<<<(N_NODES + 31) / 32, 256, 0, stream>>>(B, w2, l2, b2, out_norm, A, out);
  k_agg40<<<ab, 256, 0, stream>>>(A, colb, row_start, in_norm, out);
}

// Round 4
// 1015.185 us; speedup vs baseline: 1.2188x; 1.0620x over previous
//
#include <hip/hip_runtime.h>
#include <cstdint>
#include <cstddef>

#define N_NODES 100000
#define N_EDGES 1600000
#define EPS 1e-5f

// ---------------- graph prep ----------------
// Pass 1: degree histograms; atomic return on degd gives each edge its
// within-destination-row rank (stored), making the scatter pass atomic-free.
__global__ void k_count(const int4* __restrict__ src4, const int4* __restrict__ dst4,
                        int* degs, int* degd, int4* __restrict__ rank4) {
  int i = blockIdx.x * 256 + threadIdx.x;
  if (i >= N_EDGES / 4) return;
  int4 s = src4[i];
  int4 d = dst4[i];
  int4 r;
  r.x = atomicAdd(&degd[d.x], 1);
  r.y = atomicAdd(&degd[d.y], 1);
  r.z = atomicAdd(&degd[d.z], 1);
  r.w = atomicAdd(&degd[d.w], 1);
  atomicAdd(&degs[s.x], 1);
  atomicAdd(&degs[s.y], 1);
  atomicAdd(&degs[s.z], 1);
  atomicAdd(&degs[s.w], 1);
  rank4[i] = r;
}

__global__ void k_norms(const int* __restrict__ degs, const int* __restrict__ degd,
                        float* out_norm, float* in_norm) {
  int i = blockIdx.x * 256 + threadIdx.x;
  if (i < N_NODES) {
    out_norm[i] = rsqrtf((float)max(degs[i], 1));
    in_norm[i]  = rsqrtf((float)max(degd[i], 1));
  }
}

__global__ void k_scan1(const int* __restrict__ degd, int* bsum) {
  __shared__ int s[256];
  int t = threadIdx.x;
  int i = blockIdx.x * 256 + t;
  s[t] = (i < N_NODES) ? degd[i] : 0;
  __syncthreads();
  for (int off = 128; off > 0; off >>= 1) {
    if (t < off) s[t] += s[t + off];
    __syncthreads();
  }
  if (t == 0) bsum[blockIdx.x] = s[0];
}

__global__ void k_scan2(int* bsum, int nb) {
  __shared__ int s[512];
  int t = threadIdx.x;
  int v = (t < nb) ? bsum[t] : 0;
  s[t] = v;
  __syncthreads();
  for (int off = 1; off < 512; off <<= 1) {
    int x = (t >= off) ? s[t - off] : 0;
    __syncthreads();
    s[t] += x;
    __syncthreads();
  }
  if (t < nb) bsum[t] = s[t] - v;  // exclusive
}

__global__ void k_scan3(const int* __restrict__ degd, const int* __restrict__ bsum,
                        int* row_start) {
  __shared__ int s[256];
  int t = threadIdx.x;
  int i = blockIdx.x * 256 + t;
  int v = (i < N_NODES) ? degd[i] : 0;
  s[t] = v;
  __syncthreads();
  for (int off = 1; off < 256; off <<= 1) {
    int x = (t >= off) ? s[t - off] : 0;
    __syncthreads();
    s[t] += x;
    __syncthreads();
  }
  if (i < N_NODES) row_start[i] = bsum[blockIdx.x] + s[t] - v;
  if (i == 0) row_start[N_NODES] = N_EDGES;
}

// Pass 2: atomic-free CSR scatter using precomputed ranks.
__global__ void k_scatter(const int4* __restrict__ src4, const int4* __restrict__ dst4,
                          const int4* __restrict__ rank4,
                          const int* __restrict__ row_start, int* __restrict__ col) {
  int i = blockIdx.x * 256 + threadIdx.x;
  if (i >= N_EDGES / 4) return;
  int4 s = src4[i];
  int4 d = dst4[i];
  int4 r = rank4[i];
  col[row_start[d.x] + r.x] = s.x;
  col[row_start[d.y] + r.y] = s.y;
  col[row_start[d.z] + r.z] = s.z;
  col[row_start[d.w] + r.w] = s.w;
}

// ---------------- aggregation: out[d] = in_norm[d] * sum_e out_norm[s]*h[s]
// fp32 gather, unrolled x4 for MLP (4 independent 512B row gathers in flight per wave)
__global__ void k_agg128(const float* __restrict__ h, const int* __restrict__ col,
                         const int* __restrict__ row_start,
                         const float* __restrict__ out_norm,
                         const float* __restrict__ in_norm,
                         float* __restrict__ out) {
  int wave = threadIdx.x >> 6;
  int lane = threadIdx.x & 63;
  int node = blockIdx.x * 4 + wave;
  if (node >= N_NODES) return;
  int s0 = row_start[node], s1 = row_start[node + 1];
  const float2* hp = (const float2*)h;
  float ax0 = 0.f, ay0 = 0.f, ax1 = 0.f, ay1 = 0.f;
  float ax2 = 0.f, ay2 = 0.f, ax3 = 0.f, ay3 = 0.f;
  int e = s0;
  for (; e + 4 <= s1; e += 4) {
    int sA = col[e], sB = col[e + 1], sC = col[e + 2], sD = col[e + 3];
    float wA = out_norm[sA], wB = out_norm[sB], wC = out_norm[sC], wD = out_norm[sD];
    float2 vA = hp[(size_t)sA * 64 + lane];
    float2 vB = hp[(size_t)sB * 64 + lane];
    float2 vC = hp[(size_t)sC * 64 + lane];
    float2 vD = hp[(size_t)sD * 64 + lane];
    ax0 += vA.x * wA; ay0 += vA.y * wA;
    ax1 += vB.x * wB; ay1 += vB.y * wB;
    ax2 += vC.x * wC; ay2 += vC.y * wC;
    ax3 += vD.x * wD; ay3 += vD.y * wD;
  }
  for (; e < s1; ++e) {
    int s = col[e];
    float w = out_norm[s];
    float2 v = hp[(size_t)s * 64 + lane];
    ax0 += v.x * w; ay0 += v.y * w;
  }
  float sc = in_norm[node];
  float rx = (ax0 + ax1) + (ax2 + ax3);
  float ry = (ay0 + ay1) + (ay2 + ay3);
  ((float2*)out)[(size_t)node * 64 + lane] = make_float2(rx * sc, ry * sc);
}

// ---------------- dual GEMM: Out = Xa @ Wa^T + Xh @ Wh^T  (128x128 weights, (out,in) layout)
// Safe for Out aliasing Xh: each block reads only its own 64-row tile (staged to LDS) before writing.
__launch_bounds__(256, 2)
__global__ void k_gemm_dual(const float* __restrict__ Xa, const float* __restrict__ Xh,
                            const float* __restrict__ Wa, const float* __restrict__ Wh,
                            float* __restrict__ Out) {
  __shared__ float sX[128][64];   // [k][row] 32 KB
  __shared__ float sW[64][128];   // [k-kc][j] 32 KB
  int t = threadIdx.x;
  int row0 = blockIdx.x * 64;
  int rg = t & 7;    // 8 row-groups of 8 rows
  int cg = t >> 3;   // 32 col-groups of 4 cols
  float acc[8][4];
#pragma unroll
  for (int r = 0; r < 8; ++r)
#pragma unroll
    for (int c = 0; c < 4; ++c) acc[r][c] = 0.f;

  for (int phase = 0; phase < 2; ++phase) {
    const float* X = phase ? Xh : Xa;
    const float* W = phase ? Wh : Wa;
    __syncthreads();  // previous compute done before restaging sX
    {
      int r = t & 63, kq = t >> 6;
      int row = min(row0 + r, N_NODES - 1);
      const float4* xr = (const float4*)(X + (size_t)row * 128);
#pragma unroll
      for (int it = 0; it < 8; ++it) {
        int k4 = kq * 8 + it;
        float4 v = xr[k4];
        sX[k4 * 4 + 0][r] = v.x;
        sX[k4 * 4 + 1][r] = v.y;
        sX[k4 * 4 + 2][r] = v.z;
        sX[k4 * 4 + 3][r] = v.w;
      }
    }
    for (int kc = 0; kc < 128; kc += 64) {
      __syncthreads();  // sX staged / previous sW chunk consumed
      {
        int j = t & 127, kh = t >> 7;
        const float4* wr = (const float4*)(W + (size_t)j * 128);
#pragma unroll
        for (int it = 0; it < 8; ++it) {
          int k4 = (kc >> 2) + kh * 8 + it;
          float4 v = wr[k4];
          int kk = k4 * 4 - kc;
          sW[kk + 0][j] = v.x;
          sW[kk + 1][j] = v.y;
          sW[kk + 2][j] = v.z;
          sW[kk + 3][j] = v.w;
        }
      }
      __syncthreads();
#pragma unroll 4
      for (int k = 0; k < 64; ++k) {
        float4 a0 = *(const float4*)&sX[kc + k][rg * 8];
        float4 a1 = *(const float4*)&sX[kc + k][rg * 8 + 4];
        float4 w = *(const float4*)&sW[k][cg * 4];
        float a[8] = {a0.x, a0.y, a0.z, a0.w, a1.x, a1.y, a1.z, a1.w};
        float wv[4] = {w.x, w.y, w.z, w.w};
#pragma unroll
        for (int r = 0; r < 8; ++r)
#pragma unroll
          for (int c = 0; c < 4; ++c) acc[r][c] += a[r] * wv[c];
      }
    }
  }
#pragma unroll
  for (int r = 0; r < 8; ++r) {
    int row = row0 + rg * 8 + r;
    if (row < N_NODES) {
      float4 v = make_float4(acc[r][0], acc[r][1], acc[r][2], acc[r][3]);
      *(float4*)&Out[(size_t)row * 128 + cg * 4] = v;
    }
  }
}

// ---------------- BN stats: per-column sum & sumsq ----------------
__global__ void k_stats(const float* __restrict__ x, float* stats) {
  __shared__ float ls[256], ls2[256];
  int t = threadIdx.x;
  int c = t & 127, half = t >> 7;
  int base = blockIdx.x * 128;
  float s = 0.f, s2 = 0.f;
  for (int r = half; r < 128; r += 2) {
    int row = base + r;
    if (row < N_NODES) {
      float v = x[(size_t)row * 128 + c];
      s += v;
      s2 += v * v;
    }
  }
  ls[t] = s;
  ls2[t] = s2;
  __syncthreads();
  if (half == 0) {
    s += ls[t + 128];
    s2 += ls2[t + 128];
    atomicAdd(&stats[c], s);
    atomicAdd(&stats[128 + c], s2);
  }
}

__global__ void k_bnrelu(float* __restrict__ x, const float* __restrict__ stats,
                         const float* __restrict__ g, const float* __restrict__ b) {
  int i = blockIdx.x * 256 + threadIdx.x;  // float4 index
  if (i >= N_NODES * 32) return;
  int c4 = (i & 31) * 4;
  float4 v = ((const float4*)x)[i];
  float vv[4] = {v.x, v.y, v.z, v.w};
  const float inv = 1.f / (float)N_NODES;
#pragma unroll
  for (int j = 0; j < 4; ++j) {
    int c = c4 + j;
    float mu = stats[c] * inv;
    float var = stats[128 + c] * inv - mu * mu;
    float rs = rsqrtf(var + EPS);
    float y = (vv[j] - mu) * rs * g[c] + b[c];
    vv[j] = y > 0.f ? y : 0.f;
  }
  ((float4*)x)[i] = make_float4(vv[0], vv[1], vv[2], vv[3]);
}

// ---------------- layer-2 GEMM: p = out_norm*(X@w2^T)  (stored), out = X@l2^T + b2 ----------------
__launch_bounds__(256)
__global__ void k_gemm2(const float* __restrict__ X, const float* __restrict__ w2,
                        const float* __restrict__ l2, const float* __restrict__ b2,
                        const float* __restrict__ out_norm,
                        float* __restrict__ p, float* __restrict__ out) {
  __shared__ float sX[128][32];  // 16 KB
  __shared__ float sW[128][80];  // 40 KB  cols 0..39 = w2, 40..79 = l2
  int t = threadIdx.x;
  int row0 = blockIdx.x * 32;
  {
    int r = t & 31, kq = t >> 5;
    int row = min(row0 + r, N_NODES - 1);
    const float4* xr = (const float4*)(X + (size_t)row * 128);
#pragma unroll
    for (int it = 0; it < 4; ++it) {
      int k4 = kq * 4 + it;
      float4 v = xr[k4];
      sX[k4 * 4 + 0][r] = v.x;
      sX[k4 * 4 + 1][r] = v.y;
      sX[k4 * 4 + 2][r] = v.z;
      sX[k4 * 4 + 3][r] = v.w;
    }
  }
#pragma unroll
  for (int it = 0; it < 10; ++it) {
    int i = it * 1024 + t * 4;
    int k = i & 127, j = i >> 7;
    const float* srcp = (j < 40) ? (w2 + (size_t)j * 128 + k) : (l2 + (size_t)(j - 40) * 128 + k);
    float4 v = *(const float4*)srcp;
    sW[k + 0][j] = v.x;
    sW[k + 1][j] = v.y;
    sW[k + 2][j] = v.z;
    sW[k + 3][j] = v.w;
  }
  __syncthreads();
  int cg = t & 15, rg = t >> 4;  // 16 col-groups x 5 cols, 16 row-groups x 2 rows
  float acc[2][5];
#pragma unroll
  for (int r = 0; r < 2; ++r)
#pragma unroll
    for (int i = 0; i < 5; ++i) acc[r][i] = 0.f;
  for (int k = 0; k < 128; ++k) {
    float x0 = sX[k][rg * 2];
    float x1 = sX[k][rg * 2 + 1];
    float w[5];
#pragma unroll
    for (int i = 0; i < 5; ++i) w[i] = sW[k][cg * 5 + i];
#pragma unroll
    for (int i = 0; i < 5; ++i) {
      acc[0][i] += x0 * w[i];
      acc[1][i] += x1 * w[i];
    }
  }
#pragma unroll
  for (int r = 0; r < 2; ++r) {
    int row = row0 + rg * 2 + r;
    if (row >= N_NODES) continue;
    if (cg < 8) {
      float on = out_norm[row];
#pragma unroll
      for (int i = 0; i < 5; ++i) p[(size_t)row * 40 + cg * 5 + i] = on * acc[r][i];
    } else {
      int j0 = cg * 5 - 40;
#pragma unroll
      for (int i = 0; i < 5; ++i) out[(size_t)row * 40 + j0 + i] = acc[r][i] + b2[j0 + i];
    }
  }
}

// ---------------- layer-2 aggregation: out[d] += in_norm[d] * sum_e p[src]  (unrolled x4)
__global__ void k_agg40(const float* __restrict__ p, const int* __restrict__ col,
                        const int* __restrict__ row_start,
                        const float* __restrict__ in_norm,
                        float* __restrict__ out) {
  int wave = threadIdx.x >> 6, lane = threadIdx.x & 63;
  int node = blockIdx.x * 4 + wave;
  if (node >= N_NODES) return;
  int s0 = row_start[node], s1 = row_start[node + 1];
  float a0 = 0.f, a1 = 0.f, a2 = 0.f, a3 = 0.f;
  int e = s0;
  // lanes 40..63 read in-bounds garbage (buffer is N*128 floats), masked at store
  for (; e + 4 <= s1; e += 4) {
    int sA = col[e], sB = col[e + 1], sC = col[e + 2], sD = col[e + 3];
    float vA = p[(size_t)sA * 40 + lane];
    float vB = p[(size_t)sB * 40 + lane];
    float vC = p[(size_t)sC * 40 + lane];
    float vD = p[(size_t)sD * 40 + lane];
    a0 += vA; a1 += vB; a2 += vC; a3 += vD;
  }
  for (; e < s1; ++e) {
    a0 += p[(size_t)col[e] * 40 + lane];
  }
  if (lane < 40) out[(size_t)node * 40 + lane] += in_norm[node] * ((a0 + a1) + (a2 + a3));
}

extern "C" void kernel_launch(void* const* d_in, const int* in_sizes, int n_in,
                              void* d_out, int out_size, void* d_ws, size_t ws_size,
                              hipStream_t stream) {
  const float* feat = (const float*)d_in[0];
  const int* src = (const int*)d_in[1];
  const int* dst = (const int*)d_in[2];
  const float* w0 = (const float*)d_in[3];
  const float* w1 = (const float*)d_in[4];
  const float* w2 = (const float*)d_in[5];
  const float* b2 = (const float*)d_in[6];
  const float* l0 = (const float*)d_in[7];
  const float* l1 = (const float*)d_in[8];
  const float* l2 = (const float*)d_in[9];
  const float* g0 = (const float*)d_in[10];
  const float* beta0 = (const float*)d_in[11];
  const float* g1 = (const float*)d_in[12];
  const float* beta1 = (const float*)d_in[13];
  float* out = (float*)d_out;

  char* ws = (char*)d_ws;
  size_t off = 0;
  auto alloc = [&](size_t bytes) {
    void* ptr = ws + off;
    off = (off + bytes + 255) & ~(size_t)255;
    return ptr;
  };
  float* A = (float*)alloc(sizeof(float) * (size_t)N_NODES * 128);  // agg / p
  float* B = (float*)alloc(sizeof(float) * (size_t)N_NODES * 128);  // h
  int* degs = (int*)alloc(sizeof(int) * N_NODES);
  int* degd = (int*)alloc(sizeof(int) * N_NODES);
  int* rank = (int*)alloc(sizeof(int) * N_EDGES);
  int* row_start = (int*)alloc(sizeof(int) * (N_NODES + 1));
  int* colb = (int*)alloc(sizeof(int) * N_EDGES);
  float* out_norm = (float*)alloc(sizeof(float) * N_NODES);
  float* in_norm = (float*)alloc(sizeof(float) * N_NODES);
  int* bsum = (int*)alloc(sizeof(int) * 512);
  float* stats = (float*)alloc(sizeof(float) * 256);

  hipMemsetAsync(degs, 0, sizeof(int) * N_NODES, stream);
  hipMemsetAsync(degd, 0, sizeof(int) * N_NODES, stream);

  int eb4 = (N_EDGES / 4 + 255) / 256;  // 1563
  int nb = (N_NODES + 255) / 256;       // 391
  k_count<<<eb4, 256, 0, stream>>>((const int4*)src, (const int4*)dst, degs, degd, (int4*)rank);
  k_norms<<<nb, 256, 0, stream>>>(degs, degd, out_norm, in_norm);
  k_scan1<<<nb, 256, 0, stream>>>(degd, bsum);
  k_scan2<<<1, 512, 0, stream>>>(bsum, nb);
  k_scan3<<<nb, 256, 0, stream>>>(degd, bsum, row_start);
  k_scatter<<<eb4, 256, 0, stream>>>((const int4*)src, (const int4*)dst, (const int4*)rank,
                                     row_start, colb);

  int ab = (N_NODES + 3) / 4;  // wave per node
  int gb = (N_NODES + 63) / 64;

  // layer 0: h1 = relu(bn(agg(feat)@w0^T + feat@l0^T))
  k_agg128<<<ab, 256, 0, stream>>>(feat, colb, row_start, out_norm, in_norm, A);
  k_gemm_dual<<<gb, 256, 0, stream>>>(A, feat, w0, l0, B);
  hipMemsetAsync(stats, 0, sizeof(float) * 256, stream);
  k_stats<<<(N_NODES + 127) / 128, 256, 0, stream>>>(B, stats);
  k_bnrelu<<<(N_NODES * 32 + 255) / 256, 256, 0, stream>>>(B, stats, g0, beta0);

  // layer 1: h2 = relu(bn(agg(h1)@w1^T + h1@l1^T))   (gemm in-place on B is tile-safe)
  k_agg128<<<ab, 256, 0, stream>>>(B, colb, row_start, out_norm, in_norm, A);
  k_gemm_dual<<<gb, 256, 0, stream>>>(A, B, w1, l1, B);
  hipMemsetAsync(stats, 0, sizeof(float) * 256, stream);
  k_stats<<<(N_NODES + 127) / 128, 256, 0, stream>>>(B, stats);
  k_bnrelu<<<(N_NODES * 32 + 255) / 256, 256, 0, stream>>>(B, stats, g1, beta1);

  // layer 2: out = in_norm*agg(out_norm*(h2@w2^T)) + b2 + h2@l2^T
  k_gemm2<<<(N_NODES + 31) / 32, 256, 0, stream>>>(B, w2, l2, b2, out_norm, A, out);
  k_agg40<<<ab, 256, 0, stream>>>(A, colb, row_start, in_norm, out);
}

// Round 5
// 943.177 us; speedup vs baseline: 1.3119x; 1.0763x over previous
//
#include <hip/hip_runtime.h>
#include <hip/hip_fp16.h>
#include <cstdint>
#include <cstddef>

#define N_NODES 100000
#define N_EDGES 1600000
#define EPS 1e-5f

// ---------------- graph prep ----------------
// Pass 1: degree histograms, scalar 1-thread/edge (max wave parallelism for atomics).
// atomicAdd return on degd gives each edge its within-row rank -> atomic-free scatter.
__global__ void k_count(const int* __restrict__ src, const int* __restrict__ dst,
                        int* degs, int* degd, int* __restrict__ rank) {
  int e = blockIdx.x * 256 + threadIdx.x;
  if (e < N_EDGES) {
    atomicAdd(&degs[src[e]], 1);
    rank[e] = atomicAdd(&degd[dst[e]], 1);
  }
}

__global__ void k_norms(const int* __restrict__ degs, const int* __restrict__ degd,
                        float* out_norm, float* in_norm) {
  int i = blockIdx.x * 256 + threadIdx.x;
  if (i < N_NODES) {
    out_norm[i] = rsqrtf((float)max(degs[i], 1));
    in_norm[i]  = rsqrtf((float)max(degd[i], 1));
  }
}

__global__ void k_scan1(const int* __restrict__ degd, int* bsum) {
  __shared__ int s[256];
  int t = threadIdx.x;
  int i = blockIdx.x * 256 + t;
  s[t] = (i < N_NODES) ? degd[i] : 0;
  __syncthreads();
  for (int off = 128; off > 0; off >>= 1) {
    if (t < off) s[t] += s[t + off];
    __syncthreads();
  }
  if (t == 0) bsum[blockIdx.x] = s[0];
}

__global__ void k_scan2(int* bsum, int nb) {
  __shared__ int s[512];
  int t = threadIdx.x;
  int v = (t < nb) ? bsum[t] : 0;
  s[t] = v;
  __syncthreads();
  for (int off = 1; off < 512; off <<= 1) {
    int x = (t >= off) ? s[t - off] : 0;
    __syncthreads();
    s[t] += x;
    __syncthreads();
  }
  if (t < nb) bsum[t] = s[t] - v;  // exclusive
}

__global__ void k_scan3(const int* __restrict__ degd, const int* __restrict__ bsum,
                        int* row_start) {
  __shared__ int s[256];
  int t = threadIdx.x;
  int i = blockIdx.x * 256 + t;
  int v = (i < N_NODES) ? degd[i] : 0;
  s[t] = v;
  __syncthreads();
  for (int off = 1; off < 256; off <<= 1) {
    int x = (t >= off) ? s[t - off] : 0;
    __syncthreads();
    s[t] += x;
    __syncthreads();
  }
  if (i < N_NODES) row_start[i] = bsum[blockIdx.x] + s[t] - v;
  if (i == 0) row_start[N_NODES] = N_EDGES;
}

// Pass 2: atomic-free CSR scatter using precomputed ranks (int4 = 4 edges/thread).
__global__ void k_scatter(const int4* __restrict__ src4, const int4* __restrict__ dst4,
                          const int4* __restrict__ rank4,
                          const int* __restrict__ row_start, int* __restrict__ col) {
  int i = blockIdx.x * 256 + threadIdx.x;
  if (i >= N_EDGES / 4) return;
  int4 s = src4[i];
  int4 d = dst4[i];
  int4 r = rank4[i];
  col[row_start[d.x] + r.x] = s.x;
  col[row_start[d.y] + r.y] = s.y;
  col[row_start[d.z] + r.z] = s.z;
  col[row_start[d.w] + r.w] = s.w;
}

// ---------------- feat -> fp16 gather table (out_norm folded) ----------------
__global__ void k_feat2h(const float* __restrict__ feat, const float* __restrict__ out_norm,
                         __half* __restrict__ H) {
  int i = blockIdx.x * 256 + threadIdx.x;  // float4 index
  if (i >= N_NODES * 32) return;
  float on = out_norm[i >> 5];
  float4 v = ((const float4*)feat)[i];
  ushort4 o;
  o.x = __half_as_ushort(__float2half_rn(v.x * on));
  o.y = __half_as_ushort(__float2half_rn(v.y * on));
  o.z = __half_as_ushort(__float2half_rn(v.z * on));
  o.w = __half_as_ushort(__float2half_rn(v.w * on));
  ((ushort4*)H)[i] = o;
}

// ---------------- aggregation (fp16 gather): out[d] = in_norm[d] * sum_e H[src]
// H rows pre-scaled by out_norm. Row = 128 halves = 256B; lane loads 1 uint (2 halves).
__global__ void k_agg128h(const __half* __restrict__ H, const int* __restrict__ col,
                          const int* __restrict__ row_start,
                          const float* __restrict__ in_norm,
                          float* __restrict__ out) {
  int wave = threadIdx.x >> 6;
  int lane = threadIdx.x & 63;
  int node = blockIdx.x * 4 + wave;
  if (node >= N_NODES) return;
  int s0 = row_start[node], s1 = row_start[node + 1];
  const unsigned int* hp = (const unsigned int*)H;
  float ax0 = 0.f, ay0 = 0.f, ax1 = 0.f, ay1 = 0.f;
  float ax2 = 0.f, ay2 = 0.f, ax3 = 0.f, ay3 = 0.f;
  int e = s0;
  for (; e + 4 <= s1; e += 4) {
    int sA = col[e], sB = col[e + 1], sC = col[e + 2], sD = col[e + 3];
    unsigned int uA = hp[(size_t)sA * 64 + lane];
    unsigned int uB = hp[(size_t)sB * 64 + lane];
    unsigned int uC = hp[(size_t)sC * 64 + lane];
    unsigned int uD = hp[(size_t)sD * 64 + lane];
    float2 vA = __half22float2(*(const __half2*)&uA);
    float2 vB = __half22float2(*(const __half2*)&uB);
    float2 vC = __half22float2(*(const __half2*)&uC);
    float2 vD = __half22float2(*(const __half2*)&uD);
    ax0 += vA.x; ay0 += vA.y;
    ax1 += vB.x; ay1 += vB.y;
    ax2 += vC.x; ay2 += vC.y;
    ax3 += vD.x; ay3 += vD.y;
  }
  for (; e < s1; ++e) {
    unsigned int u = hp[(size_t)col[e] * 64 + lane];
    float2 v = __half22float2(*(const __half2*)&u);
    ax0 += v.x; ay0 += v.y;
  }
  float sc = in_norm[node];
  float rx = (ax0 + ax1) + (ax2 + ax3);
  float ry = (ay0 + ay1) + (ay2 + ay3);
  ((float2*)out)[(size_t)node * 64 + lane] = make_float2(rx * sc, ry * sc);
}

// ---------------- dual GEMM: Out = Xa @ Wa^T + Xh @ Wh^T  (128x128 weights, (out,in) layout)
// Safe for Out aliasing Xh: each block reads only its own 64-row tile (staged to LDS) before writing.
__launch_bounds__(256, 2)
__global__ void k_gemm_dual(const float* __restrict__ Xa, const float* __restrict__ Xh,
                            const float* __restrict__ Wa, const float* __restrict__ Wh,
                            float* __restrict__ Out) {
  __shared__ float sX[128][64];   // [k][row] 32 KB
  __shared__ float sW[64][128];   // [k-kc][j] 32 KB
  int t = threadIdx.x;
  int row0 = blockIdx.x * 64;
  int rg = t & 7;    // 8 row-groups of 8 rows
  int cg = t >> 3;   // 32 col-groups of 4 cols
  float acc[8][4];
#pragma unroll
  for (int r = 0; r < 8; ++r)
#pragma unroll
    for (int c = 0; c < 4; ++c) acc[r][c] = 0.f;

  for (int phase = 0; phase < 2; ++phase) {
    const float* X = phase ? Xh : Xa;
    const float* W = phase ? Wh : Wa;
    __syncthreads();  // previous compute done before restaging sX
    {
      int r = t & 63, kq = t >> 6;
      int row = min(row0 + r, N_NODES - 1);
      const float4* xr = (const float4*)(X + (size_t)row * 128);
#pragma unroll
      for (int it = 0; it < 8; ++it) {
        int k4 = kq * 8 + it;
        float4 v = xr[k4];
        sX[k4 * 4 + 0][r] = v.x;
        sX[k4 * 4 + 1][r] = v.y;
        sX[k4 * 4 + 2][r] = v.z;
        sX[k4 * 4 + 3][r] = v.w;
      }
    }
    for (int kc = 0; kc < 128; kc += 64) {
      __syncthreads();  // sX staged / previous sW chunk consumed
      {
        int j = t & 127, kh = t >> 7;
        const float4* wr = (const float4*)(W + (size_t)j * 128);
#pragma unroll
        for (int it = 0; it < 8; ++it) {
          int k4 = (kc >> 2) + kh * 8 + it;
          float4 v = wr[k4];
          int kk = k4 * 4 - kc;
          sW[kk + 0][j] = v.x;
          sW[kk + 1][j] = v.y;
          sW[kk + 2][j] = v.z;
          sW[kk + 3][j] = v.w;
        }
      }
      __syncthreads();
#pragma unroll 4
      for (int k = 0; k < 64; ++k) {
        float4 a0 = *(const float4*)&sX[kc + k][rg * 8];
        float4 a1 = *(const float4*)&sX[kc + k][rg * 8 + 4];
        float4 w = *(const float4*)&sW[k][cg * 4];
        float a[8] = {a0.x, a0.y, a0.z, a0.w, a1.x, a1.y, a1.z, a1.w};
        float wv[4] = {w.x, w.y, w.z, w.w};
#pragma unroll
        for (int r = 0; r < 8; ++r)
#pragma unroll
          for (int c = 0; c < 4; ++c) acc[r][c] += a[r] * wv[c];
      }
    }
  }
#pragma unroll
  for (int r = 0; r < 8; ++r) {
    int row = row0 + rg * 8 + r;
    if (row < N_NODES) {
      float4 v = make_float4(acc[r][0], acc[r][1], acc[r][2], acc[r][3]);
      *(float4*)&Out[(size_t)row * 128 + cg * 4] = v;
    }
  }
}

// ---------------- BN stats: per-column sum & sumsq ----------------
__global__ void k_stats(const float* __restrict__ x, float* stats) {
  __shared__ float ls[256], ls2[256];
  int t = threadIdx.x;
  int c = t & 127, half = t >> 7;
  int base = blockIdx.x * 128;
  float s = 0.f, s2 = 0.f;
  for (int r = half; r < 128; r += 2) {
    int row = base + r;
    if (row < N_NODES) {
      float v = x[(size_t)row * 128 + c];
      s += v;
      s2 += v * v;
    }
  }
  ls[t] = s;
  ls2[t] = s2;
  __syncthreads();
  if (half == 0) {
    s += ls[t + 128];
    s2 += ls2[t + 128];
    atomicAdd(&stats[c], s);
    atomicAdd(&stats[128 + c], s2);
  }
}

// BN+ReLU in-place; optionally emit fp16 gather table (out_norm folded) for next agg.
__global__ void k_bnrelu(float* __restrict__ x, const float* __restrict__ stats,
                         const float* __restrict__ g, const float* __restrict__ b,
                         const float* __restrict__ out_norm, __half* __restrict__ H) {
  int i = blockIdx.x * 256 + threadIdx.x;  // float4 index
  if (i >= N_NODES * 32) return;
  int c4 = (i & 31) * 4;
  float4 v = ((const float4*)x)[i];
  float vv[4] = {v.x, v.y, v.z, v.w};
  const float inv = 1.f / (float)N_NODES;
#pragma unroll
  for (int j = 0; j < 4; ++j) {
    int c = c4 + j;
    float mu = stats[c] * inv;
    float var = stats[128 + c] * inv - mu * mu;
    float rs = rsqrtf(var + EPS);
    float y = (vv[j] - mu) * rs * g[c] + b[c];
    vv[j] = y > 0.f ? y : 0.f;
  }
  ((float4*)x)[i] = make_float4(vv[0], vv[1], vv[2], vv[3]);
  if (H) {
    float on = out_norm[i >> 5];
    ushort4 o;
    o.x = __half_as_ushort(__float2half_rn(vv[0] * on));
    o.y = __half_as_ushort(__float2half_rn(vv[1] * on));
    o.z = __half_as_ushort(__float2half_rn(vv[2] * on));
    o.w = __half_as_ushort(__float2half_rn(vv[3] * on));
    ((ushort4*)H)[i] = o;
  }
}

// ---------------- layer-2 GEMM: p = fp16(out_norm*(X@w2^T)), out = X@l2^T + b2 ----------------
__launch_bounds__(256)
__global__ void k_gemm2(const float* __restrict__ X, const float* __restrict__ w2,
                        const float* __restrict__ l2, const float* __restrict__ b2,
                        const float* __restrict__ out_norm,
                        __half* __restrict__ p, float* __restrict__ out) {
  __shared__ float sX[128][32];  // 16 KB
  __shared__ float sW[128][80];  // 40 KB  cols 0..39 = w2, 40..79 = l2
  int t = threadIdx.x;
  int row0 = blockIdx.x * 32;
  {
    int r = t & 31, kq = t >> 5;
    int row = min(row0 + r, N_NODES - 1);
    const float4* xr = (const float4*)(X + (size_t)row * 128);
#pragma unroll
    for (int it = 0; it < 4; ++it) {
      int k4 = kq * 4 + it;
      float4 v = xr[k4];
      sX[k4 * 4 + 0][r] = v.x;
      sX[k4 * 4 + 1][r] = v.y;
      sX[k4 * 4 + 2][r] = v.z;
      sX[k4 * 4 + 3][r] = v.w;
    }
  }
#pragma unroll
  for (int it = 0; it < 10; ++it) {
    int i = it * 1024 + t * 4;
    int k = i & 127, j = i >> 7;
    const float* srcp = (j < 40) ? (w2 + (size_t)j * 128 + k) : (l2 + (size_t)(j - 40) * 128 + k);
    float4 v = *(const float4*)srcp;
    sW[k + 0][j] = v.x;
    sW[k + 1][j] = v.y;
    sW[k + 2][j] = v.z;
    sW[k + 3][j] = v.w;
  }
  __syncthreads();
  int cg = t & 15, rg = t >> 4;  // 16 col-groups x 5 cols, 16 row-groups x 2 rows
  float acc[2][5];
#pragma unroll
  for (int r = 0; r < 2; ++r)
#pragma unroll
    for (int i = 0; i < 5; ++i) acc[r][i] = 0.f;
  for (int k = 0; k < 128; ++k) {
    float x0 = sX[k][rg * 2];
    float x1 = sX[k][rg * 2 + 1];
    float w[5];
#pragma unroll
    for (int i = 0; i < 5; ++i) w[i] = sW[k][cg * 5 + i];
#pragma unroll
    for (int i = 0; i < 5; ++i) {
      acc[0][i] += x0 * w[i];
      acc[1][i] += x1 * w[i];
    }
  }
#pragma unroll
  for (int r = 0; r < 2; ++r) {
    int row = row0 + rg * 2 + r;
    if (row >= N_NODES) continue;
    if (cg < 8) {
      float on = out_norm[row];
#pragma unroll
      for (int i = 0; i < 5; ++i)
        p[(size_t)row * 40 + cg * 5 + i] = __float2half_rn(on * acc[r][i]);
    } else {
      int j0 = cg * 5 - 40;
#pragma unroll
      for (int i = 0; i < 5; ++i) out[(size_t)row * 40 + j0 + i] = acc[r][i] + b2[j0 + i];
    }
  }
}

// ---------------- layer-2 aggregation (fp16 gather): out[d] += in_norm[d] * sum_e p[src]
__global__ void k_agg40h(const __half* __restrict__ p, const int* __restrict__ col,
                         const int* __restrict__ row_start,
                         const float* __restrict__ in_norm,
                         float* __restrict__ out) {
  int wave = threadIdx.x >> 6, lane = threadIdx.x & 63;
  int node = blockIdx.x * 4 + wave;
  if (node >= N_NODES) return;
  int s0 = row_start[node], s1 = row_start[node + 1];
  float a0 = 0.f, a1 = 0.f, a2 = 0.f, a3 = 0.f;
  int e = s0;
  // lanes 40..63 read in-bounds garbage (buffer is N*128 floats reinterpreted), masked at store
  for (; e + 4 <= s1; e += 4) {
    int sA = col[e], sB = col[e + 1], sC = col[e + 2], sD = col[e + 3];
    float vA = __half2float(p[(size_t)sA * 40 + lane]);
    float vB = __half2float(p[(size_t)sB * 40 + lane]);
    float vC = __half2float(p[(size_t)sC * 40 + lane]);
    float vD = __half2float(p[(size_t)sD * 40 + lane]);
    a0 += vA; a1 += vB; a2 += vC; a3 += vD;
  }
  for (; e < s1; ++e) {
    a0 += __half2float(p[(size_t)col[e] * 40 + lane]);
  }
  if (lane < 40) out[(size_t)node * 40 + lane] += in_norm[node] * ((a0 + a1) + (a2 + a3));
}

extern "C" void kernel_launch(void* const* d_in, const int* in_sizes, int n_in,
                              void* d_out, int out_size, void* d_ws, size_t ws_size,
                              hipStream_t stream) {
  const float* feat = (const float*)d_in[0];
  const int* src = (const int*)d_in[1];
  const int* dst = (const int*)d_in[2];
  const float* w0 = (const float*)d_in[3];
  const float* w1 = (const float*)d_in[4];
  const float* w2 = (const float*)d_in[5];
  const float* b2 = (const float*)d_in[6];
  const float* l0 = (const float*)d_in[7];
  const float* l1 = (const float*)d_in[8];
  const float* l2 = (const float*)d_in[9];
  const float* g0 = (const float*)d_in[10];
  const float* beta0 = (const float*)d_in[11];
  const float* g1 = (const float*)d_in[12];
  const float* beta1 = (const float*)d_in[13];
  float* out = (float*)d_out;

  char* ws = (char*)d_ws;
  size_t off = 0;
  auto alloc = [&](size_t bytes) {
    void* ptr = ws + off;
    off = (off + bytes + 255) & ~(size_t)255;
    return ptr;
  };
  float* A = (float*)alloc(sizeof(float) * (size_t)N_NODES * 128);  // agg result / p (fp16 view)
  float* B = (float*)alloc(sizeof(float) * (size_t)N_NODES * 128);  // h
  __half* H = (__half*)alloc(sizeof(__half) * (size_t)N_NODES * 128);  // fp16 gather table
  int* degs = (int*)alloc(sizeof(int) * N_NODES);
  int* degd = (int*)alloc(sizeof(int) * N_NODES);
  int* rank = (int*)alloc(sizeof(int) * N_EDGES);
  int* row_start = (int*)alloc(sizeof(int) * (N_NODES + 1));
  int* colb = (int*)alloc(sizeof(int) * N_EDGES);
  float* out_norm = (float*)alloc(sizeof(float) * N_NODES);
  float* in_norm = (float*)alloc(sizeof(float) * N_NODES);
  int* bsum = (int*)alloc(sizeof(int) * 512);
  float* stats = (float*)alloc(sizeof(float) * 256);

  hipMemsetAsync(degs, 0, sizeof(int) * N_NODES, stream);
  hipMemsetAsync(degd, 0, sizeof(int) * N_NODES, stream);

  int eb = (N_EDGES + 255) / 256;       // 6250 (scalar, 1 thread/edge)
  int eb4 = (N_EDGES / 4 + 255) / 256;  // 1563
  int nb = (N_NODES + 255) / 256;       // 391
  k_count<<<eb, 256, 0, stream>>>(src, dst, degs, degd, rank);
  k_norms<<<nb, 256, 0, stream>>>(degs, degd, out_norm, in_norm);
  k_scan1<<<nb, 256, 0, stream>>>(degd, bsum);
  k_scan2<<<1, 512, 0, stream>>>(bsum, nb);
  k_scan3<<<nb, 256, 0, stream>>>(degd, bsum, row_start);
  k_scatter<<<eb4, 256, 0, stream>>>((const int4*)src, (const int4*)dst, (const int4*)rank,
                                     row_start, colb);

  int ab = (N_NODES + 3) / 4;  // wave per node
  int gb = (N_NODES + 63) / 64;
  int fb = (N_NODES * 32 + 255) / 256;

  // layer 0: h1 = relu(bn(agg(feat)@w0^T + feat@l0^T))
  k_feat2h<<<fb, 256, 0, stream>>>(feat, out_norm, H);
  k_agg128h<<<ab, 256, 0, stream>>>(H, colb, row_start, in_norm, A);
  k_gemm_dual<<<gb, 256, 0, stream>>>(A, feat, w0, l0, B);
  hipMemsetAsync(stats, 0, sizeof(float) * 256, stream);
  k_stats<<<(N_NODES + 127) / 128, 256, 0, stream>>>(B, stats);
  k_bnrelu<<<fb, 256, 0, stream>>>(B, stats, g0, beta0, out_norm, H);

  // layer 1: h2 = relu(bn(agg(h1)@w1^T + h1@l1^T))   (gemm in-place on B is tile-safe)
  k_agg128h<<<ab, 256, 0, stream>>>(H, colb, row_start, in_norm, A);
  k_gemm_dual<<<gb, 256, 0, stream>>>(A, B, w1, l1, B);
  hipMemsetAsync(stats, 0, sizeof(float) * 256, stream);
  k_stats<<<(N_NODES + 127) / 128, 256, 0, stream>>>(B, stats);
  k_bnrelu<<<fb, 256, 0, stream>>>(B, stats, g1, beta1, out_norm, (__half*)nullptr);

  // layer 2: out = in_norm*agg(fp16(out_norm*(h2@w2^T))) + b2 + h2@l2^T
  __half* p = (__half*)A;
  k_gemm2<<<(N_NODES + 31) / 32, 256, 0, stream>>>(B, w2, l2, b2, out_norm, p, out);
  k_agg40h<<<ab, 256, 0, stream>>>(p, colb, row_start, in_norm, out);
}

// Round 6
// 936.499 us; speedup vs baseline: 1.3212x; 1.0071x over previous
//
#include <hip/hip_runtime.h>
#include <hip/hip_fp16.h>
#include <cstdint>
#include <cstddef>

#define N_NODES 100000
#define N_EDGES 1600000
#define EPS 1e-5f

// LDS-binned histogram geometry: 7 ranges x 16384 bins covers 114688 >= 100000.
#define HCH 32            // edge chunks
#define HRG 7             // bin ranges
#define HBINS 16384       // bins per range (64 KB LDS)
#define HCHUNK (N_EDGES / HCH)   // 50000 edges per chunk
#define HCHUNK4 (HCHUNK / 4)     // 12500 int4 per chunk

// ---------------- graph prep (atomic-free at device scope) ----------------
// Pass 1: per-(chunk,range) partial histogram of keys into LDS, dump to Hpart.
__global__ void k_hist_part(const int* __restrict__ keys, unsigned int* __restrict__ Hpart) {
  __shared__ unsigned int bins[HBINS];
  int c = blockIdx.x % HCH, r = blockIdx.x / HCH;
  int base = r * HBINS;
  for (int i = threadIdx.x; i < HBINS; i += 256) bins[i] = 0;
  __syncthreads();
  const int4* k4 = (const int4*)(keys + c * HCHUNK);
  for (int i = threadIdx.x; i < HCHUNK4; i += 256) {
    int4 k = k4[i];
    int a;
    a = k.x - base; if ((unsigned)a < (unsigned)HBINS) atomicAdd(&bins[a], 1u);
    a = k.y - base; if ((unsigned)a < (unsigned)HBINS) atomicAdd(&bins[a], 1u);
    a = k.z - base; if ((unsigned)a < (unsigned)HBINS) atomicAdd(&bins[a], 1u);
    a = k.w - base; if ((unsigned)a < (unsigned)HBINS) atomicAdd(&bins[a], 1u);
  }
  __syncthreads();
  unsigned int* out = Hpart + ((size_t)(r * HCH + c) << 14);
  for (int i = threadIdx.x; i < HBINS; i += 256) out[i] = bins[i];
}

// Sum partials over chunks -> deg (for the src histogram).
__global__ void k_hist_sum(const unsigned int* __restrict__ Hpart, int* __restrict__ deg) {
  int b = blockIdx.x * 256 + threadIdx.x;
  if (b >= N_NODES) return;
  int r = b >> 14, lo = b & (HBINS - 1);
  const unsigned int* p = Hpart + ((size_t)(r * HCH) << 14) + lo;
  unsigned int t = 0;
#pragma unroll 8
  for (int c = 0; c < HCH; ++c) t += p[(size_t)c << 14];
  deg[b] = (int)t;
}

// Exclusive scan over chunks in-place (counts -> per-chunk bases) + total -> degd.
__global__ void k_hist_scan(unsigned int* __restrict__ Hpart, int* __restrict__ degd) {
  int b = blockIdx.x * 256 + threadIdx.x;
  if (b >= N_NODES) return;
  int r = b >> 14, lo = b & (HBINS - 1);
  unsigned int* p = Hpart + ((size_t)(r * HCH) << 14) + lo;
  unsigned int t = 0;
#pragma unroll 8
  for (int c = 0; c < HCH; ++c) {
    unsigned int v = p[(size_t)c << 14];
    p[(size_t)c << 14] = t;
    t += v;
  }
  degd[b] = (int)t;
}

// Pass 2: rebuild with LDS cursors; col[row_start[d] + chunkbase + ldsrank] = src.
__global__ void k_build(const int* __restrict__ src, const int* __restrict__ dst,
                        const unsigned int* __restrict__ Hbase,
                        const int* __restrict__ row_start, int* __restrict__ col) {
  __shared__ unsigned int cur[HBINS];
  int c = blockIdx.x % HCH, r = blockIdx.x / HCH;
  int base = r * HBINS;
  for (int i = threadIdx.x; i < HBINS; i += 256) cur[i] = 0;
  __syncthreads();
  const unsigned int* hb = Hbase + ((size_t)(r * HCH + c) << 14);
  const int4* d4 = (const int4*)(dst + c * HCHUNK);
  const int4* s4 = (const int4*)(src + c * HCHUNK);
  for (int i = threadIdx.x; i < HCHUNK4; i += 256) {
    int4 d = d4[i];
    int4 s = s4[i];
    int a;
    a = d.x - base;
    if ((unsigned)a < (unsigned)HBINS) {
      unsigned lr = atomicAdd(&cur[a], 1u);
      col[row_start[d.x] + hb[a] + lr] = s.x;
    }
    a = d.y - base;
    if ((unsigned)a < (unsigned)HBINS) {
      unsigned lr = atomicAdd(&cur[a], 1u);
      col[row_start[d.y] + hb[a] + lr] = s.y;
    }
    a = d.z - base;
    if ((unsigned)a < (unsigned)HBINS) {
      unsigned lr = atomicAdd(&cur[a], 1u);
      col[row_start[d.z] + hb[a] + lr] = s.z;
    }
    a = d.w - base;
    if ((unsigned)a < (unsigned)HBINS) {
      unsigned lr = atomicAdd(&cur[a], 1u);
      col[row_start[d.w] + hb[a] + lr] = s.w;
    }
  }
}

__global__ void k_norms(const int* __restrict__ degs, const int* __restrict__ degd,
                        float* out_norm, float* in_norm) {
  int i = blockIdx.x * 256 + threadIdx.x;
  if (i < N_NODES) {
    out_norm[i] = rsqrtf((float)max(degs[i], 1));
    in_norm[i]  = rsqrtf((float)max(degd[i], 1));
  }
}

__global__ void k_scan1(const int* __restrict__ degd, int* bsum) {
  __shared__ int s[256];
  int t = threadIdx.x;
  int i = blockIdx.x * 256 + t;
  s[t] = (i < N_NODES) ? degd[i] : 0;
  __syncthreads();
  for (int off = 128; off > 0; off >>= 1) {
    if (t < off) s[t] += s[t + off];
    __syncthreads();
  }
  if (t == 0) bsum[blockIdx.x] = s[0];
}

__global__ void k_scan2(int* bsum, int nb) {
  __shared__ int s[512];
  int t = threadIdx.x;
  int v = (t < nb) ? bsum[t] : 0;
  s[t] = v;
  __syncthreads();
  for (int off = 1; off < 512; off <<= 1) {
    int x = (t >= off) ? s[t - off] : 0;
    __syncthreads();
    s[t] += x;
    __syncthreads();
  }
  if (t < nb) bsum[t] = s[t] - v;  // exclusive
}

__global__ void k_scan3(const int* __restrict__ degd, const int* __restrict__ bsum,
                        int* row_start) {
  __shared__ int s[256];
  int t = threadIdx.x;
  int i = blockIdx.x * 256 + t;
  int v = (i < N_NODES) ? degd[i] : 0;
  s[t] = v;
  __syncthreads();
  for (int off = 1; off < 256; off <<= 1) {
    int x = (t >= off) ? s[t - off] : 0;
    __syncthreads();
    s[t] += x;
    __syncthreads();
  }
  if (i < N_NODES) row_start[i] = bsum[blockIdx.x] + s[t] - v;
  if (i == 0) row_start[N_NODES] = N_EDGES;
}

// ---------------- feat -> fp16 gather table (out_norm folded) ----------------
__global__ void k_feat2h(const float* __restrict__ feat, const float* __restrict__ out_norm,
                         __half* __restrict__ H) {
  int i = blockIdx.x * 256 + threadIdx.x;  // float4 index
  if (i >= N_NODES * 32) return;
  float on = out_norm[i >> 5];
  float4 v = ((const float4*)feat)[i];
  ushort4 o;
  o.x = __half_as_ushort(__float2half_rn(v.x * on));
  o.y = __half_as_ushort(__float2half_rn(v.y * on));
  o.z = __half_as_ushort(__float2half_rn(v.z * on));
  o.w = __half_as_ushort(__float2half_rn(v.w * on));
  ((ushort4*)H)[i] = o;
}

// ---------------- aggregation (fp16 gather): out[d] = in_norm[d] * sum_e H[src]
__global__ void k_agg128h(const __half* __restrict__ H, const int* __restrict__ col,
                          const int* __restrict__ row_start,
                          const float* __restrict__ in_norm,
                          float* __restrict__ out) {
  int wave = threadIdx.x >> 6;
  int lane = threadIdx.x & 63;
  int node = blockIdx.x * 4 + wave;
  if (node >= N_NODES) return;
  int s0 = row_start[node], s1 = row_start[node + 1];
  const unsigned int* hp = (const unsigned int*)H;
  float ax0 = 0.f, ay0 = 0.f, ax1 = 0.f, ay1 = 0.f;
  float ax2 = 0.f, ay2 = 0.f, ax3 = 0.f, ay3 = 0.f;
  int e = s0;
  for (; e + 4 <= s1; e += 4) {
    int sA = col[e], sB = col[e + 1], sC = col[e + 2], sD = col[e + 3];
    unsigned int uA = hp[(size_t)sA * 64 + lane];
    unsigned int uB = hp[(size_t)sB * 64 + lane];
    unsigned int uC = hp[(size_t)sC * 64 + lane];
    unsigned int uD = hp[(size_t)sD * 64 + lane];
    float2 vA = __half22float2(*(const __half2*)&uA);
    float2 vB = __half22float2(*(const __half2*)&uB);
    float2 vC = __half22float2(*(const __half2*)&uC);
    float2 vD = __half22float2(*(const __half2*)&uD);
    ax0 += vA.x; ay0 += vA.y;
    ax1 += vB.x; ay1 += vB.y;
    ax2 += vC.x; ay2 += vC.y;
    ax3 += vD.x; ay3 += vD.y;
  }
  for (; e < s1; ++e) {
    unsigned int u = hp[(size_t)col[e] * 64 + lane];
    float2 v = __half22float2(*(const __half2*)&u);
    ax0 += v.x; ay0 += v.y;
  }
  float sc = in_norm[node];
  float rx = (ax0 + ax1) + (ax2 + ax3);
  float ry = (ay0 + ay1) + (ay2 + ay3);
  ((float2*)out)[(size_t)node * 64 + lane] = make_float2(rx * sc, ry * sc);
}

// ---------------- dual GEMM: Out = Xa @ Wa^T + Xh @ Wh^T  (128x128 weights, (out,in) layout)
// Safe for Out aliasing Xh: each block reads only its own 64-row tile (staged to LDS) before writing.
__launch_bounds__(256, 2)
__global__ void k_gemm_dual(const float* __restrict__ Xa, const float* __restrict__ Xh,
                            const float* __restrict__ Wa, const float* __restrict__ Wh,
                            float* __restrict__ Out) {
  __shared__ float sX[128][64];   // [k][row] 32 KB
  __shared__ float sW[64][128];   // [k-kc][j] 32 KB
  int t = threadIdx.x;
  int row0 = blockIdx.x * 64;
  int rg = t & 7;    // 8 row-groups of 8 rows
  int cg = t >> 3;   // 32 col-groups of 4 cols
  float acc[8][4];
#pragma unroll
  for (int r = 0; r < 8; ++r)
#pragma unroll
    for (int c = 0; c < 4; ++c) acc[r][c] = 0.f;

  for (int phase = 0; phase < 2; ++phase) {
    const float* X = phase ? Xh : Xa;
    const float* W = phase ? Wh : Wa;
    __syncthreads();  // previous compute done before restaging sX
    {
      int r = t & 63, kq = t >> 6;
      int row = min(row0 + r, N_NODES - 1);
      const float4* xr = (const float4*)(X + (size_t)row * 128);
#pragma unroll
      for (int it = 0; it < 8; ++it) {
        int k4 = kq * 8 + it;
        float4 v = xr[k4];
        sX[k4 * 4 + 0][r] = v.x;
        sX[k4 * 4 + 1][r] = v.y;
        sX[k4 * 4 + 2][r] = v.z;
        sX[k4 * 4 + 3][r] = v.w;
      }
    }
    for (int kc = 0; kc < 128; kc += 64) {
      __syncthreads();  // sX staged / previous sW chunk consumed
      {
        int j = t & 127, kh = t >> 7;
        const float4* wr = (const float4*)(W + (size_t)j * 128);
#pragma unroll
        for (int it = 0; it < 8; ++it) {
          int k4 = (kc >> 2) + kh * 8 + it;
          float4 v = wr[k4];
          int kk = k4 * 4 - kc;
          sW[kk + 0][j] = v.x;
          sW[kk + 1][j] = v.y;
          sW[kk + 2][j] = v.z;
          sW[kk + 3][j] = v.w;
        }
      }
      __syncthreads();
#pragma unroll 4
      for (int k = 0; k < 64; ++k) {
        float4 a0 = *(const float4*)&sX[kc + k][rg * 8];
        float4 a1 = *(const float4*)&sX[kc + k][rg * 8 + 4];
        float4 w = *(const float4*)&sW[k][cg * 4];
        float a[8] = {a0.x, a0.y, a0.z, a0.w, a1.x, a1.y, a1.z, a1.w};
        float wv[4] = {w.x, w.y, w.z, w.w};
#pragma unroll
        for (int r = 0; r < 8; ++r)
#pragma unroll
          for (int c = 0; c < 4; ++c) acc[r][c] += a[r] * wv[c];
      }
    }
  }
#pragma unroll
  for (int r = 0; r < 8; ++r) {
    int row = row0 + rg * 8 + r;
    if (row < N_NODES) {
      float4 v = make_float4(acc[r][0], acc[r][1], acc[r][2], acc[r][3]);
      *(float4*)&Out[(size_t)row * 128 + cg * 4] = v;
    }
  }
}

// ---------------- BN stats: per-column sum & sumsq ----------------
__global__ void k_stats(const float* __restrict__ x, float* stats) {
  __shared__ float ls[256], ls2[256];
  int t = threadIdx.x;
  int c = t & 127, half = t >> 7;
  int base = blockIdx.x * 128;
  float s = 0.f, s2 = 0.f;
  for (int r = half; r < 128; r += 2) {
    int row = base + r;
    if (row < N_NODES) {
      float v = x[(size_t)row * 128 + c];
      s += v;
      s2 += v * v;
    }
  }
  ls[t] = s;
  ls2[t] = s2;
  __syncthreads();
  if (half == 0) {
    s += ls[t + 128];
    s2 += ls2[t + 128];
    atomicAdd(&stats[c], s);
    atomicAdd(&stats[128 + c], s2);
  }
}

// BN+ReLU in-place; optionally emit fp16 gather table (out_norm folded) for next agg.
__global__ void k_bnrelu(float* __restrict__ x, const float* __restrict__ stats,
                         const float* __restrict__ g, const float* __restrict__ b,
                         const float* __restrict__ out_norm, __half* __restrict__ H) {
  int i = blockIdx.x * 256 + threadIdx.x;  // float4 index
  if (i >= N_NODES * 32) return;
  int c4 = (i & 31) * 4;
  float4 v = ((const float4*)x)[i];
  float vv[4] = {v.x, v.y, v.z, v.w};
  const float inv = 1.f / (float)N_NODES;
#pragma unroll
  for (int j = 0; j < 4; ++j) {
    int c = c4 + j;
    float mu = stats[c] * inv;
    float var = stats[128 + c] * inv - mu * mu;
    float rs = rsqrtf(var + EPS);
    float y = (vv[j] - mu) * rs * g[c] + b[c];
    vv[j] = y > 0.f ? y : 0.f;
  }
  ((float4*)x)[i] = make_float4(vv[0], vv[1], vv[2], vv[3]);
  if (H) {
    float on = out_norm[i >> 5];
    ushort4 o;
    o.x = __half_as_ushort(__float2half_rn(vv[0] * on));
    o.y = __half_as_ushort(__float2half_rn(vv[1] * on));
    o.z = __half_as_ushort(__float2half_rn(vv[2] * on));
    o.w = __half_as_ushort(__float2half_rn(vv[3] * on));
    ((ushort4*)H)[i] = o;
  }
}

// ---------------- layer-2 GEMM: p = fp16(out_norm*(X@w2^T)), out = X@l2^T + b2 ----------------
__launch_bounds__(256)
__global__ void k_gemm2(const float* __restrict__ X, const float* __restrict__ w2,
                        const float* __restrict__ l2, const float* __restrict__ b2,
                        const float* __restrict__ out_norm,
                        __half* __restrict__ p, float* __restrict__ out) {
  __shared__ float sX[128][32];  // 16 KB
  __shared__ float sW[128][80];  // 40 KB  cols 0..39 = w2, 40..79 = l2
  int t = threadIdx.x;
  int row0 = blockIdx.x * 32;
  {
    int r = t & 31, kq = t >> 5;
    int row = min(row0 + r, N_NODES - 1);
    const float4* xr = (const float4*)(X + (size_t)row * 128);
#pragma unroll
    for (int it = 0; it < 4; ++it) {
      int k4 = kq * 4 + it;
      float4 v = xr[k4];
      sX[k4 * 4 + 0][r] = v.x;
      sX[k4 * 4 + 1][r] = v.y;
      sX[k4 * 4 + 2][r] = v.z;
      sX[k4 * 4 + 3][r] = v.w;
    }
  }
#pragma unroll
  for (int it = 0; it < 10; ++it) {
    int i = it * 1024 + t * 4;
    int k = i & 127, j = i >> 7;
    const float* srcp = (j < 40) ? (w2 + (size_t)j * 128 + k) : (l2 + (size_t)(j - 40) * 128 + k);
    float4 v = *(const float4*)srcp;
    sW[k + 0][j] = v.x;
    sW[k + 1][j] = v.y;
    sW[k + 2][j] = v.z;
    sW[k + 3][j] = v.w;
  }
  __syncthreads();
  int cg = t & 15, rg = t >> 4;  // 16 col-groups x 5 cols, 16 row-groups x 2 rows
  float acc[2][5];
#pragma unroll
  for (int r = 0; r < 2; ++r)
#pragma unroll
    for (int i = 0; i < 5; ++i) acc[r][i] = 0.f;
  for (int k = 0; k < 128; ++k) {
    float x0 = sX[k][rg * 2];
    float x1 = sX[k][rg * 2 + 1];
    float w[5];
#pragma unroll
    for (int i = 0; i < 5; ++i) w[i] = sW[k][cg * 5 + i];
#pragma unroll
    for (int i = 0; i < 5; ++i) {
      acc[0][i] += x0 * w[i];
      acc[1][i] += x1 * w[i];
    }
  }
#pragma unroll
  for (int r = 0; r < 2; ++r) {
    int row = row0 + rg * 2 + r;
    if (row >= N_NODES) continue;
    if (cg < 8) {
      float on = out_norm[row];
#pragma unroll
      for (int i = 0; i < 5; ++i)
        p[(size_t)row * 40 + cg * 5 + i] = __float2half_rn(on * acc[r][i]);
    } else {
      int j0 = cg * 5 - 40;
#pragma unroll
      for (int i = 0; i < 5; ++i) out[(size_t)row * 40 + j0 + i] = acc[r][i] + b2[j0 + i];
    }
  }
}

// ---------------- layer-2 aggregation (fp16 gather): out[d] += in_norm[d] * sum_e p[src]
__global__ void k_agg40h(const __half* __restrict__ p, const int* __restrict__ col,
                         const int* __restrict__ row_start,
                         const float* __restrict__ in_norm,
                         float* __restrict__ out) {
  int wave = threadIdx.x >> 6, lane = threadIdx.x & 63;
  int node = blockIdx.x * 4 + wave;
  if (node >= N_NODES) return;
  int s0 = row_start[node], s1 = row_start[node + 1];
  float a0 = 0.f, a1 = 0.f, a2 = 0.f, a3 = 0.f;
  int e = s0;
  // lanes 40..63 read in-bounds garbage (buffer is N*128 floats reinterpreted), masked at store
  for (; e + 4 <= s1; e += 4) {
    int sA = col[e], sB = col[e + 1], sC = col[e + 2], sD = col[e + 3];
    float vA = __half2float(p[(size_t)sA * 40 + lane]);
    float vB = __half2float(p[(size_t)sB * 40 + lane]);
    float vC = __half2float(p[(size_t)sC * 40 + lane]);
    float vD = __half2float(p[(size_t)sD * 40 + lane]);
    a0 += vA; a1 += vB; a2 += vC; a3 += vD;
  }
  for (; e < s1; ++e) {
    a0 += __half2float(p[(size_t)col[e] * 40 + lane]);
  }
  if (lane < 40) out[(size_t)node * 40 + lane] += in_norm[node] * ((a0 + a1) + (a2 + a3));
}

extern "C" void kernel_launch(void* const* d_in, const int* in_sizes, int n_in,
                              void* d_out, int out_size, void* d_ws, size_t ws_size,
                              hipStream_t stream) {
  const float* feat = (const float*)d_in[0];
  const int* src = (const int*)d_in[1];
  const int* dst = (const int*)d_in[2];
  const float* w0 = (const float*)d_in[3];
  const float* w1 = (const float*)d_in[4];
  const float* w2 = (const float*)d_in[5];
  const float* b2 = (const float*)d_in[6];
  const float* l0 = (const float*)d_in[7];
  const float* l1 = (const float*)d_in[8];
  const float* l2 = (const float*)d_in[9];
  const float* g0 = (const float*)d_in[10];
  const float* beta0 = (const float*)d_in[11];
  const float* g1 = (const float*)d_in[12];
  const float* beta1 = (const float*)d_in[13];
  float* out = (float*)d_out;

  char* ws = (char*)d_ws;
  size_t off = 0;
  auto alloc = [&](size_t bytes) {
    void* ptr = ws + off;
    off = (off + bytes + 255) & ~(size_t)255;
    return ptr;
  };
  float* A = (float*)alloc(sizeof(float) * (size_t)N_NODES * 128);  // Hpart (prep) / agg / p
  float* B = (float*)alloc(sizeof(float) * (size_t)N_NODES * 128);  // h
  __half* H = (__half*)alloc(sizeof(__half) * (size_t)N_NODES * 128);  // fp16 gather table
  int* degs = (int*)alloc(sizeof(int) * N_NODES);
  int* degd = (int*)alloc(sizeof(int) * N_NODES);
  int* row_start = (int*)alloc(sizeof(int) * (N_NODES + 1));
  int* colb = (int*)alloc(sizeof(int) * N_EDGES);
  float* out_norm = (float*)alloc(sizeof(float) * N_NODES);
  float* in_norm = (float*)alloc(sizeof(float) * N_NODES);
  int* bsum = (int*)alloc(sizeof(int) * 512);
  float* stats = (float*)alloc(sizeof(float) * 256);

  // Hpart (7*32*16384 uints = 14.7 MB) aliases A — A is first written by k_agg128h,
  // which runs strictly after k_build has consumed Hpart.
  unsigned int* Hpart = (unsigned int*)A;

  int nb = (N_NODES + 255) / 256;  // 391
  int hb = HCH * HRG;              // 224

  // graph prep: no device-scope atomics anywhere.
  k_hist_part<<<hb, 256, 0, stream>>>(src, Hpart);
  k_hist_sum<<<nb, 256, 0, stream>>>(Hpart, degs);
  k_hist_part<<<hb, 256, 0, stream>>>(dst, Hpart);
  k_hist_scan<<<nb, 256, 0, stream>>>(Hpart, degd);   // Hpart -> per-chunk bases
  k_norms<<<nb, 256, 0, stream>>>(degs, degd, out_norm, in_norm);
  k_scan1<<<nb, 256, 0, stream>>>(degd, bsum);
  k_scan2<<<1, 512, 0, stream>>>(bsum, nb);
  k_scan3<<<nb, 256, 0, stream>>>(degd, bsum, row_start);
  k_build<<<hb, 256, 0, stream>>>(src, dst, Hpart, row_start, colb);

  int ab = (N_NODES + 3) / 4;  // wave per node
  int gb = (N_NODES + 63) / 64;
  int fb = (N_NODES * 32 + 255) / 256;

  // layer 0: h1 = relu(bn(agg(feat)@w0^T + feat@l0^T))
  k_feat2h<<<fb, 256, 0, stream>>>(feat, out_norm, H);
  k_agg128h<<<ab, 256, 0, stream>>>(H, colb, row_start, in_norm, A);
  k_gemm_dual<<<gb, 256, 0, stream>>>(A, feat, w0, l0, B);
  hipMemsetAsync(stats, 0, sizeof(float) * 256, stream);
  k_stats<<<(N_NODES + 127) / 128, 256, 0, stream>>>(B, stats);
  k_bnrelu<<<fb, 256, 0, stream>>>(B, stats, g0, beta0, out_norm, H);

  // layer 1: h2 = relu(bn(agg(h1)@w1^T + h1@l1^T))   (gemm in-place on B is tile-safe)
  k_agg128h<<<ab, 256, 0, stream>>>(H, colb, row_start, in_norm, A);
  k_gemm_dual<<<gb, 256, 0, stream>>>(A, B, w1, l1, B);
  hipMemsetAsync(stats, 0, sizeof(float) * 256, stream);
  k_stats<<<(N_NODES + 127) / 128, 256, 0, stream>>>(B, stats);
  k_bnrelu<<<fb, 256, 0, stream>>>(B, stats, g1, beta1, out_norm, (__half*)nullptr);

  // layer 2: out = in_norm*agg(fp16(out_norm*(h2@w2^T))) + b2 + h2@l2^T
  __half* p = (__half*)A;
  k_gemm2<<<(N_NODES + 31) / 32, 256, 0, stream>>>(B, w2, l2, b2, out_norm, p, out);
  k_agg40h<<<ab, 256, 0, stream>>>(p, colb, row_start, in_norm, out);
}

// Round 7
// 797.491 us; speedup vs baseline: 1.5515x; 1.1743x over previous
//
#include <hip/hip_runtime.h>
#include <hip/hip_fp16.h>
#include <cstdint>
#include <cstddef>

#define N_NODES 100000
#define N_EDGES 1600000
#define EPS 1e-5f

typedef _Float16 half8 __attribute__((ext_vector_type(8)));
typedef float floatx4 __attribute__((ext_vector_type(4)));

// LDS-binned histogram geometry: 7 ranges x 16384 bins covers 114688 >= 100000.
#define HCH 32            // edge chunks
#define HRG 7             // bin ranges
#define HBINS 16384       // bins per range (64 KB LDS)
#define HCHUNK (N_EDGES / HCH)   // 50000 edges per chunk
#define HCHUNK4 (HCHUNK / 4)     // 12500 int4 per chunk

// ---------------- graph prep (atomic-free at device scope) ----------------
__global__ void k_hist_part(const int* __restrict__ keys, unsigned int* __restrict__ Hpart) {
  __shared__ unsigned int bins[HBINS];
  int c = blockIdx.x % HCH, r = blockIdx.x / HCH;
  int base = r * HBINS;
  for (int i = threadIdx.x; i < HBINS; i += 256) bins[i] = 0;
  __syncthreads();
  const int4* k4 = (const int4*)(keys + c * HCHUNK);
  for (int i = threadIdx.x; i < HCHUNK4; i += 256) {
    int4 k = k4[i];
    int a;
    a = k.x - base; if ((unsigned)a < (unsigned)HBINS) atomicAdd(&bins[a], 1u);
    a = k.y - base; if ((unsigned)a < (unsigned)HBINS) atomicAdd(&bins[a], 1u);
    a = k.z - base; if ((unsigned)a < (unsigned)HBINS) atomicAdd(&bins[a], 1u);
    a = k.w - base; if ((unsigned)a < (unsigned)HBINS) atomicAdd(&bins[a], 1u);
  }
  __syncthreads();
  unsigned int* out = Hpart + ((size_t)(r * HCH + c) << 14);
  for (int i = threadIdx.x; i < HBINS; i += 256) out[i] = bins[i];
}

__global__ void k_hist_sum(const unsigned int* __restrict__ Hpart, int* __restrict__ deg) {
  int b = blockIdx.x * 256 + threadIdx.x;
  if (b >= N_NODES) return;
  int r = b >> 14, lo = b & (HBINS - 1);
  const unsigned int* p = Hpart + ((size_t)(r * HCH) << 14) + lo;
  unsigned int t = 0;
#pragma unroll 8
  for (int c = 0; c < HCH; ++c) t += p[(size_t)c << 14];
  deg[b] = (int)t;
}

__global__ void k_hist_scan(unsigned int* __restrict__ Hpart, int* __restrict__ degd) {
  int b = blockIdx.x * 256 + threadIdx.x;
  if (b >= N_NODES) return;
  int r = b >> 14, lo = b & (HBINS - 1);
  unsigned int* p = Hpart + ((size_t)(r * HCH) << 14) + lo;
  unsigned int t = 0;
#pragma unroll 8
  for (int c = 0; c < HCH; ++c) {
    unsigned int v = p[(size_t)c << 14];
    p[(size_t)c << 14] = t;
    t += v;
  }
  degd[b] = (int)t;
}

__global__ void k_build(const int* __restrict__ src, const int* __restrict__ dst,
                        const unsigned int* __restrict__ Hbase,
                        const int* __restrict__ row_start, int* __restrict__ col) {
  __shared__ unsigned int cur[HBINS];
  int c = blockIdx.x % HCH, r = blockIdx.x / HCH;
  int base = r * HBINS;
  for (int i = threadIdx.x; i < HBINS; i += 256) cur[i] = 0;
  __syncthreads();
  const unsigned int* hb = Hbase + ((size_t)(r * HCH + c) << 14);
  const int4* d4 = (const int4*)(dst + c * HCHUNK);
  const int4* s4 = (const int4*)(src + c * HCHUNK);
  for (int i = threadIdx.x; i < HCHUNK4; i += 256) {
    int4 d = d4[i];
    int4 s = s4[i];
    int a;
    a = d.x - base;
    if ((unsigned)a < (unsigned)HBINS) {
      unsigned lr = atomicAdd(&cur[a], 1u);
      col[row_start[d.x] + hb[a] + lr] = s.x;
    }
    a = d.y - base;
    if ((unsigned)a < (unsigned)HBINS) {
      unsigned lr = atomicAdd(&cur[a], 1u);
      col[row_start[d.y] + hb[a] + lr] = s.y;
    }
    a = d.z - base;
    if ((unsigned)a < (unsigned)HBINS) {
      unsigned lr = atomicAdd(&cur[a], 1u);
      col[row_start[d.z] + hb[a] + lr] = s.z;
    }
    a = d.w - base;
    if ((unsigned)a < (unsigned)HBINS) {
      unsigned lr = atomicAdd(&cur[a], 1u);
      col[row_start[d.w] + hb[a] + lr] = s.w;
    }
  }
}

__global__ void k_norms(const int* __restrict__ degs, const int* __restrict__ degd,
                        float* out_norm, float* in_norm) {
  int i = blockIdx.x * 256 + threadIdx.x;
  if (i < N_NODES) {
    out_norm[i] = rsqrtf((float)max(degs[i], 1));
    in_norm[i]  = rsqrtf((float)max(degd[i], 1));
  }
}

__global__ void k_scan1(const int* __restrict__ degd, int* bsum) {
  __shared__ int s[256];
  int t = threadIdx.x;
  int i = blockIdx.x * 256 + t;
  s[t] = (i < N_NODES) ? degd[i] : 0;
  __syncthreads();
  for (int off = 128; off > 0; off >>= 1) {
    if (t < off) s[t] += s[t + off];
    __syncthreads();
  }
  if (t == 0) bsum[blockIdx.x] = s[0];
}

__global__ void k_scan2(int* bsum, int nb) {
  __shared__ int s[512];
  int t = threadIdx.x;
  int v = (t < nb) ? bsum[t] : 0;
  s[t] = v;
  __syncthreads();
  for (int off = 1; off < 512; off <<= 1) {
    int x = (t >= off) ? s[t - off] : 0;
    __syncthreads();
    s[t] += x;
    __syncthreads();
  }
  if (t < nb) bsum[t] = s[t] - v;  // exclusive
}

__global__ void k_scan3(const int* __restrict__ degd, const int* __restrict__ bsum,
                        int* row_start) {
  __shared__ int s[256];
  int t = threadIdx.x;
  int i = blockIdx.x * 256 + t;
  int v = (i < N_NODES) ? degd[i] : 0;
  s[t] = v;
  __syncthreads();
  for (int off = 1; off < 256; off <<= 1) {
    int x = (t >= off) ? s[t - off] : 0;
    __syncthreads();
    s[t] += x;
    __syncthreads();
  }
  if (i < N_NODES) row_start[i] = bsum[blockIdx.x] + s[t] - v;
  if (i == 0) row_start[N_NODES] = N_EDGES;
}

// ---------------- feat -> fp16 tables: H = fp16(feat*out_norm) for agg, F = fp16(feat) for GEMM
__global__ void k_feat2h(const float* __restrict__ feat, const float* __restrict__ out_norm,
                         unsigned short* __restrict__ H, unsigned short* __restrict__ F) {
  int i = blockIdx.x * 256 + threadIdx.x;  // float4 index
  if (i >= N_NODES * 32) return;
  float on = out_norm[i >> 5];
  float4 v = ((const float4*)feat)[i];
  ushort4 s, u;
  s.x = __half_as_ushort(__float2half_rn(v.x * on));
  s.y = __half_as_ushort(__float2half_rn(v.y * on));
  s.z = __half_as_ushort(__float2half_rn(v.z * on));
  s.w = __half_as_ushort(__float2half_rn(v.w * on));
  u.x = __half_as_ushort(__float2half_rn(v.x));
  u.y = __half_as_ushort(__float2half_rn(v.y));
  u.z = __half_as_ushort(__float2half_rn(v.z));
  u.w = __half_as_ushort(__float2half_rn(v.w));
  ((ushort4*)H)[i] = s;
  ((ushort4*)F)[i] = u;
}

// ---------------- aggregation (fp16 gather -> fp16 out): out16[d] = fp16(in_norm[d] * sum_e H[src])
__global__ void k_agg128h(const __half* __restrict__ H, const int* __restrict__ col,
                          const int* __restrict__ row_start,
                          const float* __restrict__ in_norm,
                          unsigned short* __restrict__ out16) {
  int wave = threadIdx.x >> 6;
  int lane = threadIdx.x & 63;
  int node = blockIdx.x * 4 + wave;
  if (node >= N_NODES) return;
  int s0 = row_start[node], s1 = row_start[node + 1];
  const unsigned int* hp = (const unsigned int*)H;
  float ax0 = 0.f, ay0 = 0.f, ax1 = 0.f, ay1 = 0.f;
  float ax2 = 0.f, ay2 = 0.f, ax3 = 0.f, ay3 = 0.f;
  int e = s0;
  for (; e + 4 <= s1; e += 4) {
    int sA = col[e], sB = col[e + 1], sC = col[e + 2], sD = col[e + 3];
    unsigned int uA = hp[(size_t)sA * 64 + lane];
    unsigned int uB = hp[(size_t)sB * 64 + lane];
    unsigned int uC = hp[(size_t)sC * 64 + lane];
    unsigned int uD = hp[(size_t)sD * 64 + lane];
    float2 vA = __half22float2(*(const __half2*)&uA);
    float2 vB = __half22float2(*(const __half2*)&uB);
    float2 vC = __half22float2(*(const __half2*)&uC);
    float2 vD = __half22float2(*(const __half2*)&uD);
    ax0 += vA.x; ay0 += vA.y;
    ax1 += vB.x; ay1 += vB.y;
    ax2 += vC.x; ay2 += vC.y;
    ax3 += vD.x; ay3 += vD.y;
  }
  for (; e < s1; ++e) {
    unsigned int u = hp[(size_t)col[e] * 64 + lane];
    float2 v = __half22float2(*(const __half2*)&u);
    ax0 += v.x; ay0 += v.y;
  }
  float sc = in_norm[node];
  float rx = ((ax0 + ax1) + (ax2 + ax3)) * sc;
  float ry = ((ay0 + ay1) + (ay2 + ay3)) * sc;
  __half2 r2 = __float22half2_rn(make_float2(rx, ry));
  ((unsigned int*)out16)[(size_t)node * 64 + lane] = *(const unsigned int*)&r2;
}

// ---------------- MFMA dual GEMM: Out = Xa @ Wa^T + Xh @ Wh^T
// Xa/Xh fp16 [N][128]; Wa/Wh fp32 (out,in) 128x128 converted to fp16 at stage time.
// 64-row tile / block, 4 waves, each wave: 16 rows x 128 cols via 8 accum tiles.
// mfma_f32_16x16x32_f16: A[m=lane&15][k=(lane>>4)*8+j], B[n=lane&15][k=(lane>>4)*8+j],
// D: row=(lane>>4)*4+i, col=lane&15  (layouts per learn_hip m89/m91/m120, dtype-indep).
__launch_bounds__(256)
__global__ void k_gemm_dual16(const unsigned short* __restrict__ Xa,
                              const unsigned short* __restrict__ Xh,
                              const float* __restrict__ Wa, const float* __restrict__ Wh,
                              float* __restrict__ Out) {
  __shared__ __align__(16) unsigned short sX[64][136];   // +8-half pad: standard b128 bank pattern
  __shared__ __align__(16) unsigned short sW[128][136];
  int t = threadIdx.x;
  int row0 = blockIdx.x * 64;
  int w = t >> 6, lane = t & 63;
  int q = lane >> 4, m = lane & 15;
  floatx4 acc[8];
#pragma unroll
  for (int i = 0; i < 8; ++i) acc[i] = (floatx4){0.f, 0.f, 0.f, 0.f};

  for (int phase = 0; phase < 2; ++phase) {
    const unsigned short* Xg = phase ? Xh : Xa;
    const float* Wg = phase ? Wh : Wa;
    __syncthreads();  // previous phase's compute done before restaging
    {
      int r = t >> 2;
      int c0 = (t & 3) * 4;  // 4 chunks of 8 halves each
      const uint4* xr = (const uint4*)(Xg + (size_t)min(row0 + r, N_NODES - 1) * 128);
#pragma unroll
      for (int it = 0; it < 4; ++it) {
        uint4 v = xr[c0 + it];
        *(uint4*)&sX[r][(c0 + it) * 8] = v;
      }
    }
    {
      int n = t >> 1, h = (t & 1) * 64;
      const float4* wr = (const float4*)(Wg + (size_t)n * 128 + h);
#pragma unroll
      for (int it = 0; it < 16; ++it) {
        float4 v = wr[it];
        ushort4 o;
        o.x = __half_as_ushort(__float2half_rn(v.x));
        o.y = __half_as_ushort(__float2half_rn(v.y));
        o.z = __half_as_ushort(__float2half_rn(v.z));
        o.w = __half_as_ushort(__float2half_rn(v.w));
        *(ushort4*)&sW[n][h + it * 4] = o;
      }
    }
    __syncthreads();
#pragma unroll
    for (int ks = 0; ks < 4; ++ks) {
      int kk = ks * 32 + q * 8;
      half8 a = *(const half8*)&sX[w * 16 + m][kk];
#pragma unroll
      for (int t8 = 0; t8 < 8; ++t8) {
        half8 b = *(const half8*)&sW[t8 * 16 + m][kk];
        acc[t8] = __builtin_amdgcn_mfma_f32_16x16x32_f16(a, b, acc[t8], 0, 0, 0);
      }
    }
  }
#pragma unroll
  for (int t8 = 0; t8 < 8; ++t8) {
#pragma unroll
    for (int i = 0; i < 4; ++i) {
      int row = row0 + w * 16 + q * 4 + i;
      if (row < N_NODES) Out[(size_t)row * 128 + t8 * 16 + m] = acc[t8][i];
    }
  }
}

// ---------------- BN stats: per-column sum & sumsq ----------------
__global__ void k_stats(const float* __restrict__ x, float* stats) {
  __shared__ float ls[256], ls2[256];
  int t = threadIdx.x;
  int c = t & 127, half = t >> 7;
  int base = blockIdx.x * 128;
  float s = 0.f, s2 = 0.f;
  for (int r = half; r < 128; r += 2) {
    int row = base + r;
    if (row < N_NODES) {
      float v = x[(size_t)row * 128 + c];
      s += v;
      s2 += v * v;
    }
  }
  ls[t] = s;
  ls2[t] = s2;
  __syncthreads();
  if (half == 0) {
    s += ls[t + 128];
    s2 += ls2[t + 128];
    atomicAdd(&stats[c], s);
    atomicAdd(&stats[128 + c], s2);
  }
}

// BN+ReLU. If H!=null: emit fp16 tables (H scaled by out_norm, F unscaled), skip fp32 writeback.
// Else: write fp32 result in-place.
__global__ void k_bnrelu(float* __restrict__ x, const float* __restrict__ stats,
                         const float* __restrict__ g, const float* __restrict__ b,
                         const float* __restrict__ out_norm,
                         unsigned short* __restrict__ H, unsigned short* __restrict__ F) {
  int i = blockIdx.x * 256 + threadIdx.x;  // float4 index
  if (i >= N_NODES * 32) return;
  int c4 = (i & 31) * 4;
  float4 v = ((const float4*)x)[i];
  float vv[4] = {v.x, v.y, v.z, v.w};
  const float inv = 1.f / (float)N_NODES;
#pragma unroll
  for (int j = 0; j < 4; ++j) {
    int c = c4 + j;
    float mu = stats[c] * inv;
    float var = stats[128 + c] * inv - mu * mu;
    float rs = rsqrtf(var + EPS);
    float y = (vv[j] - mu) * rs * g[c] + b[c];
    vv[j] = y > 0.f ? y : 0.f;
  }
  if (H) {
    float on = out_norm[i >> 5];
    ushort4 s, u;
    s.x = __half_as_ushort(__float2half_rn(vv[0] * on));
    s.y = __half_as_ushort(__float2half_rn(vv[1] * on));
    s.z = __half_as_ushort(__float2half_rn(vv[2] * on));
    s.w = __half_as_ushort(__float2half_rn(vv[3] * on));
    u.x = __half_as_ushort(__float2half_rn(vv[0]));
    u.y = __half_as_ushort(__float2half_rn(vv[1]));
    u.z = __half_as_ushort(__float2half_rn(vv[2]));
    u.w = __half_as_ushort(__float2half_rn(vv[3]));
    ((ushort4*)H)[i] = s;
    ((ushort4*)F)[i] = u;
  } else {
    ((float4*)x)[i] = make_float4(vv[0], vv[1], vv[2], vv[3]);
  }
}

// ---------------- layer-2 GEMM: p = fp16(out_norm*(X@w2^T)), out = X@l2^T + b2 ----------------
__launch_bounds__(256)
__global__ void k_gemm2(const float* __restrict__ X, const float* __restrict__ w2,
                        const float* __restrict__ l2, const float* __restrict__ b2,
                        const float* __restrict__ out_norm,
                        __half* __restrict__ p, float* __restrict__ out) {
  __shared__ float sX[128][32];  // 16 KB
  __shared__ float sW[128][80];  // 40 KB  cols 0..39 = w2, 40..79 = l2
  int t = threadIdx.x;
  int row0 = blockIdx.x * 32;
  {
    int r = t & 31, kq = t >> 5;
    int row = min(row0 + r, N_NODES - 1);
    const float4* xr = (const float4*)(X + (size_t)row * 128);
#pragma unroll
    for (int it = 0; it < 4; ++it) {
      int k4 = kq * 4 + it;
      float4 v = xr[k4];
      sX[k4 * 4 + 0][r] = v.x;
      sX[k4 * 4 + 1][r] = v.y;
      sX[k4 * 4 + 2][r] = v.z;
      sX[k4 * 4 + 3][r] = v.w;
    }
  }
#pragma unroll
  for (int it = 0; it < 10; ++it) {
    int i = it * 1024 + t * 4;
    int k = i & 127, j = i >> 7;
    const float* srcp = (j < 40) ? (w2 + (size_t)j * 128 + k) : (l2 + (size_t)(j - 40) * 128 + k);
    float4 v = *(const float4*)srcp;
    sW[k + 0][j] = v.x;
    sW[k + 1][j] = v.y;
    sW[k + 2][j] = v.z;
    sW[k + 3][j] = v.w;
  }
  __syncthreads();
  int cg = t & 15, rg = t >> 4;  // 16 col-groups x 5 cols, 16 row-groups x 2 rows
  float acc[2][5];
#pragma unroll
  for (int r = 0; r < 2; ++r)
#pragma unroll
    for (int i = 0; i < 5; ++i) acc[r][i] = 0.f;
  for (int k = 0; k < 128; ++k) {
    float x0 = sX[k][rg * 2];
    float x1 = sX[k][rg * 2 + 1];
    float w[5];
#pragma unroll
    for (int i = 0; i < 5; ++i) w[i] = sW[k][cg * 5 + i];
#pragma unroll
    for (int i = 0; i < 5; ++i) {
      acc[0][i] += x0 * w[i];
      acc[1][i] += x1 * w[i];
    }
  }
#pragma unroll
  for (int r = 0; r < 2; ++r) {
    int row = row0 + rg * 2 + r;
    if (row >= N_NODES) continue;
    if (cg < 8) {
      float on = out_norm[row];
#pragma unroll
      for (int i = 0; i < 5; ++i)
        p[(size_t)row * 40 + cg * 5 + i] = __float2half_rn(on * acc[r][i]);
    } else {
      int j0 = cg * 5 - 40;
#pragma unroll
      for (int i = 0; i < 5; ++i) out[(size_t)row * 40 + j0 + i] = acc[r][i] + b2[j0 + i];
    }
  }
}

// ---------------- layer-2 aggregation (fp16 gather): out[d] += in_norm[d] * sum_e p[src]
__global__ void k_agg40h(const __half* __restrict__ p, const int* __restrict__ col,
                         const int* __restrict__ row_start,
                         const float* __restrict__ in_norm,
                         float* __restrict__ out) {
  int wave = threadIdx.x >> 6, lane = threadIdx.x & 63;
  int node = blockIdx.x * 4 + wave;
  if (node >= N_NODES) return;
  int s0 = row_start[node], s1 = row_start[node + 1];
  float a0 = 0.f, a1 = 0.f, a2 = 0.f, a3 = 0.f;
  int e = s0;
  // lanes 40..63 read in-bounds garbage (table buffer is larger), masked at store
  for (; e + 4 <= s1; e += 4) {
    int sA = col[e], sB = col[e + 1], sC = col[e + 2], sD = col[e + 3];
    float vA = __half2float(p[(size_t)sA * 40 + lane]);
    float vB = __half2float(p[(size_t)sB * 40 + lane]);
    float vC = __half2float(p[(size_t)sC * 40 + lane]);
    float vD = __half2float(p[(size_t)sD * 40 + lane]);
    a0 += vA; a1 += vB; a2 += vC; a3 += vD;
  }
  for (; e < s1; ++e) {
    a0 += __half2float(p[(size_t)col[e] * 40 + lane]);
  }
  if (lane < 40) out[(size_t)node * 40 + lane] += in_norm[node] * ((a0 + a1) + (a2 + a3));
}

extern "C" void kernel_launch(void* const* d_in, const int* in_sizes, int n_in,
                              void* d_out, int out_size, void* d_ws, size_t ws_size,
                              hipStream_t stream) {
  const float* feat = (const float*)d_in[0];
  const int* src = (const int*)d_in[1];
  const int* dst = (const int*)d_in[2];
  const float* w0 = (const float*)d_in[3];
  const float* w1 = (const float*)d_in[4];
  const float* w2 = (const float*)d_in[5];
  const float* b2 = (const float*)d_in[6];
  const float* l0 = (const float*)d_in[7];
  const float* l1 = (const float*)d_in[8];
  const float* l2 = (const float*)d_in[9];
  const float* g0 = (const float*)d_in[10];
  const float* beta0 = (const float*)d_in[11];
  const float* g1 = (const float*)d_in[12];
  const float* beta1 = (const float*)d_in[13];
  float* out = (float*)d_out;

  char* ws = (char*)d_ws;
  size_t off = 0;
  auto alloc = [&](size_t bytes) {
    void* ptr = ws + off;
    off = (off + bytes + 255) & ~(size_t)255;
    return ptr;
  };
  unsigned short* A16 = (unsigned short*)alloc(2 * (size_t)N_NODES * 128);  // Hpart / agg out / p
  float* B = (float*)alloc(sizeof(float) * (size_t)N_NODES * 128);          // gemm out / h
  unsigned short* H = (unsigned short*)alloc(2 * (size_t)N_NODES * 128);    // scaled fp16 gather table
  unsigned short* F = (unsigned short*)alloc(2 * (size_t)N_NODES * 128);    // unscaled fp16 gemm table
  int* degs = (int*)alloc(sizeof(int) * N_NODES);
  int* degd = (int*)alloc(sizeof(int) * N_NODES);
  int* row_start = (int*)alloc(sizeof(int) * (N_NODES + 1));
  int* colb = (int*)alloc(sizeof(int) * N_EDGES);
  float* out_norm = (float*)alloc(sizeof(float) * N_NODES);
  float* in_norm = (float*)alloc(sizeof(float) * N_NODES);
  int* bsum = (int*)alloc(sizeof(int) * 512);
  float* stats = (float*)alloc(sizeof(float) * 256);

  // Hpart (7*32*16384 uints = 14.7 MB) aliases A16 (25.6 MB): consumed by k_build before
  // A16 is first written by k_agg128h.
  unsigned int* Hpart = (unsigned int*)A16;

  int nb = (N_NODES + 255) / 256;  // 391
  int hb = HCH * HRG;              // 224

  k_hist_part<<<hb, 256, 0, stream>>>(src, Hpart);
  k_hist_sum<<<nb, 256, 0, stream>>>(Hpart, degs);
  k_hist_part<<<hb, 256, 0, stream>>>(dst, Hpart);
  k_hist_scan<<<nb, 256, 0, stream>>>(Hpart, degd);   // Hpart -> per-chunk bases
  k_norms<<<nb, 256, 0, stream>>>(degs, degd, out_norm, in_norm);
  k_scan1<<<nb, 256, 0, stream>>>(degd, bsum);
  k_scan2<<<1, 512, 0, stream>>>(bsum, nb);
  k_scan3<<<nb, 256, 0, stream>>>(degd, bsum, row_start);
  k_build<<<hb, 256, 0, stream>>>(src, dst, Hpart, row_start, colb);

  int ab = (N_NODES + 3) / 4;   // wave per node
  int gb = (N_NODES + 63) / 64;
  int fb = (N_NODES * 32 + 255) / 256;

  // layer 0: h1 = relu(bn(agg(feat)@w0^T + feat@l0^T))
  k_feat2h<<<fb, 256, 0, stream>>>(feat, out_norm, H, F);
  k_agg128h<<<ab, 256, 0, stream>>>((const __half*)H, colb, row_start, in_norm, A16);
  k_gemm_dual16<<<gb, 256, 0, stream>>>(A16, F, w0, l0, B);
  hipMemsetAsync(stats, 0, sizeof(float) * 256, stream);
  k_stats<<<(N_NODES + 127) / 128, 256, 0, stream>>>(B, stats);
  k_bnrelu<<<fb, 256, 0, stream>>>(B, stats, g0, beta0, out_norm, H, F);  // emits H,F; no fp32 writeback

  // layer 1: h2 = relu(bn(agg(h1)@w1^T + h1@l1^T))
  k_agg128h<<<ab, 256, 0, stream>>>((const __half*)H, colb, row_start, in_norm, A16);
  k_gemm_dual16<<<gb, 256, 0, stream>>>(A16, F, w1, l1, B);  // overwrites B (pre-BN h1 dead)
  hipMemsetAsync(stats, 0, sizeof(float) * 256, stream);
  k_stats<<<(N_NODES + 127) / 128, 256, 0, stream>>>(B, stats);
  k_bnrelu<<<fb, 256, 0, stream>>>(B, stats, g1, beta1, out_norm,
                                   (unsigned short*)nullptr, (unsigned short*)nullptr);

  // layer 2: out = in_norm*agg(fp16(out_norm*(h2@w2^T))) + b2 + h2@l2^T
  __half* p = (__half*)A16;  // A16 dead after layer-1 gemm
  k_gemm2<<<(N_NODES + 31) / 32, 256, 0, stream>>>(B, w2, l2, b2, out_norm, p, out);
  k_agg40h<<<ab, 256, 0, stream>>>(p, colb, row_start, in_norm, out);
}

// Round 8
// 707.773 us; speedup vs baseline: 1.7482x; 1.1268x over previous
//
#include <hip/hip_runtime.h>
#include <hip/hip_fp16.h>
#include <cstdint>
#include <cstddef>

#define N_NODES 100000
#define N_EDGES 1600000
#define EPS 1e-5f

typedef _Float16 half8 __attribute__((ext_vector_type(8)));
typedef float floatx4 __attribute__((ext_vector_type(4)));

// LDS-binned histogram geometry: 7 ranges x 16384 bins covers 114688 >= 100000.
#define HCH 32            // edge chunks
#define HRG 7             // bin ranges
#define HBINS 16384       // bins per range (64 KB LDS)
#define HCHUNK (N_EDGES / HCH)   // 50000 edges per chunk
#define HCHUNK4 (HCHUNK / 4)     // 12500 int4 per chunk

// ---------------- graph prep (atomic-free at device scope) ----------------
__global__ void k_hist_part(const int* __restrict__ keys, unsigned int* __restrict__ Hpart) {
  __shared__ unsigned int bins[HBINS];
  int c = blockIdx.x % HCH, r = blockIdx.x / HCH;
  int base = r * HBINS;
  for (int i = threadIdx.x; i < HBINS; i += 256) bins[i] = 0;
  __syncthreads();
  const int4* k4 = (const int4*)(keys + c * HCHUNK);
  for (int i = threadIdx.x; i < HCHUNK4; i += 256) {
    int4 k = k4[i];
    int a;
    a = k.x - base; if ((unsigned)a < (unsigned)HBINS) atomicAdd(&bins[a], 1u);
    a = k.y - base; if ((unsigned)a < (unsigned)HBINS) atomicAdd(&bins[a], 1u);
    a = k.z - base; if ((unsigned)a < (unsigned)HBINS) atomicAdd(&bins[a], 1u);
    a = k.w - base; if ((unsigned)a < (unsigned)HBINS) atomicAdd(&bins[a], 1u);
  }
  __syncthreads();
  unsigned int* out = Hpart + ((size_t)(r * HCH + c) << 14);
  for (int i = threadIdx.x; i < HBINS; i += 256) out[i] = bins[i];
}

__global__ void k_hist_sum(const unsigned int* __restrict__ Hpart, int* __restrict__ deg) {
  int b = blockIdx.x * 256 + threadIdx.x;
  if (b >= N_NODES) return;
  int r = b >> 14, lo = b & (HBINS - 1);
  const unsigned int* p = Hpart + ((size_t)(r * HCH) << 14) + lo;
  unsigned int t = 0;
#pragma unroll 8
  for (int c = 0; c < HCH; ++c) t += p[(size_t)c << 14];
  deg[b] = (int)t;
}

__global__ void k_hist_scan(unsigned int* __restrict__ Hpart, int* __restrict__ degd) {
  int b = blockIdx.x * 256 + threadIdx.x;
  if (b >= N_NODES) return;
  int r = b >> 14, lo = b & (HBINS - 1);
  unsigned int* p = Hpart + ((size_t)(r * HCH) << 14) + lo;
  unsigned int t = 0;
#pragma unroll 8
  for (int c = 0; c < HCH; ++c) {
    unsigned int v = p[(size_t)c << 14];
    p[(size_t)c << 14] = t;
    t += v;
  }
  degd[b] = (int)t;
}

__global__ void k_build(const int* __restrict__ src, const int* __restrict__ dst,
                        const unsigned int* __restrict__ Hbase,
                        const int* __restrict__ row_start, int* __restrict__ col) {
  __shared__ unsigned int cur[HBINS];
  int c = blockIdx.x % HCH, r = blockIdx.x / HCH;
  int base = r * HBINS;
  for (int i = threadIdx.x; i < HBINS; i += 256) cur[i] = 0;
  __syncthreads();
  const unsigned int* hb = Hbase + ((size_t)(r * HCH + c) << 14);
  const int4* d4 = (const int4*)(dst + c * HCHUNK);
  const int4* s4 = (const int4*)(src + c * HCHUNK);
  for (int i = threadIdx.x; i < HCHUNK4; i += 256) {
    int4 d = d4[i];
    int4 s = s4[i];
    int a;
    a = d.x - base;
    if ((unsigned)a < (unsigned)HBINS) {
      unsigned lr = atomicAdd(&cur[a], 1u);
      col[row_start[d.x] + hb[a] + lr] = s.x;
    }
    a = d.y - base;
    if ((unsigned)a < (unsigned)HBINS) {
      unsigned lr = atomicAdd(&cur[a], 1u);
      col[row_start[d.y] + hb[a] + lr] = s.y;
    }
    a = d.z - base;
    if ((unsigned)a < (unsigned)HBINS) {
      unsigned lr = atomicAdd(&cur[a], 1u);
      col[row_start[d.z] + hb[a] + lr] = s.z;
    }
    a = d.w - base;
    if ((unsigned)a < (unsigned)HBINS) {
      unsigned lr = atomicAdd(&cur[a], 1u);
      col[row_start[d.w] + hb[a] + lr] = s.w;
    }
  }
}

__global__ void k_norms(const int* __restrict__ degs, const int* __restrict__ degd,
                        float* out_norm, float* in_norm) {
  int i = blockIdx.x * 256 + threadIdx.x;
  if (i < N_NODES) {
    out_norm[i] = rsqrtf((float)max(degs[i], 1));
    in_norm[i]  = rsqrtf((float)max(degd[i], 1));
  }
}

__global__ void k_scan1(const int* __restrict__ degd, int* bsum) {
  __shared__ int s[256];
  int t = threadIdx.x;
  int i = blockIdx.x * 256 + t;
  s[t] = (i < N_NODES) ? degd[i] : 0;
  __syncthreads();
  for (int off = 128; off > 0; off >>= 1) {
    if (t < off) s[t] += s[t + off];
    __syncthreads();
  }
  if (t == 0) bsum[blockIdx.x] = s[0];
}

__global__ void k_scan2(int* bsum, int nb) {
  __shared__ int s[512];
  int t = threadIdx.x;
  int v = (t < nb) ? bsum[t] : 0;
  s[t] = v;
  __syncthreads();
  for (int off = 1; off < 512; off <<= 1) {
    int x = (t >= off) ? s[t - off] : 0;
    __syncthreads();
    s[t] += x;
    __syncthreads();
  }
  if (t < nb) bsum[t] = s[t] - v;  // exclusive
}

__global__ void k_scan3(const int* __restrict__ degd, const int* __restrict__ bsum,
                        int* row_start) {
  __shared__ int s[256];
  int t = threadIdx.x;
  int i = blockIdx.x * 256 + t;
  int v = (i < N_NODES) ? degd[i] : 0;
  s[t] = v;
  __syncthreads();
  for (int off = 1; off < 256; off <<= 1) {
    int x = (t >= off) ? s[t - off] : 0;
    __syncthreads();
    s[t] += x;
    __syncthreads();
  }
  if (i < N_NODES) row_start[i] = bsum[blockIdx.x] + s[t] - v;
  if (i == 0) row_start[N_NODES] = N_EDGES;
}

// ---------------- feat -> fp16 tables: H = fp16(feat*out_norm) for agg, F = fp16(feat) for GEMM
__global__ void k_feat2h(const float* __restrict__ feat, const float* __restrict__ out_norm,
                         unsigned short* __restrict__ H, unsigned short* __restrict__ F) {
  int i = blockIdx.x * 256 + threadIdx.x;  // float4 index
  if (i >= N_NODES * 32) return;
  float on = out_norm[i >> 5];
  float4 v = ((const float4*)feat)[i];
  ushort4 s, u;
  s.x = __half_as_ushort(__float2half_rn(v.x * on));
  s.y = __half_as_ushort(__float2half_rn(v.y * on));
  s.z = __half_as_ushort(__float2half_rn(v.z * on));
  s.w = __half_as_ushort(__float2half_rn(v.w * on));
  u.x = __half_as_ushort(__float2half_rn(v.x));
  u.y = __half_as_ushort(__float2half_rn(v.y));
  u.z = __half_as_ushort(__float2half_rn(v.z));
  u.w = __half_as_ushort(__float2half_rn(v.w));
  ((ushort4*)H)[i] = s;
  ((ushort4*)F)[i] = u;
}

// ---------------- aggregation (fp16 gather -> fp16 out): out16[d] = fp16(in_norm[d] * sum_e H[src])
__global__ void k_agg128h(const __half* __restrict__ H, const int* __restrict__ col,
                          const int* __restrict__ row_start,
                          const float* __restrict__ in_norm,
                          unsigned short* __restrict__ out16) {
  int wave = threadIdx.x >> 6;
  int lane = threadIdx.x & 63;
  int node = blockIdx.x * 4 + wave;
  if (node >= N_NODES) return;
  int s0 = row_start[node], s1 = row_start[node + 1];
  const unsigned int* hp = (const unsigned int*)H;
  float ax0 = 0.f, ay0 = 0.f, ax1 = 0.f, ay1 = 0.f;
  float ax2 = 0.f, ay2 = 0.f, ax3 = 0.f, ay3 = 0.f;
  int e = s0;
  for (; e + 4 <= s1; e += 4) {
    int sA = col[e], sB = col[e + 1], sC = col[e + 2], sD = col[e + 3];
    unsigned int uA = hp[(size_t)sA * 64 + lane];
    unsigned int uB = hp[(size_t)sB * 64 + lane];
    unsigned int uC = hp[(size_t)sC * 64 + lane];
    unsigned int uD = hp[(size_t)sD * 64 + lane];
    float2 vA = __half22float2(*(const __half2*)&uA);
    float2 vB = __half22float2(*(const __half2*)&uB);
    float2 vC = __half22float2(*(const __half2*)&uC);
    float2 vD = __half22float2(*(const __half2*)&uD);
    ax0 += vA.x; ay0 += vA.y;
    ax1 += vB.x; ay1 += vB.y;
    ax2 += vC.x; ay2 += vC.y;
    ax3 += vD.x; ay3 += vD.y;
  }
  for (; e < s1; ++e) {
    unsigned int u = hp[(size_t)col[e] * 64 + lane];
    float2 v = __half22float2(*(const __half2*)&u);
    ax0 += v.x; ay0 += v.y;
  }
  float sc = in_norm[node];
  float rx = ((ax0 + ax1) + (ax2 + ax3)) * sc;
  float ry = ((ay0 + ay1) + (ay2 + ay3)) * sc;
  __half2 r2 = __float22half2_rn(make_float2(rx, ry));
  ((unsigned int*)out16)[(size_t)node * 64 + lane] = *(const unsigned int*)&r2;
}

// ---------------- MFMA dual GEMM: Out = Xa @ Wa^T + Xh @ Wh^T
// 64-row tile / block, 4 waves, each wave: 16 rows x 128 cols via 8 accum tiles.
// mfma_f32_16x16x32_f16: A[m=lane&15][k=(lane>>4)*8+j], B[n=lane&15][k=...], D row=(lane>>4)*4+i, col=lane&15.
__launch_bounds__(256)
__global__ void k_gemm_dual16(const unsigned short* __restrict__ Xa,
                              const unsigned short* __restrict__ Xh,
                              const float* __restrict__ Wa, const float* __restrict__ Wh,
                              float* __restrict__ Out) {
  __shared__ __align__(16) unsigned short sX[64][136];   // +8-half pad
  __shared__ __align__(16) unsigned short sW[128][136];
  int t = threadIdx.x;
  int row0 = blockIdx.x * 64;
  int w = t >> 6, lane = t & 63;
  int q = lane >> 4, m = lane & 15;
  floatx4 acc[8];
#pragma unroll
  for (int i = 0; i < 8; ++i) acc[i] = (floatx4){0.f, 0.f, 0.f, 0.f};

  for (int phase = 0; phase < 2; ++phase) {
    const unsigned short* Xg = phase ? Xh : Xa;
    const float* Wg = phase ? Wh : Wa;
    __syncthreads();
    {
      int r = t >> 2;
      int c0 = (t & 3) * 4;
      const uint4* xr = (const uint4*)(Xg + (size_t)min(row0 + r, N_NODES - 1) * 128);
#pragma unroll
      for (int it = 0; it < 4; ++it) {
        uint4 v = xr[c0 + it];
        *(uint4*)&sX[r][(c0 + it) * 8] = v;
      }
    }
    {
      int n = t >> 1, h = (t & 1) * 64;
      const float4* wr = (const float4*)(Wg + (size_t)n * 128 + h);
#pragma unroll
      for (int it = 0; it < 16; ++it) {
        float4 v = wr[it];
        ushort4 o;
        o.x = __half_as_ushort(__float2half_rn(v.x));
        o.y = __half_as_ushort(__float2half_rn(v.y));
        o.z = __half_as_ushort(__float2half_rn(v.z));
        o.w = __half_as_ushort(__float2half_rn(v.w));
        *(ushort4*)&sW[n][h + it * 4] = o;
      }
    }
    __syncthreads();
#pragma unroll
    for (int ks = 0; ks < 4; ++ks) {
      int kk = ks * 32 + q * 8;
      half8 a = *(const half8*)&sX[w * 16 + m][kk];
#pragma unroll
      for (int t8 = 0; t8 < 8; ++t8) {
        half8 b = *(const half8*)&sW[t8 * 16 + m][kk];
        acc[t8] = __builtin_amdgcn_mfma_f32_16x16x32_f16(a, b, acc[t8], 0, 0, 0);
      }
    }
  }
#pragma unroll
  for (int t8 = 0; t8 < 8; ++t8) {
#pragma unroll
    for (int i = 0; i < 4; ++i) {
      int row = row0 + w * 16 + q * 4 + i;
      if (row < N_NODES) Out[(size_t)row * 128 + t8 * 16 + m] = acc[t8][i];
    }
  }
}

// ---------------- BN stats: per-column sum & sumsq ----------------
__global__ void k_stats(const float* __restrict__ x, float* stats) {
  __shared__ float ls[256], ls2[256];
  int t = threadIdx.x;
  int c = t & 127, half = t >> 7;
  int base = blockIdx.x * 128;
  float s = 0.f, s2 = 0.f;
  for (int r = half; r < 128; r += 2) {
    int row = base + r;
    if (row < N_NODES) {
      float v = x[(size_t)row * 128 + c];
      s += v;
      s2 += v * v;
    }
  }
  ls[t] = s;
  ls2[t] = s2;
  __syncthreads();
  if (half == 0) {
    s += ls[t + 128];
    s2 += ls2[t + 128];
    atomicAdd(&stats[c], s);
    atomicAdd(&stats[128 + c], s2);
  }
}

// BN+ReLU. Emits fp16 tables (H scaled by out_norm, F unscaled) as requested;
// writes fp32 back only if neither table requested.
__global__ void k_bnrelu(float* __restrict__ x, const float* __restrict__ stats,
                         const float* __restrict__ g, const float* __restrict__ b,
                         const float* __restrict__ out_norm,
                         unsigned short* __restrict__ H, unsigned short* __restrict__ F) {
  int i = blockIdx.x * 256 + threadIdx.x;  // float4 index
  if (i >= N_NODES * 32) return;
  int c4 = (i & 31) * 4;
  float4 v = ((const float4*)x)[i];
  float vv[4] = {v.x, v.y, v.z, v.w};
  const float inv = 1.f / (float)N_NODES;
#pragma unroll
  for (int j = 0; j < 4; ++j) {
    int c = c4 + j;
    float mu = stats[c] * inv;
    float var = stats[128 + c] * inv - mu * mu;
    float rs = rsqrtf(var + EPS);
    float y = (vv[j] - mu) * rs * g[c] + b[c];
    vv[j] = y > 0.f ? y : 0.f;
  }
  if (H) {
    float on = out_norm[i >> 5];
    ushort4 s;
    s.x = __half_as_ushort(__float2half_rn(vv[0] * on));
    s.y = __half_as_ushort(__float2half_rn(vv[1] * on));
    s.z = __half_as_ushort(__float2half_rn(vv[2] * on));
    s.w = __half_as_ushort(__float2half_rn(vv[3] * on));
    ((ushort4*)H)[i] = s;
  }
  if (F) {
    ushort4 u;
    u.x = __half_as_ushort(__float2half_rn(vv[0]));
    u.y = __half_as_ushort(__float2half_rn(vv[1]));
    u.z = __half_as_ushort(__float2half_rn(vv[2]));
    u.w = __half_as_ushort(__float2half_rn(vv[3]));
    ((ushort4*)F)[i] = u;
  }
  if (!H && !F) ((float4*)x)[i] = make_float4(vv[0], vv[1], vv[2], vv[3]);
}

// ---------------- MFMA layer-2 GEMM: p = fp16(out_norm*(X@w2^T)), out = X@l2^T + b2
// X fp16 [N][128]; combined weight rows 0..39=w2, 40..79=l2. 64-row tile, 4 waves,
// each wave 16 rows x 80 cols (5 acc tiles).
__launch_bounds__(256)
__global__ void k_gemm2_16(const unsigned short* __restrict__ X,
                           const float* __restrict__ w2, const float* __restrict__ l2,
                           const float* __restrict__ b2,
                           const float* __restrict__ out_norm,
                           __half* __restrict__ p, float* __restrict__ out) {
  __shared__ __align__(16) unsigned short sX[64][136];  // 17.4 KB
  __shared__ __align__(16) unsigned short sW[80][136];  // 21.8 KB
  int t = threadIdx.x;
  int row0 = blockIdx.x * 64;
  int w = t >> 6, lane = t & 63;
  int q = lane >> 4, m = lane & 15;
  {
    int r = t >> 2;
    int c0 = (t & 3) * 4;
    const uint4* xr = (const uint4*)(X + (size_t)min(row0 + r, N_NODES - 1) * 128);
#pragma unroll
    for (int it = 0; it < 4; ++it) {
      uint4 v = xr[c0 + it];
      *(uint4*)&sX[r][(c0 + it) * 8] = v;
    }
  }
  {
#pragma unroll
    for (int it = 0; it < 10; ++it) {
      int i = it * 256 + t;   // float4 index 0..2559
      int j = i >> 5;         // weight row 0..79
      int kq = i & 31;        // float4 within row
      const float* srcp = (j < 40) ? (w2 + (size_t)j * 128) : (l2 + (size_t)(j - 40) * 128);
      float4 v = ((const float4*)srcp)[kq];
      ushort4 o;
      o.x = __half_as_ushort(__float2half_rn(v.x));
      o.y = __half_as_ushort(__float2half_rn(v.y));
      o.z = __half_as_ushort(__float2half_rn(v.z));
      o.w = __half_as_ushort(__float2half_rn(v.w));
      *(ushort4*)&sW[j][kq * 4] = o;
    }
  }
  __syncthreads();
  floatx4 acc[5];
#pragma unroll
  for (int i = 0; i < 5; ++i) acc[i] = (floatx4){0.f, 0.f, 0.f, 0.f};
#pragma unroll
  for (int ks = 0; ks < 4; ++ks) {
    int kk = ks * 32 + q * 8;
    half8 a = *(const half8*)&sX[w * 16 + m][kk];
#pragma unroll
    for (int t5 = 0; t5 < 5; ++t5) {
      half8 b = *(const half8*)&sW[t5 * 16 + m][kk];
      acc[t5] = __builtin_amdgcn_mfma_f32_16x16x32_f16(a, b, acc[t5], 0, 0, 0);
    }
  }
#pragma unroll
  for (int t5 = 0; t5 < 5; ++t5) {
    int col = t5 * 16 + m;
#pragma unroll
    for (int i = 0; i < 4; ++i) {
      int row = row0 + w * 16 + q * 4 + i;
      if (row >= N_NODES) continue;
      if (col < 40) {
        p[(size_t)row * 40 + col] = __float2half_rn(out_norm[row] * acc[t5][i]);
      } else {
        out[(size_t)row * 40 + (col - 40)] = acc[t5][i] + b2[col - 40];
      }
    }
  }
}

// ---------------- layer-2 aggregation (fp16 gather): out[d] += in_norm[d] * sum_e p[src]
__global__ void k_agg40h(const __half* __restrict__ p, const int* __restrict__ col,
                         const int* __restrict__ row_start,
                         const float* __restrict__ in_norm,
                         float* __restrict__ out) {
  int wave = threadIdx.x >> 6, lane = threadIdx.x & 63;
  int node = blockIdx.x * 4 + wave;
  if (node >= N_NODES) return;
  int s0 = row_start[node], s1 = row_start[node + 1];
  float a0 = 0.f, a1 = 0.f, a2 = 0.f, a3 = 0.f;
  int e = s0;
  // lanes 40..63 read in-bounds garbage (table buffer is larger), masked at store
  for (; e + 4 <= s1; e += 4) {
    int sA = col[e], sB = col[e + 1], sC = col[e + 2], sD = col[e + 3];
    float vA = __half2float(p[(size_t)sA * 40 + lane]);
    float vB = __half2float(p[(size_t)sB * 40 + lane]);
    float vC = __half2float(p[(size_t)sC * 40 + lane]);
    float vD = __half2float(p[(size_t)sD * 40 + lane]);
    a0 += vA; a1 += vB; a2 += vC; a3 += vD;
  }
  for (; e < s1; ++e) {
    a0 += __half2float(p[(size_t)col[e] * 40 + lane]);
  }
  if (lane < 40) out[(size_t)node * 40 + lane] += in_norm[node] * ((a0 + a1) + (a2 + a3));
}

extern "C" void kernel_launch(void* const* d_in, const int* in_sizes, int n_in,
                              void* d_out, int out_size, void* d_ws, size_t ws_size,
                              hipStream_t stream) {
  const float* feat = (const float*)d_in[0];
  const int* src = (const int*)d_in[1];
  const int* dst = (const int*)d_in[2];
  const float* w0 = (const float*)d_in[3];
  const float* w1 = (const float*)d_in[4];
  const float* w2 = (const float*)d_in[5];
  const float* b2 = (const float*)d_in[6];
  const float* l0 = (const float*)d_in[7];
  const float* l1 = (const float*)d_in[8];
  const float* l2 = (const float*)d_in[9];
  const float* g0 = (const float*)d_in[10];
  const float* beta0 = (const float*)d_in[11];
  const float* g1 = (const float*)d_in[12];
  const float* beta1 = (const float*)d_in[13];
  float* out = (float*)d_out;

  char* ws = (char*)d_ws;
  size_t off = 0;
  auto alloc = [&](size_t bytes) {
    void* ptr = ws + off;
    off = (off + bytes + 255) & ~(size_t)255;
    return ptr;
  };
  unsigned short* A16 = (unsigned short*)alloc(2 * (size_t)N_NODES * 128);  // Hpart / agg out / p
  float* B = (float*)alloc(sizeof(float) * (size_t)N_NODES * 128);          // gemm out
  unsigned short* H = (unsigned short*)alloc(2 * (size_t)N_NODES * 128);    // scaled fp16 gather table
  unsigned short* F = (unsigned short*)alloc(2 * (size_t)N_NODES * 128);    // unscaled fp16 gemm table
  int* degs = (int*)alloc(sizeof(int) * N_NODES);
  int* degd = (int*)alloc(sizeof(int) * N_NODES);
  int* row_start = (int*)alloc(sizeof(int) * (N_NODES + 1));
  int* colb = (int*)alloc(sizeof(int) * N_EDGES);
  float* out_norm = (float*)alloc(sizeof(float) * N_NODES);
  float* in_norm = (float*)alloc(sizeof(float) * N_NODES);
  int* bsum = (int*)alloc(sizeof(int) * 512);
  float* stats = (float*)alloc(sizeof(float) * 256);

  // Hpart (14.7 MB) aliases A16 (25.6 MB): consumed by k_build before A16's first write.
  unsigned int* Hpart = (unsigned int*)A16;

  int nb = (N_NODES + 255) / 256;  // 391
  int hb = HCH * HRG;              // 224

  k_hist_part<<<hb, 256, 0, stream>>>(src, Hpart);
  k_hist_sum<<<nb, 256, 0, stream>>>(Hpart, degs);
  k_hist_part<<<hb, 256, 0, stream>>>(dst, Hpart);
  k_hist_scan<<<nb, 256, 0, stream>>>(Hpart, degd);   // Hpart -> per-chunk bases
  k_norms<<<nb, 256, 0, stream>>>(degs, degd, out_norm, in_norm);
  k_scan1<<<nb, 256, 0, stream>>>(degd, bsum);
  k_scan2<<<1, 512, 0, stream>>>(bsum, nb);
  k_scan3<<<nb, 256, 0, stream>>>(degd, bsum, row_start);
  k_build<<<hb, 256, 0, stream>>>(src, dst, Hpart, row_start, colb);

  int ab = (N_NODES + 3) / 4;   // wave per node
  int gb = (N_NODES + 63) / 64;
  int fb = (N_NODES * 32 + 255) / 256;

  // layer 0: h1 = relu(bn(agg(feat)@w0^T + feat@l0^T))
  k_feat2h<<<fb, 256, 0, stream>>>(feat, out_norm, H, F);
  k_agg128h<<<ab, 256, 0, stream>>>((const __half*)H, colb, row_start, in_norm, A16);
  k_gemm_dual16<<<gb, 256, 0, stream>>>(A16, F, w0, l0, B);
  hipMemsetAsync(stats, 0, sizeof(float) * 256, stream);
  k_stats<<<(N_NODES + 127) / 128, 256, 0, stream>>>(B, stats);
  k_bnrelu<<<fb, 256, 0, stream>>>(B, stats, g0, beta0, out_norm, H, F);

  // layer 1: h2 = relu(bn(agg(h1)@w1^T + h1@l1^T))
  k_agg128h<<<ab, 256, 0, stream>>>((const __half*)H, colb, row_start, in_norm, A16);
  k_gemm_dual16<<<gb, 256, 0, stream>>>(A16, F, w1, l1, B);
  hipMemsetAsync(stats, 0, sizeof(float) * 256, stream);
  k_stats<<<(N_NODES + 127) / 128, 256, 0, stream>>>(B, stats);
  k_bnrelu<<<fb, 256, 0, stream>>>(B, stats, g1, beta1, out_norm,
                                   (unsigned short*)nullptr, F);  // F = fp16 h2, no fp32 writeback

  // layer 2: out = in_norm*agg(fp16(out_norm*(h2@w2^T))) + b2 + h2@l2^T
  __half* p = (__half*)A16;  // A16 dead after layer-1 gemm
  k_gemm2_16<<<gb, 256, 0, stream>>>(F, w2, l2, b2, out_norm, p, out);
  k_agg40h<<<ab, 256, 0, stream>>>(p, colb, row_start, in_norm, out);
}

// Round 9
// 628.848 us; speedup vs baseline: 1.9676x; 1.1255x over previous
//
#include <hip/hip_runtime.h>
#include <hip/hip_fp16.h>
#include <cstdint>
#include <cstddef>

#define N_NODES 100000
#define N_EDGES 1600000
#define EPS 1e-5f

typedef _Float16 half8 __attribute__((ext_vector_type(8)));
typedef float floatx4 __attribute__((ext_vector_type(4)));

// LDS-binned histogram: ushort counters packed 2/uint (per-chunk count <= 12500 < 65536,
// so the low halfword can never carry into the high). 32768 bins/range -> 4 ranges
// cover 131072 >= 100000; 128 chunks -> grid 512 = 2 blocks/CU at 64 KB LDS.
#define HCH 128                  // edge chunks
#define HRG 4                    // bin ranges
#define HBINS 32768              // ushort bins per range
#define HWORDS (HBINS / 2)       // 16384 uints = 64 KB LDS
#define HCHUNK (N_EDGES / HCH)   // 12500 edges per chunk
#define HCHUNK4 (HCHUNK / 4)     // 3125 int4 per chunk

// ---------------- graph prep (no device-scope atomics) ----------------
__global__ void k_hist_part(const int* __restrict__ keys, unsigned int* __restrict__ Hpart) {
  __shared__ unsigned int bins[HWORDS];
  int c = blockIdx.x % HCH, r = blockIdx.x / HCH;
  int base = r * HBINS;
  for (int i = threadIdx.x; i < HWORDS; i += 256) bins[i] = 0;
  __syncthreads();
  const int4* k4 = (const int4*)(keys + c * HCHUNK);
  for (int i = threadIdx.x; i < HCHUNK4; i += 256) {
    int4 k = k4[i];
    int a;
    a = k.x - base; if ((unsigned)a < (unsigned)HBINS) atomicAdd(&bins[a >> 1], 1u << ((a & 1) * 16));
    a = k.y - base; if ((unsigned)a < (unsigned)HBINS) atomicAdd(&bins[a >> 1], 1u << ((a & 1) * 16));
    a = k.z - base; if ((unsigned)a < (unsigned)HBINS) atomicAdd(&bins[a >> 1], 1u << ((a & 1) * 16));
    a = k.w - base; if ((unsigned)a < (unsigned)HBINS) atomicAdd(&bins[a >> 1], 1u << ((a & 1) * 16));
  }
  __syncthreads();
  unsigned int* outp = Hpart + ((size_t)blockIdx.x << 14);  // 16384 uints per slab
  for (int i = threadIdx.x; i < HWORDS; i += 256) outp[i] = bins[i];
}

// Sum ushort partials over chunks -> deg (used for the src histogram).
__global__ void k_hist_sum(const unsigned short* __restrict__ Hp, int* __restrict__ deg) {
  int b = blockIdx.x * 256 + threadIdx.x;
  if (b >= N_NODES) return;
  int r = b >> 15, lo = b & (HBINS - 1);
  const unsigned short* p = Hp + ((size_t)(r * HCH) << 15) + lo;  // slab = 32768 ushorts
  unsigned int t = 0;
#pragma unroll 8
  for (int c = 0; c < HCH; ++c) t += p[(size_t)c << 15];
  deg[b] = (int)t;
}

// Exclusive scan over chunks in-place (halfword stores; threads own distinct halfwords).
__global__ void k_hist_scan(unsigned short* __restrict__ Hp, int* __restrict__ degd) {
  int b = blockIdx.x * 256 + threadIdx.x;
  if (b >= N_NODES) return;
  int r = b >> 15, lo = b & (HBINS - 1);
  unsigned short* p = Hp + ((size_t)(r * HCH) << 15) + lo;
  unsigned int t = 0;
#pragma unroll 8
  for (int c = 0; c < HCH; ++c) {
    unsigned int v = p[(size_t)c << 15];
    p[(size_t)c << 15] = (unsigned short)t;
    t += v;
  }
  degd[b] = (int)t;
}

// Rebuild pass: LDS packed-ushort cursors; col[row_start[d] + chunkbase[d] + ldsrank] = src.
__global__ void k_build(const int* __restrict__ src, const int* __restrict__ dst,
                        const unsigned short* __restrict__ Hbase,
                        const int* __restrict__ row_start, int* __restrict__ col) {
  __shared__ unsigned int cur[HWORDS];
  int c = blockIdx.x % HCH, r = blockIdx.x / HCH;
  int base = r * HBINS;
  for (int i = threadIdx.x; i < HWORDS; i += 256) cur[i] = 0;
  __syncthreads();
  const unsigned short* hb = Hbase + ((size_t)blockIdx.x << 15);
  const int4* d4 = (const int4*)(dst + c * HCHUNK);
  const int4* s4 = (const int4*)(src + c * HCHUNK);
  for (int i = threadIdx.x; i < HCHUNK4; i += 256) {
    int4 d = d4[i];
    int4 s = s4[i];
    int a;
    a = d.x - base;
    if ((unsigned)a < (unsigned)HBINS) {
      unsigned old = atomicAdd(&cur[a >> 1], 1u << ((a & 1) * 16));
      unsigned lr = (old >> ((a & 1) * 16)) & 0xffffu;
      col[row_start[d.x] + hb[a] + lr] = s.x;
    }
    a = d.y - base;
    if ((unsigned)a < (unsigned)HBINS) {
      unsigned old = atomicAdd(&cur[a >> 1], 1u << ((a & 1) * 16));
      unsigned lr = (old >> ((a & 1) * 16)) & 0xffffu;
      col[row_start[d.y] + hb[a] + lr] = s.y;
    }
    a = d.z - base;
    if ((unsigned)a < (unsigned)HBINS) {
      unsigned old = atomicAdd(&cur[a >> 1], 1u << ((a & 1) * 16));
      unsigned lr = (old >> ((a & 1) * 16)) & 0xffffu;
      col[row_start[d.z] + hb[a] + lr] = s.z;
    }
    a = d.w - base;
    if ((unsigned)a < (unsigned)HBINS) {
      unsigned old = atomicAdd(&cur[a >> 1], 1u << ((a & 1) * 16));
      unsigned lr = (old >> ((a & 1) * 16)) & 0xffffu;
      col[row_start[d.w] + hb[a] + lr] = s.w;
    }
  }
}

__global__ void k_norms(const int* __restrict__ degs, const int* __restrict__ degd,
                        float* out_norm, float* in_norm) {
  int i = blockIdx.x * 256 + threadIdx.x;
  if (i < N_NODES) {
    out_norm[i] = rsqrtf((float)max(degs[i], 1));
    in_norm[i]  = rsqrtf((float)max(degd[i], 1));
  }
}

__global__ void k_scan1(const int* __restrict__ degd, int* bsum) {
  __shared__ int s[256];
  int t = threadIdx.x;
  int i = blockIdx.x * 256 + t;
  s[t] = (i < N_NODES) ? degd[i] : 0;
  __syncthreads();
  for (int off = 128; off > 0; off >>= 1) {
    if (t < off) s[t] += s[t + off];
    __syncthreads();
  }
  if (t == 0) bsum[blockIdx.x] = s[0];
}

__global__ void k_scan2(int* bsum, int nb) {
  __shared__ int s[512];
  int t = threadIdx.x;
  int v = (t < nb) ? bsum[t] : 0;
  s[t] = v;
  __syncthreads();
  for (int off = 1; off < 512; off <<= 1) {
    int x = (t >= off) ? s[t - off] : 0;
    __syncthreads();
    s[t] += x;
    __syncthreads();
  }
  if (t < nb) bsum[t] = s[t] - v;  // exclusive
}

__global__ void k_scan3(const int* __restrict__ degd, const int* __restrict__ bsum,
                        int* row_start) {
  __shared__ int s[256];
  int t = threadIdx.x;
  int i = blockIdx.x * 256 + t;
  int v = (i < N_NODES) ? degd[i] : 0;
  s[t] = v;
  __syncthreads();
  for (int off = 1; off < 256; off <<= 1) {
    int x = (t >= off) ? s[t - off] : 0;
    __syncthreads();
    s[t] += x;
    __syncthreads();
  }
  if (i < N_NODES) row_start[i] = bsum[blockIdx.x] + s[t] - v;
  if (i == 0) row_start[N_NODES] = N_EDGES;
}

// ---------------- feat -> fp16 tables ----------------
__global__ void k_feat2h(const float* __restrict__ feat, const float* __restrict__ out_norm,
                         unsigned short* __restrict__ H, unsigned short* __restrict__ F) {
  int i = blockIdx.x * 256 + threadIdx.x;  // float4 index
  if (i >= N_NODES * 32) return;
  float on = out_norm[i >> 5];
  float4 v = ((const float4*)feat)[i];
  ushort4 s, u;
  s.x = __half_as_ushort(__float2half_rn(v.x * on));
  s.y = __half_as_ushort(__float2half_rn(v.y * on));
  s.z = __half_as_ushort(__float2half_rn(v.z * on));
  s.w = __half_as_ushort(__float2half_rn(v.w * on));
  u.x = __half_as_ushort(__float2half_rn(v.x));
  u.y = __half_as_ushort(__float2half_rn(v.y));
  u.z = __half_as_ushort(__float2half_rn(v.z));
  u.w = __half_as_ushort(__float2half_rn(v.w));
  ((ushort4*)H)[i] = s;
  ((ushort4*)F)[i] = u;
}

// ---------------- aggregation (fp16 gather, unroll 8) ----------------
__global__ void k_agg128h(const __half* __restrict__ H, const int* __restrict__ col,
                          const int* __restrict__ row_start,
                          const float* __restrict__ in_norm,
                          unsigned short* __restrict__ out16) {
  int wave = threadIdx.x >> 6;
  int lane = threadIdx.x & 63;
  int node = blockIdx.x * 4 + wave;
  if (node >= N_NODES) return;
  int s0 = row_start[node], s1 = row_start[node + 1];
  const unsigned int* hp = (const unsigned int*)H;
  float ax[8], ay[8];
#pragma unroll
  for (int j = 0; j < 8; ++j) { ax[j] = 0.f; ay[j] = 0.f; }
  int e = s0;
  for (; e + 8 <= s1; e += 8) {
    unsigned int u[8];
#pragma unroll
    for (int j = 0; j < 8; ++j) u[j] = hp[(size_t)col[e + j] * 64 + lane];
#pragma unroll
    for (int j = 0; j < 8; ++j) {
      float2 v = __half22float2(*(const __half2*)&u[j]);
      ax[j] += v.x; ay[j] += v.y;
    }
  }
  for (; e < s1; ++e) {
    unsigned int u = hp[(size_t)col[e] * 64 + lane];
    float2 v = __half22float2(*(const __half2*)&u);
    ax[0] += v.x; ay[0] += v.y;
  }
  float sc = in_norm[node];
  float rx = (((ax[0] + ax[1]) + (ax[2] + ax[3])) + ((ax[4] + ax[5]) + (ax[6] + ax[7]))) * sc;
  float ry = (((ay[0] + ay[1]) + (ay[2] + ay[3])) + ((ay[4] + ay[5]) + (ay[6] + ay[7]))) * sc;
  __half2 r2 = __float22half2_rn(make_float2(rx, ry));
  ((unsigned int*)out16)[(size_t)node * 64 + lane] = *(const unsigned int*)&r2;
}

// ---------------- MFMA dual GEMM + fused BN stats: Out16 = fp16(Xa@Wa^T + Xh@Wh^T),
// stats[c] += col-sum, stats[128+c] += col-sumsq (fp32 acc, tail rows masked).
__launch_bounds__(256)
__global__ void k_gemm_dual16(const unsigned short* __restrict__ Xa,
                              const unsigned short* __restrict__ Xh,
                              const float* __restrict__ Wa, const float* __restrict__ Wh,
                              unsigned short* __restrict__ Out16, float* __restrict__ stats) {
  __shared__ __align__(16) unsigned short sX[64][136];
  __shared__ __align__(16) unsigned short sW[128][136];
  __shared__ float sSum[128], sSq[128];
  int t = threadIdx.x;
  int row0 = blockIdx.x * 64;
  int w = t >> 6, lane = t & 63;
  int q = lane >> 4, m = lane & 15;
  if (t < 128) { sSum[t] = 0.f; sSq[t] = 0.f; }
  floatx4 acc[8];
#pragma unroll
  for (int i = 0; i < 8; ++i) acc[i] = (floatx4){0.f, 0.f, 0.f, 0.f};

  for (int phase = 0; phase < 2; ++phase) {
    const unsigned short* Xg = phase ? Xh : Xa;
    const float* Wg = phase ? Wh : Wa;
    __syncthreads();
    {
      int r = t >> 2;
      int c0 = (t & 3) * 4;
      const uint4* xr = (const uint4*)(Xg + (size_t)min(row0 + r, N_NODES - 1) * 128);
#pragma unroll
      for (int it = 0; it < 4; ++it) {
        uint4 v = xr[c0 + it];
        *(uint4*)&sX[r][(c0 + it) * 8] = v;
      }
    }
    {
      int n = t >> 1, h = (t & 1) * 64;
      const float4* wr = (const float4*)(Wg + (size_t)n * 128 + h);
#pragma unroll
      for (int it = 0; it < 16; ++it) {
        float4 v = wr[it];
        ushort4 o;
        o.x = __half_as_ushort(__float2half_rn(v.x));
        o.y = __half_as_ushort(__float2half_rn(v.y));
        o.z = __half_as_ushort(__float2half_rn(v.z));
        o.w = __half_as_ushort(__float2half_rn(v.w));
        *(ushort4*)&sW[n][h + it * 4] = o;
      }
    }
    __syncthreads();
#pragma unroll
    for (int ks = 0; ks < 4; ++ks) {
      int kk = ks * 32 + q * 8;
      half8 a = *(const half8*)&sX[w * 16 + m][kk];
#pragma unroll
      for (int t8 = 0; t8 < 8; ++t8) {
        half8 b = *(const half8*)&sW[t8 * 16 + m][kk];
        acc[t8] = __builtin_amdgcn_mfma_f32_16x16x32_f16(a, b, acc[t8], 0, 0, 0);
      }
    }
  }
#pragma unroll
  for (int t8 = 0; t8 < 8; ++t8) {
    int colj = t8 * 16 + m;
    float s = 0.f, sq = 0.f;
#pragma unroll
    for (int i = 0; i < 4; ++i) {
      int row = row0 + w * 16 + q * 4 + i;
      if (row < N_NODES) {
        float v = acc[t8][i];
        s += v; sq += v * v;
        Out16[(size_t)row * 128 + colj] = __half_as_ushort(__float2half_rn(v));
      }
    }
    atomicAdd(&sSum[colj], s);
    atomicAdd(&sSq[colj], sq);
  }
  __syncthreads();
  if (t < 128) {
    atomicAdd(&stats[t], sSum[t]);
    atomicAdd(&stats[128 + t], sSq[t]);
  }
}

// ---------------- BN+ReLU on fp16 input; emits H (scaled) and/or F (unscaled) fp16 tables.
__global__ void k_bnrelu16(const unsigned short* __restrict__ x16,
                           const float* __restrict__ stats,
                           const float* __restrict__ g, const float* __restrict__ b,
                           const float* __restrict__ out_norm,
                           unsigned short* __restrict__ H, unsigned short* __restrict__ F) {
  int i = blockIdx.x * 256 + threadIdx.x;  // ushort8 index
  if (i >= N_NODES * 16) return;
  int c8 = (i & 15) * 8;
  uint4 raw = ((const uint4*)x16)[i];
  const __half2* hp2 = (const __half2*)&raw;
  float v[8];
#pragma unroll
  for (int j = 0; j < 4; ++j) {
    float2 f = __half22float2(hp2[j]);
    v[2 * j] = f.x;
    v[2 * j + 1] = f.y;
  }
  const float inv = 1.f / (float)N_NODES;
#pragma unroll
  for (int j = 0; j < 8; ++j) {
    int c = c8 + j;
    float mu = stats[c] * inv;
    float var = stats[128 + c] * inv - mu * mu;
    float rs = rsqrtf(var + EPS);
    float y = (v[j] - mu) * rs * g[c] + b[c];
    v[j] = y > 0.f ? y : 0.f;
  }
  if (H) {
    float on = out_norm[i >> 4];
    ushort4 o[2];
#pragma unroll
    for (int j = 0; j < 8; ++j) ((unsigned short*)o)[j] = __half_as_ushort(__float2half_rn(v[j] * on));
    ((uint4*)H)[i] = *(const uint4*)o;
  }
  if (F) {
    ushort4 o[2];
#pragma unroll
    for (int j = 0; j < 8; ++j) ((unsigned short*)o)[j] = __half_as_ushort(__float2half_rn(v[j]));
    ((uint4*)F)[i] = *(const uint4*)o;
  }
}

// ---------------- MFMA layer-2 GEMM: p = fp16(out_norm*(X@w2^T)), out = X@l2^T + b2
__launch_bounds__(256)
__global__ void k_gemm2_16(const unsigned short* __restrict__ X,
                           const float* __restrict__ w2, const float* __restrict__ l2,
                           const float* __restrict__ b2,
                           const float* __restrict__ out_norm,
                           __half* __restrict__ p, float* __restrict__ out) {
  __shared__ __align__(16) unsigned short sX[64][136];
  __shared__ __align__(16) unsigned short sW[80][136];
  int t = threadIdx.x;
  int row0 = blockIdx.x * 64;
  int w = t >> 6, lane = t & 63;
  int q = lane >> 4, m = lane & 15;
  {
    int r = t >> 2;
    int c0 = (t & 3) * 4;
    const uint4* xr = (const uint4*)(X + (size_t)min(row0 + r, N_NODES - 1) * 128);
#pragma unroll
    for (int it = 0; it < 4; ++it) {
      uint4 v = xr[c0 + it];
      *(uint4*)&sX[r][(c0 + it) * 8] = v;
    }
  }
  {
#pragma unroll
    for (int it = 0; it < 10; ++it) {
      int i = it * 256 + t;   // float4 index 0..2559
      int j = i >> 5;         // weight row 0..79
      int kq = i & 31;
      const float* srcp = (j < 40) ? (w2 + (size_t)j * 128) : (l2 + (size_t)(j - 40) * 128);
      float4 v = ((const float4*)srcp)[kq];
      ushort4 o;
      o.x = __half_as_ushort(__float2half_rn(v.x));
      o.y = __half_as_ushort(__float2half_rn(v.y));
      o.z = __half_as_ushort(__float2half_rn(v.z));
      o.w = __half_as_ushort(__float2half_rn(v.w));
      *(ushort4*)&sW[j][kq * 4] = o;
    }
  }
  __syncthreads();
  floatx4 acc[5];
#pragma unroll
  for (int i = 0; i < 5; ++i) acc[i] = (floatx4){0.f, 0.f, 0.f, 0.f};
#pragma unroll
  for (int ks = 0; ks < 4; ++ks) {
    int kk = ks * 32 + q * 8;
    half8 a = *(const half8*)&sX[w * 16 + m][kk];
#pragma unroll
    for (int t5 = 0; t5 < 5; ++t5) {
      half8 b = *(const half8*)&sW[t5 * 16 + m][kk];
      acc[t5] = __builtin_amdgcn_mfma_f32_16x16x32_f16(a, b, acc[t5], 0, 0, 0);
    }
  }
#pragma unroll
  for (int t5 = 0; t5 < 5; ++t5) {
    int col = t5 * 16 + m;
#pragma unroll
    for (int i = 0; i < 4; ++i) {
      int row = row0 + w * 16 + q * 4 + i;
      if (row >= N_NODES) continue;
      if (col < 40) {
        p[(size_t)row * 40 + col] = __float2half_rn(out_norm[row] * acc[t5][i]);
      } else {
        out[(size_t)row * 40 + (col - 40)] = acc[t5][i] + b2[col - 40];
      }
    }
  }
}

// ---------------- layer-2 aggregation (fp16 gather): out[d] += in_norm[d] * sum_e p[src]
__global__ void k_agg40h(const __half* __restrict__ p, const int* __restrict__ col,
                         const int* __restrict__ row_start,
                         const float* __restrict__ in_norm,
                         float* __restrict__ out) {
  int wave = threadIdx.x >> 6, lane = threadIdx.x & 63;
  int node = blockIdx.x * 4 + wave;
  if (node >= N_NODES) return;
  int s0 = row_start[node], s1 = row_start[node + 1];
  float a0 = 0.f, a1 = 0.f, a2 = 0.f, a3 = 0.f;
  int e = s0;
  for (; e + 4 <= s1; e += 4) {
    int sA = col[e], sB = col[e + 1], sC = col[e + 2], sD = col[e + 3];
    float vA = __half2float(p[(size_t)sA * 40 + lane]);
    float vB = __half2float(p[(size_t)sB * 40 + lane]);
    float vC = __half2float(p[(size_t)sC * 40 + lane]);
    float vD = __half2float(p[(size_t)sD * 40 + lane]);
    a0 += vA; a1 += vB; a2 += vC; a3 += vD;
  }
  for (; e < s1; ++e) {
    a0 += __half2float(p[(size_t)col[e] * 40 + lane]);
  }
  if (lane < 40) out[(size_t)node * 40 + lane] += in_norm[node] * ((a0 + a1) + (a2 + a3));
}

extern "C" void kernel_launch(void* const* d_in, const int* in_sizes, int n_in,
                              void* d_out, int out_size, void* d_ws, size_t ws_size,
                              hipStream_t stream) {
  const float* feat = (const float*)d_in[0];
  const int* src = (const int*)d_in[1];
  const int* dst = (const int*)d_in[2];
  const float* w0 = (const float*)d_in[3];
  const float* w1 = (const float*)d_in[4];
  const float* w2 = (const float*)d_in[5];
  const float* b2 = (const float*)d_in[6];
  const float* l0 = (const float*)d_in[7];
  const float* l1 = (const float*)d_in[8];
  const float* l2 = (const float*)d_in[9];
  const float* g0 = (const float*)d_in[10];
  const float* beta0 = (const float*)d_in[11];
  const float* g1 = (const float*)d_in[12];
  const float* beta1 = (const float*)d_in[13];
  float* out = (float*)d_out;

  char* ws = (char*)d_ws;
  size_t off = 0;
  auto alloc = [&](size_t bytes) {
    void* ptr = ws + off;
    off = (off + bytes + 255) & ~(size_t)255;
    return ptr;
  };
  unsigned short* A16 = (unsigned short*)alloc(2 * (size_t)N_NODES * 128);  // agg out / p
  float* B = (float*)alloc(sizeof(float) * (size_t)N_NODES * 128);          // Hpart (prep) / B16
  unsigned short* H = (unsigned short*)alloc(2 * (size_t)N_NODES * 128);    // scaled fp16 gather table
  unsigned short* F = (unsigned short*)alloc(2 * (size_t)N_NODES * 128);    // unscaled fp16 gemm table
  int* degs = (int*)alloc(sizeof(int) * N_NODES);
  int* degd = (int*)alloc(sizeof(int) * N_NODES);
  int* row_start = (int*)alloc(sizeof(int) * (N_NODES + 1));
  int* colb = (int*)alloc(sizeof(int) * N_EDGES);
  float* out_norm = (float*)alloc(sizeof(float) * N_NODES);
  float* in_norm = (float*)alloc(sizeof(float) * N_NODES);
  int* bsum = (int*)alloc(sizeof(int) * 512);
  float* stats = (float*)alloc(sizeof(float) * 256);

  // Hpart (4*128*16384 uints = 33.6 MB) aliases B (51.2 MB): consumed by k_build,
  // B's first write is k_gemm_dual16 afterwards. B16 = fp16 view of B.
  unsigned int* Hpart = (unsigned int*)B;
  unsigned short* B16 = (unsigned short*)B;

  int nb = (N_NODES + 255) / 256;  // 391
  int hb = HCH * HRG;              // 512

  k_hist_part<<<hb, 256, 0, stream>>>(src, Hpart);
  k_hist_sum<<<nb, 256, 0, stream>>>((const unsigned short*)Hpart, degs);
  k_hist_part<<<hb, 256, 0, stream>>>(dst, Hpart);
  k_hist_scan<<<nb, 256, 0, stream>>>((unsigned short*)Hpart, degd);  // -> per-chunk bases
  k_norms<<<nb, 256, 0, stream>>>(degs, degd, out_norm, in_norm);
  k_scan1<<<nb, 256, 0, stream>>>(degd, bsum);
  k_scan2<<<1, 512, 0, stream>>>(bsum, nb);
  k_scan3<<<nb, 256, 0, stream>>>(degd, bsum, row_start);
  k_build<<<hb, 256, 0, stream>>>(src, dst, (const unsigned short*)Hpart, row_start, colb);

  int ab = (N_NODES + 3) / 4;   // wave per node
  int gb = (N_NODES + 63) / 64;
  int fb = (N_NODES * 32 + 255) / 256;
  int hb16 = (N_NODES * 16 + 255) / 256;

  // layer 0: h1 = relu(bn(agg(feat)@w0^T + feat@l0^T))
  k_feat2h<<<fb, 256, 0, stream>>>(feat, out_norm, H, F);
  k_agg128h<<<ab, 256, 0, stream>>>((const __half*)H, colb, row_start, in_norm, A16);
  hipMemsetAsync(stats, 0, sizeof(float) * 256, stream);
  k_gemm_dual16<<<gb, 256, 0, stream>>>(A16, F, w0, l0, B16, stats);
  k_bnrelu16<<<hb16, 256, 0, stream>>>(B16, stats, g0, beta0, out_norm, H, F);

  // layer 1: h2 = relu(bn(agg(h1)@w1^T + h1@l1^T))
  k_agg128h<<<ab, 256, 0, stream>>>((const __half*)H, colb, row_start, in_norm, A16);
  hipMemsetAsync(stats, 0, sizeof(float) * 256, stream);
  k_gemm_dual16<<<gb, 256, 0, stream>>>(A16, F, w1, l1, B16, stats);
  k_bnrelu16<<<hb16, 256, 0, stream>>>(B16, stats, g1, beta1, out_norm,
                                       (unsigned short*)nullptr, F);  // F = fp16 h2

  // layer 2: out = in_norm*agg(fp16(out_norm*(h2@w2^T))) + b2 + h2@l2^T
  __half* p = (__half*)A16;  // A16 dead after layer-1 gemm
  k_gemm2_16<<<gb, 256, 0, stream>>>(F, w2, l2, b2, out_norm, p, out);
  k_agg40h<<<ab, 256, 0, stream>>>(p, colb, row_start, in_norm, out);
}

// Round 10
// 598.411 us; speedup vs baseline: 2.0677x; 1.0509x over previous
//
#include <hip/hip_runtime.h>
#include <hip/hip_fp16.h>
#include <cstdint>
#include <cstddef>

#define N_NODES 100000
#define N_EDGES 1600000
#define EPS 1e-5f

typedef _Float16 half8 __attribute__((ext_vector_type(8)));
typedef float floatx4 __attribute__((ext_vector_type(4)));

// LDS-binned histogram: ushort counters packed 2/uint (per-chunk count <= 12500 < 65536).
#define HCH 128                  // edge chunks
#define HRG 4                    // bin ranges
#define HBINS 32768              // ushort bins per range
#define HWORDS (HBINS / 2)       // 16384 uints = 64 KB LDS
#define HCHUNK (N_EDGES / HCH)   // 12500 edges per chunk
#define HCHUNK4 (HCHUNK / 4)     // 3125 int4 per chunk

// ---------------- graph prep (no device-scope atomics) ----------------
__global__ void k_hist_part(const int* __restrict__ keys, unsigned int* __restrict__ Hpart) {
  __shared__ unsigned int bins[HWORDS];
  int c = blockIdx.x % HCH, r = blockIdx.x / HCH;
  int base = r * HBINS;
  for (int i = threadIdx.x; i < HWORDS; i += 256) bins[i] = 0;
  __syncthreads();
  const int4* k4 = (const int4*)(keys + c * HCHUNK);
  for (int i = threadIdx.x; i < HCHUNK4; i += 256) {
    int4 k = k4[i];
    int a;
    a = k.x - base; if ((unsigned)a < (unsigned)HBINS) atomicAdd(&bins[a >> 1], 1u << ((a & 1) * 16));
    a = k.y - base; if ((unsigned)a < (unsigned)HBINS) atomicAdd(&bins[a >> 1], 1u << ((a & 1) * 16));
    a = k.z - base; if ((unsigned)a < (unsigned)HBINS) atomicAdd(&bins[a >> 1], 1u << ((a & 1) * 16));
    a = k.w - base; if ((unsigned)a < (unsigned)HBINS) atomicAdd(&bins[a >> 1], 1u << ((a & 1) * 16));
  }
  __syncthreads();
  unsigned int* outp = Hpart + ((size_t)blockIdx.x << 14);
  for (int i = threadIdx.x; i < HWORDS; i += 256) outp[i] = bins[i];
}

__global__ void k_hist_sum(const unsigned short* __restrict__ Hp, int* __restrict__ deg) {
  int b = blockIdx.x * 256 + threadIdx.x;
  if (b >= N_NODES) return;
  int r = b >> 15, lo = b & (HBINS - 1);
  const unsigned short* p = Hp + ((size_t)(r * HCH) << 15) + lo;
  unsigned int t = 0;
#pragma unroll 8
  for (int c = 0; c < HCH; ++c) t += p[(size_t)c << 15];
  deg[b] = (int)t;
}

__global__ void k_hist_scan(unsigned short* __restrict__ Hp, int* __restrict__ degd) {
  int b = blockIdx.x * 256 + threadIdx.x;
  if (b >= N_NODES) return;
  int r = b >> 15, lo = b & (HBINS - 1);
  unsigned short* p = Hp + ((size_t)(r * HCH) << 15) + lo;
  unsigned int t = 0;
#pragma unroll 8
  for (int c = 0; c < HCH; ++c) {
    unsigned int v = p[(size_t)c << 15];
    p[(size_t)c << 15] = (unsigned short)t;
    t += v;
  }
  degd[b] = (int)t;
}

__global__ void k_build(const int* __restrict__ src, const int* __restrict__ dst,
                        const unsigned short* __restrict__ Hbase,
                        const int* __restrict__ row_start, int* __restrict__ col) {
  __shared__ unsigned int cur[HWORDS];
  int c = blockIdx.x % HCH, r = blockIdx.x / HCH;
  int base = r * HBINS;
  for (int i = threadIdx.x; i < HWORDS; i += 256) cur[i] = 0;
  __syncthreads();
  const unsigned short* hb = Hbase + ((size_t)blockIdx.x << 15);
  const int4* d4 = (const int4*)(dst + c * HCHUNK);
  const int4* s4 = (const int4*)(src + c * HCHUNK);
  for (int i = threadIdx.x; i < HCHUNK4; i += 256) {
    int4 d = d4[i];
    int4 s = s4[i];
    int a;
    a = d.x - base;
    if ((unsigned)a < (unsigned)HBINS) {
      unsigned old = atomicAdd(&cur[a >> 1], 1u << ((a & 1) * 16));
      unsigned lr = (old >> ((a & 1) * 16)) & 0xffffu;
      col[row_start[d.x] + hb[a] + lr] = s.x;
    }
    a = d.y - base;
    if ((unsigned)a < (unsigned)HBINS) {
      unsigned old = atomicAdd(&cur[a >> 1], 1u << ((a & 1) * 16));
      unsigned lr = (old >> ((a & 1) * 16)) & 0xffffu;
      col[row_start[d.y] + hb[a] + lr] = s.y;
    }
    a = d.z - base;
    if ((unsigned)a < (unsigned)HBINS) {
      unsigned old = atomicAdd(&cur[a >> 1], 1u << ((a & 1) * 16));
      unsigned lr = (old >> ((a & 1) * 16)) & 0xffffu;
      col[row_start[d.z] + hb[a] + lr] = s.z;
    }
    a = d.w - base;
    if ((unsigned)a < (unsigned)HBINS) {
      unsigned old = atomicAdd(&cur[a >> 1], 1u << ((a & 1) * 16));
      unsigned lr = (old >> ((a & 1) * 16)) & 0xffffu;
      col[row_start[d.w] + hb[a] + lr] = s.w;
    }
  }
}

__global__ void k_norms(const int* __restrict__ degs, const int* __restrict__ degd,
                        float* out_norm, float* in_norm) {
  int i = blockIdx.x * 256 + threadIdx.x;
  if (i < N_NODES) {
    out_norm[i] = rsqrtf((float)max(degs[i], 1));
    in_norm[i]  = rsqrtf((float)max(degd[i], 1));
  }
}

__global__ void k_scan1(const int* __restrict__ degd, int* bsum) {
  __shared__ int s[256];
  int t = threadIdx.x;
  int i = blockIdx.x * 256 + t;
  s[t] = (i < N_NODES) ? degd[i] : 0;
  __syncthreads();
  for (int off = 128; off > 0; off >>= 1) {
    if (t < off) s[t] += s[t + off];
    __syncthreads();
  }
  if (t == 0) bsum[blockIdx.x] = s[0];
}

__global__ void k_scan2(int* bsum, int nb) {
  __shared__ int s[512];
  int t = threadIdx.x;
  int v = (t < nb) ? bsum[t] : 0;
  s[t] = v;
  __syncthreads();
  for (int off = 1; off < 512; off <<= 1) {
    int x = (t >= off) ? s[t - off] : 0;
    __syncthreads();
    s[t] += x;
    __syncthreads();
  }
  if (t < nb) bsum[t] = s[t] - v;  // exclusive
}

__global__ void k_scan3(const int* __restrict__ degd, const int* __restrict__ bsum,
                        int* row_start) {
  __shared__ int s[256];
  int t = threadIdx.x;
  int i = blockIdx.x * 256 + t;
  int v = (i < N_NODES) ? degd[i] : 0;
  s[t] = v;
  __syncthreads();
  for (int off = 1; off < 256; off <<= 1) {
    int x = (t >= off) ? s[t - off] : 0;
    __syncthreads();
    s[t] += x;
    __syncthreads();
  }
  if (i < N_NODES) row_start[i] = bsum[blockIdx.x] + s[t] - v;
  if (i == 0) row_start[N_NODES] = N_EDGES;
}

// ---------------- feat -> fp16 tables ----------------
__global__ void k_feat2h(const float* __restrict__ feat, const float* __restrict__ out_norm,
                         unsigned short* __restrict__ H, unsigned short* __restrict__ F) {
  int i = blockIdx.x * 256 + threadIdx.x;  // float4 index
  if (i >= N_NODES * 32) return;
  float on = out_norm[i >> 5];
  float4 v = ((const float4*)feat)[i];
  ushort4 s, u;
  s.x = __half_as_ushort(__float2half_rn(v.x * on));
  s.y = __half_as_ushort(__float2half_rn(v.y * on));
  s.z = __half_as_ushort(__float2half_rn(v.z * on));
  s.w = __half_as_ushort(__float2half_rn(v.w * on));
  u.x = __half_as_ushort(__float2half_rn(v.x));
  u.y = __half_as_ushort(__float2half_rn(v.y));
  u.z = __half_as_ushort(__float2half_rn(v.z));
  u.w = __half_as_ushort(__float2half_rn(v.w));
  ((ushort4*)H)[i] = s;
  ((ushort4*)F)[i] = u;
}

// ---------------- aggregation (fp16 gather, unroll 8) ----------------
__global__ void k_agg128h(const __half* __restrict__ H, const int* __restrict__ col,
                          const int* __restrict__ row_start,
                          const float* __restrict__ in_norm,
                          unsigned short* __restrict__ out16) {
  int wave = threadIdx.x >> 6;
  int lane = threadIdx.x & 63;
  int node = blockIdx.x * 4 + wave;
  if (node >= N_NODES) return;
  int s0 = row_start[node], s1 = row_start[node + 1];
  const unsigned int* hp = (const unsigned int*)H;
  float ax[8], ay[8];
#pragma unroll
  for (int j = 0; j < 8; ++j) { ax[j] = 0.f; ay[j] = 0.f; }
  int e = s0;
  for (; e + 8 <= s1; e += 8) {
    unsigned int u[8];
#pragma unroll
    for (int j = 0; j < 8; ++j) u[j] = hp[(size_t)col[e + j] * 64 + lane];
#pragma unroll
    for (int j = 0; j < 8; ++j) {
      float2 v = __half22float2(*(const __half2*)&u[j]);
      ax[j] += v.x; ay[j] += v.y;
    }
  }
  for (; e < s1; ++e) {
    unsigned int u = hp[(size_t)col[e] * 64 + lane];
    float2 v = __half22float2(*(const __half2*)&u);
    ax[0] += v.x; ay[0] += v.y;
  }
  float sc = in_norm[node];
  float rx = (((ax[0] + ax[1]) + (ax[2] + ax[3])) + ((ax[4] + ax[5]) + (ax[6] + ax[7]))) * sc;
  float ry = (((ay[0] + ay[1]) + (ay[2] + ay[3])) + ((ay[4] + ay[5]) + (ay[6] + ay[7]))) * sc;
  __half2 r2 = __float22half2_rn(make_float2(rx, ry));
  ((unsigned int*)out16)[(size_t)node * 64 + lane] = *(const unsigned int*)&r2;
}

// ---------------- MFMA dual GEMM + fused BN stats (contention-free epilogue)
// Out16 = fp16(Xa@Wa^T + Xh@Wh^T); stats[c] += col-sum, stats[128+c] += col-sumsq.
// Stats path: shfl-xor reduce the 4 same-column lane copies in-register, per-wave
// partials into reused sX LDS (dead after MFMA), block reduce, 1 global atomic pair/col.
__launch_bounds__(256)
__global__ void k_gemm_dual16(const unsigned short* __restrict__ Xa,
                              const unsigned short* __restrict__ Xh,
                              const float* __restrict__ Wa, const float* __restrict__ Wh,
                              unsigned short* __restrict__ Out16, float* __restrict__ stats) {
  __shared__ __align__(16) unsigned short sX[64][136];
  __shared__ __align__(16) unsigned short sW[128][136];
  int t = threadIdx.x;
  int row0 = blockIdx.x * 64;
  int w = t >> 6, lane = t & 63;
  int q = lane >> 4, m = lane & 15;
  floatx4 acc[8];
#pragma unroll
  for (int i = 0; i < 8; ++i) acc[i] = (floatx4){0.f, 0.f, 0.f, 0.f};

  for (int phase = 0; phase < 2; ++phase) {
    const unsigned short* Xg = phase ? Xh : Xa;
    const float* Wg = phase ? Wh : Wa;
    __syncthreads();
    {
      int r = t >> 2;
      int c0 = (t & 3) * 4;
      const uint4* xr = (const uint4*)(Xg + (size_t)min(row0 + r, N_NODES - 1) * 128);
#pragma unroll
      for (int it = 0; it < 4; ++it) {
        uint4 v = xr[c0 + it];
        *(uint4*)&sX[r][(c0 + it) * 8] = v;
      }
    }
    {
      int n = t >> 1, h = (t & 1) * 64;
      const float4* wr = (const float4*)(Wg + (size_t)n * 128 + h);
#pragma unroll
      for (int it = 0; it < 16; ++it) {
        float4 v = wr[it];
        ushort4 o;
        o.x = __half_as_ushort(__float2half_rn(v.x));
        o.y = __half_as_ushort(__float2half_rn(v.y));
        o.z = __half_as_ushort(__float2half_rn(v.z));
        o.w = __half_as_ushort(__float2half_rn(v.w));
        *(ushort4*)&sW[n][h + it * 4] = o;
      }
    }
    __syncthreads();
#pragma unroll
    for (int ks = 0; ks < 4; ++ks) {
      int kk = ks * 32 + q * 8;
      half8 a = *(const half8*)&sX[w * 16 + m][kk];
#pragma unroll
      for (int t8 = 0; t8 < 8; ++t8) {
        half8 b = *(const half8*)&sW[t8 * 16 + m][kk];
        acc[t8] = __builtin_amdgcn_mfma_f32_16x16x32_f16(a, b, acc[t8], 0, 0, 0);
      }
    }
  }
  // Epilogue: Out16 stores + per-column partial stats, contention-free.
  float ps[8], pq[8];
#pragma unroll
  for (int t8 = 0; t8 < 8; ++t8) {
    int colj = t8 * 16 + m;
    float s = 0.f, sq = 0.f;
#pragma unroll
    for (int i = 0; i < 4; ++i) {
      int row = row0 + w * 16 + q * 4 + i;
      if (row < N_NODES) {
        float v = acc[t8][i];
        s += v; sq += v * v;
        Out16[(size_t)row * 128 + colj] = __half_as_ushort(__float2half_rn(v));
      }
    }
    // reduce the 4 lane copies of colj (lanes m, m+16, m+32, m+48)
    s += __shfl_xor(s, 16);
    s += __shfl_xor(s, 32);
    sq += __shfl_xor(sq, 16);
    sq += __shfl_xor(sq, 32);
    ps[t8] = s; pq[t8] = sq;
  }
  __syncthreads();  // all MFMA reads of sX done -> safe to alias
  float* pSum = (float*)&sX[0][0];       // [4][128]
  float* pSq = pSum + 512;               // [4][128]
  if (q == 0) {
#pragma unroll
    for (int t8 = 0; t8 < 8; ++t8) {
      pSum[w * 128 + t8 * 16 + m] = ps[t8];
      pSq[w * 128 + t8 * 16 + m] = pq[t8];
    }
  }
  __syncthreads();
  if (t < 128) {
    float s = (pSum[t] + pSum[128 + t]) + (pSum[256 + t] + pSum[384 + t]);
    float sq = (pSq[t] + pSq[128 + t]) + (pSq[256 + t] + pSq[384 + t]);
    atomicAdd(&stats[t], s);
    atomicAdd(&stats[128 + t], sq);
  }
}

// ---------------- BN+ReLU on fp16 input; emits H (scaled) and/or F (unscaled) fp16 tables.
__global__ void k_bnrelu16(const unsigned short* __restrict__ x16,
                           const float* __restrict__ stats,
                           const float* __restrict__ g, const float* __restrict__ b,
                           const float* __restrict__ out_norm,
                           unsigned short* __restrict__ H, unsigned short* __restrict__ F) {
  int i = blockIdx.x * 256 + threadIdx.x;  // ushort8 index
  if (i >= N_NODES * 16) return;
  int c8 = (i & 15) * 8;
  uint4 raw = ((const uint4*)x16)[i];
  const __half2* hp2 = (const __half2*)&raw;
  float v[8];
#pragma unroll
  for (int j = 0; j < 4; ++j) {
    float2 f = __half22float2(hp2[j]);
    v[2 * j] = f.x;
    v[2 * j + 1] = f.y;
  }
  const float inv = 1.f / (float)N_NODES;
#pragma unroll
  for (int j = 0; j < 8; ++j) {
    int c = c8 + j;
    float mu = stats[c] * inv;
    float var = stats[128 + c] * inv - mu * mu;
    float rs = rsqrtf(var + EPS);
    float y = (v[j] - mu) * rs * g[c] + b[c];
    v[j] = y > 0.f ? y : 0.f;
  }
  if (H) {
    float on = out_norm[i >> 4];
    ushort4 o[2];
#pragma unroll
    for (int j = 0; j < 8; ++j) ((unsigned short*)o)[j] = __half_as_ushort(__float2half_rn(v[j] * on));
    ((uint4*)H)[i] = *(const uint4*)o;
  }
  if (F) {
    ushort4 o[2];
#pragma unroll
    for (int j = 0; j < 8; ++j) ((unsigned short*)o)[j] = __half_as_ushort(__float2half_rn(v[j]));
    ((uint4*)F)[i] = *(const uint4*)o;
  }
}

// ---------------- MFMA layer-2 GEMM: p = fp16(out_norm*(X@w2^T)), out = X@l2^T + b2
__launch_bounds__(256)
__global__ void k_gemm2_16(const unsigned short* __restrict__ X,
                           const float* __restrict__ w2, const float* __restrict__ l2,
                           const float* __restrict__ b2,
                           const float* __restrict__ out_norm,
                           __half* __restrict__ p, float* __restrict__ out) {
  __shared__ __align__(16) unsigned short sX[64][136];
  __shared__ __align__(16) unsigned short sW[80][136];
  int t = threadIdx.x;
  int row0 = blockIdx.x * 64;
  int w = t >> 6, lane = t & 63;
  int q = lane >> 4, m = lane & 15;
  {
    int r = t >> 2;
    int c0 = (t & 3) * 4;
    const uint4* xr = (const uint4*)(X + (size_t)min(row0 + r, N_NODES - 1) * 128);
#pragma unroll
    for (int it = 0; it < 4; ++it) {
      uint4 v = xr[c0 + it];
      *(uint4*)&sX[r][(c0 + it) * 8] = v;
    }
  }
  {
#pragma unroll
    for (int it = 0; it < 10; ++it) {
      int i = it * 256 + t;   // float4 index 0..2559
      int j = i >> 5;         // weight row 0..79
      int kq = i & 31;
      const float* srcp = (j < 40) ? (w2 + (size_t)j * 128) : (l2 + (size_t)(j - 40) * 128);
      float4 v = ((const float4*)srcp)[kq];
      ushort4 o;
      o.x = __half_as_ushort(__float2half_rn(v.x));
      o.y = __half_as_ushort(__float2half_rn(v.y));
      o.z = __half_as_ushort(__float2half_rn(v.z));
      o.w = __half_as_ushort(__float2half_rn(v.w));
      *(ushort4*)&sW[j][kq * 4] = o;
    }
  }
  __syncthreads();
  floatx4 acc[5];
#pragma unroll
  for (int i = 0; i < 5; ++i) acc[i] = (floatx4){0.f, 0.f, 0.f, 0.f};
#pragma unroll
  for (int ks = 0; ks < 4; ++ks) {
    int kk = ks * 32 + q * 8;
    half8 a = *(const half8*)&sX[w * 16 + m][kk];
#pragma unroll
    for (int t5 = 0; t5 < 5; ++t5) {
      half8 b = *(const half8*)&sW[t5 * 16 + m][kk];
      acc[t5] = __builtin_amdgcn_mfma_f32_16x16x32_f16(a, b, acc[t5], 0, 0, 0);
    }
  }
#pragma unroll
  for (int t5 = 0; t5 < 5; ++t5) {
    int col = t5 * 16 + m;
#pragma unroll
    for (int i = 0; i < 4; ++i) {
      int row = row0 + w * 16 + q * 4 + i;
      if (row >= N_NODES) continue;
      if (col < 40) {
        p[(size_t)row * 40 + col] = __float2half_rn(out_norm[row] * acc[t5][i]);
      } else {
        out[(size_t)row * 40 + (col - 40)] = acc[t5][i] + b2[col - 40];
      }
    }
  }
}

// ---------------- layer-2 aggregation (fp16 gather): out[d] += in_norm[d] * sum_e p[src]
__global__ void k_agg40h(const __half* __restrict__ p, const int* __restrict__ col,
                         const int* __restrict__ row_start,
                         const float* __restrict__ in_norm,
                         float* __restrict__ out) {
  int wave = threadIdx.x >> 6, lane = threadIdx.x & 63;
  int node = blockIdx.x * 4 + wave;
  if (node >= N_NODES) return;
  int s0 = row_start[node], s1 = row_start[node + 1];
  float a0 = 0.f, a1 = 0.f, a2 = 0.f, a3 = 0.f;
  int e = s0;
  for (; e + 4 <= s1; e += 4) {
    int sA = col[e], sB = col[e + 1], sC = col[e + 2], sD = col[e + 3];
    float vA = __half2float(p[(size_t)sA * 40 + lane]);
    float vB = __half2float(p[(size_t)sB * 40 + lane]);
    float vC = __half2float(p[(size_t)sC * 40 + lane]);
    float vD = __half2float(p[(size_t)sD * 40 + lane]);
    a0 += vA; a1 += vB; a2 += vC; a3 += vD;
  }
  for (; e < s1; ++e) {
    a0 += __half2float(p[(size_t)col[e] * 40 + lane]);
  }
  if (lane < 40) out[(size_t)node * 40 + lane] += in_norm[node] * ((a0 + a1) + (a2 + a3));
}

extern "C" void kernel_launch(void* const* d_in, const int* in_sizes, int n_in,
                              void* d_out, int out_size, void* d_ws, size_t ws_size,
                              hipStream_t stream) {
  const float* feat = (const float*)d_in[0];
  const int* src = (const int*)d_in[1];
  const int* dst = (const int*)d_in[2];
  const float* w0 = (const float*)d_in[3];
  const float* w1 = (const float*)d_in[4];
  const float* w2 = (const float*)d_in[5];
  const float* b2 = (const float*)d_in[6];
  const float* l0 = (const float*)d_in[7];
  const float* l1 = (const float*)d_in[8];
  const float* l2 = (const float*)d_in[9];
  const float* g0 = (const float*)d_in[10];
  const float* beta0 = (const float*)d_in[11];
  const float* g1 = (const float*)d_in[12];
  const float* beta1 = (const float*)d_in[13];
  float* out = (float*)d_out;

  char* ws = (char*)d_ws;
  size_t off = 0;
  auto alloc = [&](size_t bytes) {
    void* ptr = ws + off;
    off = (off + bytes + 255) & ~(size_t)255;
    return ptr;
  };
  unsigned short* A16 = (unsigned short*)alloc(2 * (size_t)N_NODES * 128);  // agg out / p
  float* B = (float*)alloc(sizeof(float) * (size_t)N_NODES * 128);          // Hpart (prep) / B16
  unsigned short* H = (unsigned short*)alloc(2 * (size_t)N_NODES * 128);    // scaled fp16 gather table
  unsigned short* F = (unsigned short*)alloc(2 * (size_t)N_NODES * 128);    // unscaled fp16 gemm table
  int* degs = (int*)alloc(sizeof(int) * N_NODES);
  int* degd = (int*)alloc(sizeof(int) * N_NODES);
  int* row_start = (int*)alloc(sizeof(int) * (N_NODES + 1));
  int* colb = (int*)alloc(sizeof(int) * N_EDGES);
  float* out_norm = (float*)alloc(sizeof(float) * N_NODES);
  float* in_norm = (float*)alloc(sizeof(float) * N_NODES);
  int* bsum = (int*)alloc(sizeof(int) * 512);
  float* stats = (float*)alloc(sizeof(float) * 256);

  // Hpart (33.6 MB) aliases B (51.2 MB): consumed by k_build before B's first write.
  unsigned int* Hpart = (unsigned int*)B;
  unsigned short* B16 = (unsigned short*)B;

  int nb = (N_NODES + 255) / 256;  // 391
  int hb = HCH * HRG;              // 512

  k_hist_part<<<hb, 256, 0, stream>>>(src, Hpart);
  k_hist_sum<<<nb, 256, 0, stream>>>((const unsigned short*)Hpart, degs);
  k_hist_part<<<hb, 256, 0, stream>>>(dst, Hpart);
  k_hist_scan<<<nb, 256, 0, stream>>>((unsigned short*)Hpart, degd);  // -> per-chunk bases
  k_norms<<<nb, 256, 0, stream>>>(degs, degd, out_norm, in_norm);
  k_scan1<<<nb, 256, 0, stream>>>(degd, bsum);
  k_scan2<<<1, 512, 0, stream>>>(bsum, nb);
  k_scan3<<<nb, 256, 0, stream>>>(degd, bsum, row_start);
  k_build<<<hb, 256, 0, stream>>>(src, dst, (const unsigned short*)Hpart, row_start, colb);

  int ab = (N_NODES + 3) / 4;   // wave per node
  int gb = (N_NODES + 63) / 64;
  int fb = (N_NODES * 32 + 255) / 256;
  int hb16 = (N_NODES * 16 + 255) / 256;

  // layer 0: h1 = relu(bn(agg(feat)@w0^T + feat@l0^T))
  k_feat2h<<<fb, 256, 0, stream>>>(feat, out_norm, H, F);
  k_agg128h<<<ab, 256, 0, stream>>>((const __half*)H, colb, row_start, in_norm, A16);
  hipMemsetAsync(stats, 0, sizeof(float) * 256, stream);
  k_gemm_dual16<<<gb, 256, 0, stream>>>(A16, F, w0, l0, B16, stats);
  k_bnrelu16<<<hb16, 256, 0, stream>>>(B16, stats, g0, beta0, out_norm, H, F);

  // layer 1: h2 = relu(bn(agg(h1)@w1^T + h1@l1^T))
  k_agg128h<<<ab, 256, 0, stream>>>((const __half*)H, colb, row_start, in_norm, A16);
  hipMemsetAsync(stats, 0, sizeof(float) * 256, stream);
  k_gemm_dual16<<<gb, 256, 0, stream>>>(A16, F, w1, l1, B16, stats);
  k_bnrelu16<<<hb16, 256, 0, stream>>>(B16, stats, g1, beta1, out_norm,
                                       (unsigned short*)nullptr, F);  // F = fp16 h2

  // layer 2: out = in_norm*agg(fp16(out_norm*(h2@w2^T))) + b2 + h2@l2^T
  __half* p = (__half*)A16;  // A16 dead after layer-1 gemm
  k_gemm2_16<<<gb, 256, 0, stream>>>(F, w2, l2, b2, out_norm, p, out);
  k_agg40h<<<ab, 256, 0, stream>>>(p, colb, row_start, in_norm, out);
}

// Round 11
// 575.038 us; speedup vs baseline: 2.1517x; 1.0406x over previous
//
#include <hip/hip_runtime.h>
#include <hip/hip_fp16.h>
#include <cstdint>
#include <cstddef>

#define N_NODES 100000
#define N_EDGES 1600000
#define EPS 1e-5f

typedef _Float16 half8 __attribute__((ext_vector_type(8)));
typedef float floatx4 __attribute__((ext_vector_type(4)));

// LDS-binned histogram: ushort counters packed 2/uint (per-chunk count <= 12500 < 65536).
#define HCH 128                  // edge chunks
#define HRG 4                    // bin ranges
#define HBINS 32768              // ushort bins per range
#define HWORDS (HBINS / 2)       // 16384 uints = 64 KB LDS
#define HCHUNK (N_EDGES / HCH)   // 12500 edges per chunk
#define HCHUNK4 (HCHUNK / 4)     // 3125 int4 per chunk

// ---------------- graph prep (no device-scope atomics) ----------------
__global__ void k_hist_part(const int* __restrict__ keys, unsigned int* __restrict__ Hpart) {
  __shared__ unsigned int bins[HWORDS];
  int c = blockIdx.x % HCH, r = blockIdx.x / HCH;
  int base = r * HBINS;
  for (int i = threadIdx.x; i < HWORDS; i += 256) bins[i] = 0;
  __syncthreads();
  const int4* k4 = (const int4*)(keys + c * HCHUNK);
  for (int i = threadIdx.x; i < HCHUNK4; i += 256) {
    int4 k = k4[i];
    int a;
    a = k.x - base; if ((unsigned)a < (unsigned)HBINS) atomicAdd(&bins[a >> 1], 1u << ((a & 1) * 16));
    a = k.y - base; if ((unsigned)a < (unsigned)HBINS) atomicAdd(&bins[a >> 1], 1u << ((a & 1) * 16));
    a = k.z - base; if ((unsigned)a < (unsigned)HBINS) atomicAdd(&bins[a >> 1], 1u << ((a & 1) * 16));
    a = k.w - base; if ((unsigned)a < (unsigned)HBINS) atomicAdd(&bins[a >> 1], 1u << ((a & 1) * 16));
  }
  __syncthreads();
  unsigned int* outp = Hpart + ((size_t)blockIdx.x << 14);
  for (int i = threadIdx.x; i < HWORDS; i += 256) outp[i] = bins[i];
}

__global__ void k_hist_sum(const unsigned short* __restrict__ Hp, int* __restrict__ deg) {
  int b = blockIdx.x * 256 + threadIdx.x;
  if (b >= N_NODES) return;
  int r = b >> 15, lo = b & (HBINS - 1);
  const unsigned short* p = Hp + ((size_t)(r * HCH) << 15) + lo;
  unsigned int t = 0;
#pragma unroll 8
  for (int c = 0; c < HCH; ++c) t += p[(size_t)c << 15];
  deg[b] = (int)t;
}

__global__ void k_hist_scan(unsigned short* __restrict__ Hp, int* __restrict__ degd) {
  int b = blockIdx.x * 256 + threadIdx.x;
  if (b >= N_NODES) return;
  int r = b >> 15, lo = b & (HBINS - 1);
  unsigned short* p = Hp + ((size_t)(r * HCH) << 15) + lo;
  unsigned int t = 0;
#pragma unroll 8
  for (int c = 0; c < HCH; ++c) {
    unsigned int v = p[(size_t)c << 15];
    p[(size_t)c << 15] = (unsigned short)t;
    t += v;
  }
  degd[b] = (int)t;
}

__global__ void k_build(const int* __restrict__ src, const int* __restrict__ dst,
                        const unsigned short* __restrict__ Hbase,
                        const int* __restrict__ row_start, int* __restrict__ col) {
  __shared__ unsigned int cur[HWORDS];
  int c = blockIdx.x % HCH, r = blockIdx.x / HCH;
  int base = r * HBINS;
  for (int i = threadIdx.x; i < HWORDS; i += 256) cur[i] = 0;
  __syncthreads();
  const unsigned short* hb = Hbase + ((size_t)blockIdx.x << 15);
  const int4* d4 = (const int4*)(dst + c * HCHUNK);
  const int4* s4 = (const int4*)(src + c * HCHUNK);
  for (int i = threadIdx.x; i < HCHUNK4; i += 256) {
    int4 d = d4[i];
    int4 s = s4[i];
    int a;
    a = d.x - base;
    if ((unsigned)a < (unsigned)HBINS) {
      unsigned old = atomicAdd(&cur[a >> 1], 1u << ((a & 1) * 16));
      unsigned lr = (old >> ((a & 1) * 16)) & 0xffffu;
      col[row_start[d.x] + hb[a] + lr] = s.x;
    }
    a = d.y - base;
    if ((unsigned)a < (unsigned)HBINS) {
      unsigned old = atomicAdd(&cur[a >> 1], 1u << ((a & 1) * 16));
      unsigned lr = (old >> ((a & 1) * 16)) & 0xffffu;
      col[row_start[d.y] + hb[a] + lr] = s.y;
    }
    a = d.z - base;
    if ((unsigned)a < (unsigned)HBINS) {
      unsigned old = atomicAdd(&cur[a >> 1], 1u << ((a & 1) * 16));
      unsigned lr = (old >> ((a & 1) * 16)) & 0xffffu;
      col[row_start[d.z] + hb[a] + lr] = s.z;
    }
    a = d.w - base;
    if ((unsigned)a < (unsigned)HBINS) {
      unsigned old = atomicAdd(&cur[a >> 1], 1u << ((a & 1) * 16));
      unsigned lr = (old >> ((a & 1) * 16)) & 0xffffu;
      col[row_start[d.w] + hb[a] + lr] = s.w;
    }
  }
}

__global__ void k_norms(const int* __restrict__ degs, const int* __restrict__ degd,
                        float* out_norm, float* in_norm) {
  int i = blockIdx.x * 256 + threadIdx.x;
  if (i < N_NODES) {
    out_norm[i] = rsqrtf((float)max(degs[i], 1));
    in_norm[i]  = rsqrtf((float)max(degd[i], 1));
  }
}

__global__ void k_scan1(const int* __restrict__ degd, int* bsum) {
  __shared__ int s[256];
  int t = threadIdx.x;
  int i = blockIdx.x * 256 + t;
  s[t] = (i < N_NODES) ? degd[i] : 0;
  __syncthreads();
  for (int off = 128; off > 0; off >>= 1) {
    if (t < off) s[t] += s[t + off];
    __syncthreads();
  }
  if (t == 0) bsum[blockIdx.x] = s[0];
}

__global__ void k_scan2(int* bsum, int nb) {
  __shared__ int s[512];
  int t = threadIdx.x;
  int v = (t < nb) ? bsum[t] : 0;
  s[t] = v;
  __syncthreads();
  for (int off = 1; off < 512; off <<= 1) {
    int x = (t >= off) ? s[t - off] : 0;
    __syncthreads();
    s[t] += x;
    __syncthreads();
  }
  if (t < nb) bsum[t] = s[t] - v;  // exclusive
}

__global__ void k_scan3(const int* __restrict__ degd, const int* __restrict__ bsum,
                        int* row_start) {
  __shared__ int s[256];
  int t = threadIdx.x;
  int i = blockIdx.x * 256 + t;
  int v = (i < N_NODES) ? degd[i] : 0;
  s[t] = v;
  __syncthreads();
  for (int off = 1; off < 256; off <<= 1) {
    int x = (t >= off) ? s[t - off] : 0;
    __syncthreads();
    s[t] += x;
    __syncthreads();
  }
  if (i < N_NODES) row_start[i] = bsum[blockIdx.x] + s[t] - v;
  if (i == 0) row_start[N_NODES] = N_EDGES;
}

// ---------------- feat -> fp16 tables ----------------
__global__ void k_feat2h(const float* __restrict__ feat, const float* __restrict__ out_norm,
                         unsigned short* __restrict__ H, unsigned short* __restrict__ F) {
  int i = blockIdx.x * 256 + threadIdx.x;  // float4 index
  if (i >= N_NODES * 32) return;
  float on = out_norm[i >> 5];
  float4 v = ((const float4*)feat)[i];
  ushort4 s, u;
  s.x = __half_as_ushort(__float2half_rn(v.x * on));
  s.y = __half_as_ushort(__float2half_rn(v.y * on));
  s.z = __half_as_ushort(__float2half_rn(v.z * on));
  s.w = __half_as_ushort(__float2half_rn(v.w * on));
  u.x = __half_as_ushort(__float2half_rn(v.x));
  u.y = __half_as_ushort(__float2half_rn(v.y));
  u.z = __half_as_ushort(__float2half_rn(v.z));
  u.w = __half_as_ushort(__float2half_rn(v.w));
  ((ushort4*)H)[i] = s;
  ((ushort4*)F)[i] = u;
}

// ---------------- aggregation: quarter-wave gather (16 lanes x uint4 = one 256B row).
// One VMEM instruction gathers 4 edge rows (4 quarters); unroll 2 -> 8 rows in flight/wave.
__global__ void k_agg128h(const __half* __restrict__ H, const int* __restrict__ col,
                          const int* __restrict__ row_start,
                          const float* __restrict__ in_norm,
                          unsigned short* __restrict__ out16) {
  int wave = threadIdx.x >> 6;
  int lane = threadIdx.x & 63;
  int node = blockIdx.x * 4 + wave;
  if (node >= N_NODES) return;
  int q = lane >> 4;    // quarter 0..3 — each quarter walks edges s0+q, s0+q+4, ...
  int sub = lane & 15;  // 16 lanes x 16B cover the 256B row
  int s0 = row_start[node], s1 = row_start[node + 1];
  const uint4* hp = (const uint4*)H;  // row = 16 uint4
  float a[8];
#pragma unroll
  for (int j = 0; j < 8; ++j) a[j] = 0.f;
  int e = s0 + q;
  for (; e + 4 < s1; e += 8) {
    int c0 = col[e];
    int c1 = col[e + 4];
    uint4 u0 = hp[(size_t)c0 * 16 + sub];
    uint4 u1 = hp[(size_t)c1 * 16 + sub];
    const __half2* h0 = (const __half2*)&u0;
    const __half2* h1 = (const __half2*)&u1;
#pragma unroll
    for (int j = 0; j < 4; ++j) {
      float2 f0 = __half22float2(h0[j]);
      float2 f1 = __half22float2(h1[j]);
      a[2 * j] += f0.x + f1.x;
      a[2 * j + 1] += f0.y + f1.y;
    }
  }
  if (e < s1) {
    uint4 u = hp[(size_t)col[e] * 16 + sub];
    const __half2* h0 = (const __half2*)&u;
#pragma unroll
    for (int j = 0; j < 4; ++j) {
      float2 f = __half22float2(h0[j]);
      a[2 * j] += f.x;
      a[2 * j + 1] += f.y;
    }
  }
  // combine quarters (same sub -> same row components)
#pragma unroll
  for (int j = 0; j < 8; ++j) {
    a[j] += __shfl_xor(a[j], 16);
    a[j] += __shfl_xor(a[j], 32);
  }
  if (q == 0) {
    float sc = in_norm[node];
    __half2 o[4];
#pragma unroll
    for (int j = 0; j < 4; ++j)
      o[j] = __float22half2_rn(make_float2(a[2 * j] * sc, a[2 * j + 1] * sc));
    ((uint4*)out16)[(size_t)node * 16 + sub] = *(const uint4*)o;
  }
}

// ---------------- MFMA dual GEMM + fused BN stats (contention-free epilogue)
__launch_bounds__(256)
__global__ void k_gemm_dual16(const unsigned short* __restrict__ Xa,
                              const unsigned short* __restrict__ Xh,
                              const float* __restrict__ Wa, const float* __restrict__ Wh,
                              unsigned short* __restrict__ Out16, float* __restrict__ stats) {
  __shared__ __align__(16) unsigned short sX[64][136];
  __shared__ __align__(16) unsigned short sW[128][136];
  int t = threadIdx.x;
  int row0 = blockIdx.x * 64;
  int w = t >> 6, lane = t & 63;
  int q = lane >> 4, m = lane & 15;
  floatx4 acc[8];
#pragma unroll
  for (int i = 0; i < 8; ++i) acc[i] = (floatx4){0.f, 0.f, 0.f, 0.f};

  for (int phase = 0; phase < 2; ++phase) {
    const unsigned short* Xg = phase ? Xh : Xa;
    const float* Wg = phase ? Wh : Wa;
    __syncthreads();
    {
      int r = t >> 2;
      int c0 = (t & 3) * 4;
      const uint4* xr = (const uint4*)(Xg + (size_t)min(row0 + r, N_NODES - 1) * 128);
#pragma unroll
      for (int it = 0; it < 4; ++it) {
        uint4 v = xr[c0 + it];
        *(uint4*)&sX[r][(c0 + it) * 8] = v;
      }
    }
    {
      int n = t >> 1, h = (t & 1) * 64;
      const float4* wr = (const float4*)(Wg + (size_t)n * 128 + h);
#pragma unroll
      for (int it = 0; it < 16; ++it) {
        float4 v = wr[it];
        ushort4 o;
        o.x = __half_as_ushort(__float2half_rn(v.x));
        o.y = __half_as_ushort(__float2half_rn(v.y));
        o.z = __half_as_ushort(__float2half_rn(v.z));
        o.w = __half_as_ushort(__float2half_rn(v.w));
        *(ushort4*)&sW[n][h + it * 4] = o;
      }
    }
    __syncthreads();
#pragma unroll
    for (int ks = 0; ks < 4; ++ks) {
      int kk = ks * 32 + q * 8;
      half8 a = *(const half8*)&sX[w * 16 + m][kk];
#pragma unroll
      for (int t8 = 0; t8 < 8; ++t8) {
        half8 b = *(const half8*)&sW[t8 * 16 + m][kk];
        acc[t8] = __builtin_amdgcn_mfma_f32_16x16x32_f16(a, b, acc[t8], 0, 0, 0);
      }
    }
  }
  float ps[8], pq[8];
#pragma unroll
  for (int t8 = 0; t8 < 8; ++t8) {
    int colj = t8 * 16 + m;
    float s = 0.f, sq = 0.f;
#pragma unroll
    for (int i = 0; i < 4; ++i) {
      int row = row0 + w * 16 + q * 4 + i;
      if (row < N_NODES) {
        float v = acc[t8][i];
        s += v; sq += v * v;
        Out16[(size_t)row * 128 + colj] = __half_as_ushort(__float2half_rn(v));
      }
    }
    s += __shfl_xor(s, 16);
    s += __shfl_xor(s, 32);
    sq += __shfl_xor(sq, 16);
    sq += __shfl_xor(sq, 32);
    ps[t8] = s; pq[t8] = sq;
  }
  __syncthreads();  // all MFMA reads of sX done -> safe to alias
  float* pSum = (float*)&sX[0][0];       // [4][128]
  float* pSq = pSum + 512;               // [4][128]
  if (q == 0) {
#pragma unroll
    for (int t8 = 0; t8 < 8; ++t8) {
      pSum[w * 128 + t8 * 16 + m] = ps[t8];
      pSq[w * 128 + t8 * 16 + m] = pq[t8];
    }
  }
  __syncthreads();
  if (t < 128) {
    float s = (pSum[t] + pSum[128 + t]) + (pSum[256 + t] + pSum[384 + t]);
    float sq = (pSq[t] + pSq[128 + t]) + (pSq[256 + t] + pSq[384 + t]);
    atomicAdd(&stats[t], s);
    atomicAdd(&stats[128 + t], sq);
  }
}

// ---------------- BN+ReLU on fp16 input; emits H (scaled) and/or F (unscaled) fp16 tables.
__global__ void k_bnrelu16(const unsigned short* __restrict__ x16,
                           const float* __restrict__ stats,
                           const float* __restrict__ g, const float* __restrict__ b,
                           const float* __restrict__ out_norm,
                           unsigned short* __restrict__ H, unsigned short* __restrict__ F) {
  int i = blockIdx.x * 256 + threadIdx.x;  // ushort8 index
  if (i >= N_NODES * 16) return;
  int c8 = (i & 15) * 8;
  uint4 raw = ((const uint4*)x16)[i];
  const __half2* hp2 = (const __half2*)&raw;
  float v[8];
#pragma unroll
  for (int j = 0; j < 4; ++j) {
    float2 f = __half22float2(hp2[j]);
    v[2 * j] = f.x;
    v[2 * j + 1] = f.y;
  }
  const float inv = 1.f / (float)N_NODES;
#pragma unroll
  for (int j = 0; j < 8; ++j) {
    int c = c8 + j;
    float mu = stats[c] * inv;
    float var = stats[128 + c] * inv - mu * mu;
    float rs = rsqrtf(var + EPS);
    float y = (v[j] - mu) * rs * g[c] + b[c];
    v[j] = y > 0.f ? y : 0.f;
  }
  if (H) {
    float on = out_norm[i >> 4];
    ushort4 o[2];
#pragma unroll
    for (int j = 0; j < 8; ++j) ((unsigned short*)o)[j] = __half_as_ushort(__float2half_rn(v[j] * on));
    ((uint4*)H)[i] = *(const uint4*)o;
  }
  if (F) {
    ushort4 o[2];
#pragma unroll
    for (int j = 0; j < 8; ++j) ((unsigned short*)o)[j] = __half_as_ushort(__float2half_rn(v[j]));
    ((uint4*)F)[i] = *(const uint4*)o;
  }
}

// ---------------- MFMA layer-2 GEMM: p = fp16(out_norm*(X@w2^T)), out = X@l2^T + b2
__launch_bounds__(256)
__global__ void k_gemm2_16(const unsigned short* __restrict__ X,
                           const float* __restrict__ w2, const float* __restrict__ l2,
                           const float* __restrict__ b2,
                           const float* __restrict__ out_norm,
                           __half* __restrict__ p, float* __restrict__ out) {
  __shared__ __align__(16) unsigned short sX[64][136];
  __shared__ __align__(16) unsigned short sW[80][136];
  int t = threadIdx.x;
  int row0 = blockIdx.x * 64;
  int w = t >> 6, lane = t & 63;
  int q = lane >> 4, m = lane & 15;
  {
    int r = t >> 2;
    int c0 = (t & 3) * 4;
    const uint4* xr = (const uint4*)(X + (size_t)min(row0 + r, N_NODES - 1) * 128);
#pragma unroll
    for (int it = 0; it < 4; ++it) {
      uint4 v = xr[c0 + it];
      *(uint4*)&sX[r][(c0 + it) * 8] = v;
    }
  }
  {
#pragma unroll
    for (int it = 0; it < 10; ++it) {
      int i = it * 256 + t;   // float4 index 0..2559
      int j = i >> 5;         // weight row 0..79
      int kq = i & 31;
      const float* srcp = (j < 40) ? (w2 + (size_t)j * 128) : (l2 + (size_t)(j - 40) * 128);
      float4 v = ((const float4*)srcp)[kq];
      ushort4 o;
      o.x = __half_as_ushort(__float2half_rn(v.x));
      o.y = __half_as_ushort(__float2half_rn(v.y));
      o.z = __half_as_ushort(__float2half_rn(v.z));
      o.w = __half_as_ushort(__float2half_rn(v.w));
      *(ushort4*)&sW[j][kq * 4] = o;
    }
  }
  __syncthreads();
  floatx4 acc[5];
#pragma unroll
  for (int i = 0; i < 5; ++i) acc[i] = (floatx4){0.f, 0.f, 0.f, 0.f};
#pragma unroll
  for (int ks = 0; ks < 4; ++ks) {
    int kk = ks * 32 + q * 8;
    half8 a = *(const half8*)&sX[w * 16 + m][kk];
#pragma unroll
    for (int t5 = 0; t5 < 5; ++t5) {
      half8 b = *(const half8*)&sW[t5 * 16 + m][kk];
      acc[t5] = __builtin_amdgcn_mfma_f32_16x16x32_f16(a, b, acc[t5], 0, 0, 0);
    }
  }
#pragma unroll
  for (int t5 = 0; t5 < 5; ++t5) {
    int col = t5 * 16 + m;
#pragma unroll
    for (int i = 0; i < 4; ++i) {
      int row = row0 + w * 16 + q * 4 + i;
      if (row >= N_NODES) continue;
      if (col < 40) {
        p[(size_t)row * 40 + col] = __float2half_rn(out_norm[row] * acc[t5][i]);
      } else {
        out[(size_t)row * 40 + (col - 40)] = acc[t5][i] + b2[col - 40];
      }
    }
  }
}

// ---------------- layer-2 aggregation (fp16 gather): out[d] += in_norm[d] * sum_e p[src]
__global__ void k_agg40h(const __half* __restrict__ p, const int* __restrict__ col,
                         const int* __restrict__ row_start,
                         const float* __restrict__ in_norm,
                         float* __restrict__ out) {
  int wave = threadIdx.x >> 6, lane = threadIdx.x & 63;
  int node = blockIdx.x * 4 + wave;
  if (node >= N_NODES) return;
  int s0 = row_start[node], s1 = row_start[node + 1];
  float a0 = 0.f, a1 = 0.f, a2 = 0.f, a3 = 0.f;
  int e = s0;
  for (; e + 4 <= s1; e += 4) {
    int sA = col[e], sB = col[e + 1], sC = col[e + 2], sD = col[e + 3];
    float vA = __half2float(p[(size_t)sA * 40 + lane]);
    float vB = __half2float(p[(size_t)sB * 40 + lane]);
    float vC = __half2float(p[(size_t)sC * 40 + lane]);
    float vD = __half2float(p[(size_t)sD * 40 + lane]);
    a0 += vA; a1 += vB; a2 += vC; a3 += vD;
  }
  for (; e < s1; ++e) {
    a0 += __half2float(p[(size_t)col[e] * 40 + lane]);
  }
  if (lane < 40) out[(size_t)node * 40 + lane] += in_norm[node] * ((a0 + a1) + (a2 + a3));
}

extern "C" void kernel_launch(void* const* d_in, const int* in_sizes, int n_in,
                              void* d_out, int out_size, void* d_ws, size_t ws_size,
                              hipStream_t stream) {
  const float* feat = (const float*)d_in[0];
  const int* src = (const int*)d_in[1];
  const int* dst = (const int*)d_in[2];
  const float* w0 = (const float*)d_in[3];
  const float* w1 = (const float*)d_in[4];
  const float* w2 = (const float*)d_in[5];
  const float* b2 = (const float*)d_in[6];
  const float* l0 = (const float*)d_in[7];
  const float* l1 = (const float*)d_in[8];
  const float* l2 = (const float*)d_in[9];
  const float* g0 = (const float*)d_in[10];
  const float* beta0 = (const float*)d_in[11];
  const float* g1 = (const float*)d_in[12];
  const float* beta1 = (const float*)d_in[13];
  float* out = (float*)d_out;

  char* ws = (char*)d_ws;
  size_t off = 0;
  auto alloc = [&](size_t bytes) {
    void* ptr = ws + off;
    off = (off + bytes + 255) & ~(size_t)255;
    return ptr;
  };
  unsigned short* A16 = (unsigned short*)alloc(2 * (size_t)N_NODES * 128);  // agg out / p
  float* B = (float*)alloc(sizeof(float) * (size_t)N_NODES * 128);          // Hpart (prep) / B16
  unsigned short* H = (unsigned short*)alloc(2 * (size_t)N_NODES * 128);    // scaled fp16 gather table
  unsigned short* F = (unsigned short*)alloc(2 * (size_t)N_NODES * 128);    // unscaled fp16 gemm table
  int* degs = (int*)alloc(sizeof(int) * N_NODES);
  int* degd = (int*)alloc(sizeof(int) * N_NODES);
  int* row_start = (int*)alloc(sizeof(int) * (N_NODES + 1));
  int* colb = (int*)alloc(sizeof(int) * N_EDGES);
  float* out_norm = (float*)alloc(sizeof(float) * N_NODES);
  float* in_norm = (float*)alloc(sizeof(float) * N_NODES);
  int* bsum = (int*)alloc(sizeof(int) * 512);
  float* stats = (float*)alloc(sizeof(float) * 256);

  // Hpart (33.6 MB) aliases B (51.2 MB): consumed by k_build before B's first write.
  unsigned int* Hpart = (unsigned int*)B;
  unsigned short* B16 = (unsigned short*)B;

  int nb = (N_NODES + 255) / 256;  // 391
  int hb = HCH * HRG;              // 512

  k_hist_part<<<hb, 256, 0, stream>>>(src, Hpart);
  k_hist_sum<<<nb, 256, 0, stream>>>((const unsigned short*)Hpart, degs);
  k_hist_part<<<hb, 256, 0, stream>>>(dst, Hpart);
  k_hist_scan<<<nb, 256, 0, stream>>>((unsigned short*)Hpart, degd);  // -> per-chunk bases
  k_norms<<<nb, 256, 0, stream>>>(degs, degd, out_norm, in_norm);
  k_scan1<<<nb, 256, 0, stream>>>(degd, bsum);
  k_scan2<<<1, 512, 0, stream>>>(bsum, nb);
  k_scan3<<<nb, 256, 0, stream>>>(degd, bsum, row_start);
  k_build<<<hb, 256, 0, stream>>>(src, dst, (const unsigned short*)Hpart, row_start, colb);

  int ab = (N_NODES + 3) / 4;   // wave per node
  int gb = (N_NODES + 63) / 64;
  int fb = (N_NODES * 32 + 255) / 256;
  int hb16 = (N_NODES * 16 + 255) / 256;

  // layer 0: h1 = relu(bn(agg(feat)@w0^T + feat@l0^T))
  k_feat2h<<<fb, 256, 0, stream>>>(feat, out_norm, H, F);
  k_agg128h<<<ab, 256, 0, stream>>>((const __half*)H, colb, row_start, in_norm, A16);
  hipMemsetAsync(stats, 0, sizeof(float) * 256, stream);
  k_gemm_dual16<<<gb, 256, 0, stream>>>(A16, F, w0, l0, B16, stats);
  k_bnrelu16<<<hb16, 256, 0, stream>>>(B16, stats, g0, beta0, out_norm, H, F);

  // layer 1: h2 = relu(bn(agg(h1)@w1^T + h1@l1^T))
  k_agg128h<<<ab, 256, 0, stream>>>((const __half*)H, colb, row_start, in_norm, A16);
  hipMemsetAsync(stats, 0, sizeof(float) * 256, stream);
  k_gemm_dual16<<<gb, 256, 0, stream>>>(A16, F, w1, l1, B16, stats);
  k_bnrelu16<<<hb16, 256, 0, stream>>>(B16, stats, g1, beta1, out_norm,
                                       (unsigned short*)nullptr, F);  // F = fp16 h2

  // layer 2: out = in_norm*agg(fp16(out_norm*(h2@w2^T))) + b2 + h2@l2^T
  __half* p = (__half*)A16;  // A16 dead after layer-1 gemm
  k_gemm2_16<<<gb, 256, 0, stream>>>(F, w2, l2, b2, out_norm, p, out);
  k_agg40h<<<ab, 256, 0, stream>>>(p, colb, row_start, in_norm, out);
}